// Round 4
// baseline (2697.337 us; speedup 1.0000x reference)
//
#include <hip/hip_runtime.h>
#include <hip/hip_bf16.h>
#include <math.h>

// Problem dims (fixed by the reference)
#define NB 64      // batch
#define NS 64      // encoder steps
#define NL 64      // decoder steps
#define NH 256     // hidden
#define G3 768     // 3*NH (gates r,z,n)
#define NVIN 10000
#define NVOUT 10000
#define KP1 10016   // NVIN padded to multiple of 32 (BK) for enc GEMM
#define NOUTP 10112 // NVOUT padded to multiple of 128 (BN) for out GEMM

typedef __attribute__((ext_vector_type(8))) short bf16x8;  // 8 bf16 (4 VGPRs)
typedef __attribute__((ext_vector_type(4))) float f32x4;   // MFMA accumulator

// async global->LDS, 16B per lane (dest must be wave-uniform base + lane*16)
__device__ __forceinline__ void gld_lds16(const __hip_bfloat16* g, __hip_bfloat16* l) {
  __builtin_amdgcn_global_load_lds(
      (const __attribute__((address_space(1))) unsigned int*)(const void*)g,
      (__attribute__((address_space(3))) unsigned int*)(void*)l, 16, 0, 0);
}

__device__ __forceinline__ unsigned int f2bf(float f) {  // RNE fp32->bf16 bits
  unsigned int u = __float_as_uint(f);
  return (u + 0x7fff + ((u >> 16) & 1)) >> 16;
}

// ---------------------------------------------------------------------------
// fp32 -> bf16 row-wise convert with row/col zero-padding.
// ---------------------------------------------------------------------------
__global__ __launch_bounds__(256) void k_cvt_pad(
    const float* __restrict__ in, __hip_bfloat16* __restrict__ out,
    int in_rows, int in_cols, int out_cols) {
  int r = blockIdx.x;
  const float* src = in + (size_t)r * in_cols;
  __hip_bfloat16* dst = out + (size_t)r * out_cols;
  bool live = r < in_rows;
  for (int c = threadIdx.x * 4; c < out_cols; c += 1024) {
    __hip_bfloat16 v[4];
    if (live && c < in_cols) {
      float4 f = *(const float4*)(src + c);
      v[0] = __float2bfloat16(f.x); v[1] = __float2bfloat16(f.y);
      v[2] = __float2bfloat16(f.z); v[3] = __float2bfloat16(f.w);
    } else {
      v[0] = v[1] = v[2] = v[3] = __float2bfloat16(0.f);
    }
    *(ushort4*)(dst + c) = *(const ushort4*)v;
  }
}

// ---------------------------------------------------------------------------
// Pack recurrent weights to bf16 Wcat[f][c][k]: f<3 from A (gate f, stride
// strideA), f>=3 from B (gate f-3, stride strideB). c,k in [0,256).
// ---------------------------------------------------------------------------
__global__ __launch_bounds__(256) void k_wpack(
    const float* __restrict__ srcA, int strideA,
    const float* __restrict__ srcB, int strideB,
    __hip_bfloat16* __restrict__ out, int total) {
  int idx = blockIdx.x * 256 + threadIdx.x;
  if (idx >= total) return;
  int k = idx & 255, c = (idx >> 8) & 255, f = idx >> 16;
  float v = (f < 3) ? srcA[(size_t)(f * 256 + c) * strideA + k]
                    : srcB[(size_t)((f - 3) * 256 + c) * strideB + k];
  out[idx] = __float2bfloat16(v);
}

// ---------------------------------------------------------------------------
// MFMA GEMM (NT): C[m][n] = sum_k A[m][k]*B[n][k] + bias[n]
// A [4096][KP1] bf16 (row = b*64+s, X order), B [768][KP1] bf16.
// ---------------------------------------------------------------------------
__global__ __launch_bounds__(256) void k_gemm_enc_mfma(
    const __hip_bfloat16* __restrict__ A, const __hip_bfloat16* __restrict__ B,
    const float* __restrict__ bias, float* __restrict__ C) {
  __shared__ __hip_bfloat16 As[128][32];
  __shared__ __hip_bfloat16 Bs[128][32];
  int t = threadIdx.x;
  int wid = t >> 6, lane = t & 63;
  int m0 = blockIdx.y * 128, n0 = blockIdx.x * 128;
  int wr = wid >> 1, wc = wid & 1;
  f32x4 acc[4][4] = {};
  for (int k0 = 0; k0 < KP1; k0 += 32) {
    __syncthreads();
#pragma unroll
    for (int is = 0; is < 2; ++is) {
      int off = is * 4096 + wid * 1024 + lane * 16;
      int r = off >> 6, cb = (off & 63) >> 1;
      gld_lds16(A + (size_t)(m0 + r) * KP1 + k0 + cb, &As[r][cb]);
      gld_lds16(B + (size_t)(n0 + r) * KP1 + k0 + cb, &Bs[r][cb]);
    }
    __syncthreads();
    int r16 = lane & 15, kb = (lane >> 4) * 8;
    bf16x8 af[4], bfr[4];
#pragma unroll
    for (int i = 0; i < 4; ++i) {
      af[i]  = *(const bf16x8*)&As[wr * 64 + i * 16 + r16][kb];
      bfr[i] = *(const bf16x8*)&Bs[wc * 64 + i * 16 + r16][kb];
    }
#pragma unroll
    for (int i = 0; i < 4; ++i)
#pragma unroll
      for (int j = 0; j < 4; ++j)
        acc[i][j] = __builtin_amdgcn_mfma_f32_16x16x32_bf16(af[i], bfr[j], acc[i][j], 0, 0, 0);
  }
  int r16 = lane & 15, rg = lane >> 4;
#pragma unroll
  for (int i = 0; i < 4; ++i)
#pragma unroll
    for (int j = 0; j < 4; ++j) {
      int ccol = n0 + wc * 64 + j * 16 + r16;
      float bs = bias[ccol];
#pragma unroll
      for (int q = 0; q < 4; ++q) {
        int crow = m0 + wr * 64 + i * 16 + rg * 4 + q;
        C[(size_t)crow * G3 + ccol] = acc[i][j][q] + bs;
      }
    }
}

// ---------------------------------------------------------------------------
// MFMA GEMM out: A dec_h bf16 [4096][256] (row = l*64+b), B out_W bf16
// [10112][256] zero-padded. C row (b*NL+l), col guard < NVOUT.
// ---------------------------------------------------------------------------
__global__ __launch_bounds__(256) void k_gemm_out_mfma(
    const __hip_bfloat16* __restrict__ A, const __hip_bfloat16* __restrict__ B,
    const float* __restrict__ bias, float* __restrict__ C) {
  __shared__ __hip_bfloat16 As[128][32];
  __shared__ __hip_bfloat16 Bs[128][32];
  int t = threadIdx.x;
  int wid = t >> 6, lane = t & 63;
  int m0 = blockIdx.y * 128, n0 = blockIdx.x * 128;
  int wr = wid >> 1, wc = wid & 1;
  f32x4 acc[4][4] = {};
  for (int k0 = 0; k0 < NH; k0 += 32) {
    __syncthreads();
#pragma unroll
    for (int is = 0; is < 2; ++is) {
      int off = is * 4096 + wid * 1024 + lane * 16;
      int r = off >> 6, cb = (off & 63) >> 1;
      gld_lds16(A + (size_t)(m0 + r) * NH + k0 + cb, &As[r][cb]);
      gld_lds16(B + (size_t)(n0 + r) * NH + k0 + cb, &Bs[r][cb]);
    }
    __syncthreads();
    int r16 = lane & 15, kb = (lane >> 4) * 8;
    bf16x8 af[4], bfr[4];
#pragma unroll
    for (int i = 0; i < 4; ++i) {
      af[i]  = *(const bf16x8*)&As[wr * 64 + i * 16 + r16][kb];
      bfr[i] = *(const bf16x8*)&Bs[wc * 64 + i * 16 + r16][kb];
    }
#pragma unroll
    for (int i = 0; i < 4; ++i)
#pragma unroll
      for (int j = 0; j < 4; ++j)
        acc[i][j] = __builtin_amdgcn_mfma_f32_16x16x32_bf16(af[i], bfr[j], acc[i][j], 0, 0, 0);
  }
  int r16 = lane & 15, rg = lane >> 4;
#pragma unroll
  for (int i = 0; i < 4; ++i)
#pragma unroll
    for (int j = 0; j < 4; ++j) {
      int ccol = n0 + wc * 64 + j * 16 + r16;
      if (ccol < NVOUT) {
        float bs = bias[ccol];
#pragma unroll
        for (int q = 0; q < 4; ++q) {
          int crow = m0 + wr * 64 + i * 16 + rg * 4 + q;  // = l*64+b
          int l = crow >> 6, b = crow & 63;
          C[((size_t)b * NL + l) * NVOUT + ccol] = acc[i][j][q] + bs;
        }
      }
    }
}

// ---------------------------------------------------------------------------
// Pre-gather decoder one-hot input term: Gdec = bih + onehot column.
// ---------------------------------------------------------------------------
__global__ __launch_bounds__(256) void k_pregather(
    const float* __restrict__ Wih, const float* __restrict__ bih,
    const int* __restrict__ gt, float* __restrict__ Gdec) {
  int ib = blockIdx.x;              // i*64+b
  int i = ib >> 6, b = ib & 63;
  int tok = (i > 0) ? gt[b * NL + (i - 1)] : -1;
  for (int g = threadIdx.x; g < G3; g += 256) {
    float v = bih[g];
    if (tok >= 0) v += Wih[(size_t)g * (NH + NVOUT) + NH + tok];
    Gdec[(size_t)ib * G3 + g] = v;
  }
}

// ---------------------------------------------------------------------------
// Encoder scan, weight-stationary MFMA. 8 WGs x 1024 thr; WG handles batches
// b0..b0+7. Wave w owns gate-cols [w*16,w*16+16) of all 3 Whh panels as 24
// bf16x8 B-frags in VGPRs (loaded once). Per step: 8 swizzled ds_read_b128
// A-frags (h, 8 live batch rows + 8 zero rows), 24 MFMA, gates on lanes<32,
// ONE barrier. escore fused (wave w<8 after barrier). h double-buffered.
// ---------------------------------------------------------------------------
__global__ __launch_bounds__(1024, 4) void k_encoder2(
    const float* __restrict__ Gi, const __hip_bfloat16* __restrict__ Wcat,
    const float* __restrict__ bhh, const float* __restrict__ att_w,
    float* __restrict__ enchB, float* __restrict__ escoreT) {
  __shared__ float h32[2][8][256];
  __shared__ __hip_bfloat16 hbf[2][16][256];
  int t = threadIdx.x, w = t >> 6, lane = t & 63;
  int b0 = blockIdx.x * 8;
  int row = lane & 15, hi16 = lane >> 4;
  // weights: wave w, frag col = w*16+row, k-slice hi16*8
  bf16x8 wv[3][8];
#pragma unroll
  for (int f = 0; f < 3; ++f)
#pragma unroll
    for (int kf = 0; kf < 8; ++kf)
      wv[f][kf] = *(const bf16x8*)(Wcat + (((size_t)f * 256 + w * 16 + row) * 256 + kf * 32 + hi16 * 8));
  int c = w * 16 + row;
  bool live = lane < 32;
  float bh[3];
#pragma unroll
  for (int g = 0; g < 3; ++g) bh[g] = bhh[g * 256 + c];
  float aw[4];
#pragma unroll
  for (int q = 0; q < 4; ++q) aw[q] = att_w[256 + lane + q * 64];   // w_enc
  // init: h=0
  for (int e = t; e < 2048; e += 1024) h32[0][e >> 8][e & 255] = 0.f;
  for (int e = t; e < 4096; e += 1024) {
    int r = e >> 8, j = e & 255;
    hbf[0][r][j] = __float2bfloat16(0.f);
    if (r >= 8) hbf[1][r][j] = __float2bfloat16(0.f);
  }
  __syncthreads();
  int cur = 0;
  int xr = (row & 7) << 4;
  int abase = row * 512 + hi16 * 16;
  for (int s = 0; s < NS; ++s) {
    // Gi loads first (latency hides under MFMA issue)
    float gd[3][4];
    if (live) {
#pragma unroll
      for (int g = 0; g < 3; ++g)
#pragma unroll
        for (int q = 0; q < 4; ++q) {
          int b = hi16 * 4 + q;
          gd[g][q] = Gi[((size_t)(b0 + b) * 64 + s) * G3 + g * 256 + c];
        }
    }
    const char* hb = (const char*)&hbf[cur][0][0];
    bf16x8 ah[8];
#pragma unroll
    for (int kf = 0; kf < 8; ++kf)
      ah[kf] = *(const bf16x8*)(hb + ((abase + kf * 64) ^ xr));
    f32x4 acc[3] = {};
#pragma unroll
    for (int f = 0; f < 3; ++f)
#pragma unroll
      for (int kf = 0; kf < 8; ++kf)
        acc[f] = __builtin_amdgcn_mfma_f32_16x16x32_bf16(ah[kf], wv[f][kf], acc[f], 0, 0, 0);
    if (live) {
      int nxt = cur ^ 1;
      char* hbw = (char*)&hbf[nxt][0][0];
#pragma unroll
      for (int q = 0; q < 4; ++q) {
        int b = hi16 * 4 + q;
        float rr = 1.f / (1.f + __expf(-(gd[0][q] + acc[0][q] + bh[0])));
        float zz = 1.f / (1.f + __expf(-(gd[1][q] + acc[1][q] + bh[1])));
        float nn = tanhf(gd[2][q] + rr * (acc[2][q] + bh[2]));
        float ho = h32[cur][b][c];
        float hn = (1.f - zz) * nn + zz * ho;
        h32[nxt][b][c] = hn;
        *(__hip_bfloat16*)(hbw + ((b * 512 + c * 2) ^ ((b & 7) << 4))) = __float2bfloat16(hn);
        enchB[((size_t)(b0 + b) * 64 + s) * 256 + c] = hn;
      }
    }
    __syncthreads();
    cur ^= 1;
    // escore for step s on just-written h (overlaps next step's phases)
    if (w < 8) {
      float p = h32[cur][w][lane] * aw[0] + h32[cur][w][lane + 64] * aw[1]
              + h32[cur][w][lane + 128] * aw[2] + h32[cur][w][lane + 192] * aw[3];
#pragma unroll
      for (int off = 32; off; off >>= 1) p += __shfl_xor(p, off, 64);
      if (lane == 0) escoreT[(size_t)(b0 + w) * 64 + s] = p;
    }
  }
}

// ---------------------------------------------------------------------------
// Decoder scan, weight-stationary MFMA. Same shape as encoder; wave w owns
// 16 cols of 6 panels (gi r,z,n from Wih-ctx; gh r,z,n from Whh) = 48 frags.
// Per step: [gh MFMA + softmax] bar [ctx fp32 pk-FMA] bar [gi MFMA + gates]
// bar. 3 barriers/step.
// ---------------------------------------------------------------------------
__global__ __launch_bounds__(1024, 4) void k_decoder2(
    const float* __restrict__ Gdec, const __hip_bfloat16* __restrict__ Wcat6,
    const float* __restrict__ bhh, const float* __restrict__ enchB,
    const float* __restrict__ escoreT, const float* __restrict__ att_w,
    const float* __restrict__ att_b, __hip_bfloat16* __restrict__ dechb) {
  __shared__ float h32[2][8][256];
  __shared__ __hip_bfloat16 hbf[2][16][256];
  __shared__ __hip_bfloat16 ctxbf[16][256];
  __shared__ float wts[8][64];
  int t = threadIdx.x, w = t >> 6, lane = t & 63;
  int b0 = blockIdx.x * 8;
  int row = lane & 15, hi16 = lane >> 4;
  bf16x8 wv[6][8];
#pragma unroll
  for (int f = 0; f < 6; ++f)
#pragma unroll
    for (int kf = 0; kf < 8; ++kf)
      wv[f][kf] = *(const bf16x8*)(Wcat6 + (((size_t)f * 256 + w * 16 + row) * 256 + kf * 32 + hi16 * 8));
  int c = w * 16 + row;
  bool live = lane < 32;
  float bh[3];
#pragma unroll
  for (int g = 0; g < 3; ++g) bh[g] = bhh[g * 256 + c];
  float aw[4];
#pragma unroll
  for (int q = 0; q < 4; ++q) aw[q] = att_w[lane + q * 64];         // w_dec
  float attb = att_b[0];
  // init: h0 = enc_h[S-1]; zero dead rows of hbf/ctxbf
  for (int e = t; e < 2048; e += 1024) {
    int b = e >> 8, j = e & 255;
    float v = enchB[((size_t)(b0 + b) * 64 + 63) * 256 + j];
    h32[0][b][j] = v;
    *(__hip_bfloat16*)((char*)&hbf[0][0][0] + ((b * 512 + j * 2) ^ ((b & 7) << 4))) = __float2bfloat16(v);
  }
  for (int e = t; e < 2048; e += 1024) {
    int r = 8 + (e >> 8), j = e & 255;
    hbf[0][r][j] = __float2bfloat16(0.f);
    hbf[1][r][j] = __float2bfloat16(0.f);
    ctxbf[r][j] = __float2bfloat16(0.f);
  }
  __syncthreads();
  int cur = 0;
  int xr = (row & 7) << 4;
  int abase = row * 512 + hi16 * 16;
  for (int i = 0; i < NL; ++i) {
    // Gdec loads first
    float gd[3][4];
    if (live) {
#pragma unroll
      for (int g = 0; g < 3; ++g)
#pragma unroll
        for (int q = 0; q < 4; ++q) {
          int b = hi16 * 4 + q;
          gd[g][q] = Gdec[((size_t)i * 64 + b0 + b) * G3 + g * 256 + c];
        }
    }
    // gh = h @ Whh^T (frags 3..5)
    const char* hb = (const char*)&hbf[cur][0][0];
    bf16x8 ah[8];
#pragma unroll
    for (int kf = 0; kf < 8; ++kf)
      ah[kf] = *(const bf16x8*)(hb + ((abase + kf * 64) ^ xr));
    f32x4 acch[3] = {};
#pragma unroll
    for (int f = 0; f < 3; ++f)
#pragma unroll
      for (int kf = 0; kf < 8; ++kf)
        acch[f] = __builtin_amdgcn_mfma_f32_16x16x32_bf16(ah[kf], wv[3 + f][kf], acch[f], 0, 0, 0);
    // softmax over S (one wave per batch)
    if (w < 8) {
      float p = h32[cur][w][lane] * aw[0] + h32[cur][w][lane + 64] * aw[1]
              + h32[cur][w][lane + 128] * aw[2] + h32[cur][w][lane + 192] * aw[3];
#pragma unroll
      for (int off = 32; off; off >>= 1) p += __shfl_xor(p, off, 64);
      float lg = fmaxf(escoreT[(size_t)(b0 + w) * 64 + lane] + p + attb, 0.f);
      float mx = lg;
#pragma unroll
      for (int off = 32; off; off >>= 1) mx = fmaxf(mx, __shfl_xor(mx, off, 64));
      float e = __expf(lg - mx);
      float sm = e;
#pragma unroll
      for (int off = 32; off; off >>= 1) sm += __shfl_xor(sm, off, 64);
      wts[w][lane] = e / sm;
    }
    __syncthreads();
    // ctx[b][j-pair] = sum_s wts[b][s] * enchB[b][s][j-pair]  (fp32 pk-FMA)
    {
      int bl = t >> 7, jp = t & 127;
      const float* eb = enchB + (size_t)(b0 + bl) * 64 * 256 + 2 * jp;
      float cx = 0.f, cy = 0.f;
#pragma unroll 8
      for (int s2 = 0; s2 < 32; ++s2) {
        float2 w2 = *(const float2*)&wts[bl][2 * s2];
        float2 e0 = *(const float2*)(eb + (size_t)(2 * s2) * 256);
        float2 e1 = *(const float2*)(eb + (size_t)(2 * s2 + 1) * 256);
        cx = fmaf(w2.x, e0.x, cx); cy = fmaf(w2.x, e0.y, cy);
        cx = fmaf(w2.y, e1.x, cx); cy = fmaf(w2.y, e1.y, cy);
      }
      unsigned u = f2bf(cx) | (f2bf(cy) << 16);
      *(unsigned*)((char*)&ctxbf[0][0] + ((bl * 512 + jp * 4) ^ ((bl & 7) << 4))) = u;
    }
    __syncthreads();
    // gi = ctx @ Wih^T (frags 0..2) + gates
    const char* cb = (const char*)&ctxbf[0][0];
    bf16x8 ac[8];
#pragma unroll
    for (int kf = 0; kf < 8; ++kf)
      ac[kf] = *(const bf16x8*)(cb + ((abase + kf * 64) ^ xr));
    f32x4 acci[3] = {};
#pragma unroll
    for (int f = 0; f < 3; ++f)
#pragma unroll
      for (int kf = 0; kf < 8; ++kf)
        acci[f] = __builtin_amdgcn_mfma_f32_16x16x32_bf16(ac[kf], wv[f][kf], acci[f], 0, 0, 0);
    if (live) {
      int nxt = cur ^ 1;
      char* hbw = (char*)&hbf[nxt][0][0];
#pragma unroll
      for (int q = 0; q < 4; ++q) {
        int b = hi16 * 4 + q;
        float rr = 1.f / (1.f + __expf(-(gd[0][q] + acci[0][q] + acch[0][q] + bh[0])));
        float zz = 1.f / (1.f + __expf(-(gd[1][q] + acci[1][q] + acch[1][q] + bh[1])));
        float nn = tanhf(gd[2][q] + acci[2][q] + rr * (acch[2][q] + bh[2]));
        float ho = h32[cur][b][c];
        float hn = (1.f - zz) * nn + zz * ho;
        h32[nxt][b][c] = hn;
        *(__hip_bfloat16*)(hbw + ((b * 512 + c * 2) ^ ((b & 7) << 4))) = __float2bfloat16(hn);
        dechb[((size_t)i * 64 + b0 + b) * 256 + c] = __float2bfloat16(hn);
      }
    }
    __syncthreads();
    cur ^= 1;
  }
}

// In-place row log-softmax over VOUT (one WG per (b,l) row).
__global__ __launch_bounds__(256) void k_logsoftmax(float* __restrict__ out) {
  float* x = out + (size_t)blockIdx.x * NVOUT;
  __shared__ float red[256];
  int t = threadIdx.x;
  float mx = -1e30f;
  for (int v = t; v < NVOUT; v += 256) mx = fmaxf(mx, x[v]);
  red[t] = mx; __syncthreads();
  for (int off = 128; off; off >>= 1) {
    if (t < off) red[t] = fmaxf(red[t], red[t + off]);
    __syncthreads();
  }
  mx = red[0]; __syncthreads();
  float sm = 0.f;
  for (int v = t; v < NVOUT; v += 256) sm += __expf(x[v] - mx);
  red[t] = sm; __syncthreads();
  for (int off = 128; off; off >>= 1) {
    if (t < off) red[t] += red[t + off];
    __syncthreads();
  }
  float lse = mx + logf(red[0]);
  for (int v = t; v < NVOUT; v += 256) x[v] -= lse;
}

// ---------------------------------------------------------------------------
extern "C" void kernel_launch(void* const* d_in, const int* in_sizes, int n_in,
                              void* d_out, int out_size, void* d_ws, size_t ws_size,
                              hipStream_t stream) {
  const float* X        = (const float*)d_in[0];
  const int*   gt       = (const int*)  d_in[1];
  const float* enc_Wih  = (const float*)d_in[2];
  const float* enc_Whh  = (const float*)d_in[3];
  const float* enc_bih  = (const float*)d_in[4];
  const float* enc_bhh  = (const float*)d_in[5];
  const float* att_w    = (const float*)d_in[6];
  const float* att_b    = (const float*)d_in[7];
  const float* dec_Wih  = (const float*)d_in[8];
  const float* dec_Whh  = (const float*)d_in[9];
  const float* dec_bih  = (const float*)d_in[10];
  const float* dec_bhh  = (const float*)d_in[11];
  const float* out_W    = (const float*)d_in[12];
  const float* out_b    = (const float*)d_in[13];
  float* out = (float*)d_out;

  // workspace carve-up (~136 MB)
  float* p = (float*)d_ws;
  float* Gienc  = p; p += NS * NB * G3;          // [b*64+s][768]
  float* Gdec   = p; p += NL * NB * G3;          // [i*64+b][768]
  float* enchB  = p; p += NB * NS * NH;          // [b][s][j] fp32
  float* escoreT = p; p += NB * NS;              // [b][s]
  __hip_bfloat16* q = (__hip_bfloat16*)p;
  __hip_bfloat16* Wcat_e = q; q += (size_t)3 * 256 * 256;  // enc Whh r,z,n
  __hip_bfloat16* Wcat_d = q; q += (size_t)6 * 256 * 256;  // dec Wih(ctx) + Whh
  __hip_bfloat16* Xb     = q; q += (size_t)4096 * KP1;
  __hip_bfloat16* Wencb  = q; q += (size_t)G3 * KP1;
  __hip_bfloat16* Woutb  = q; q += (size_t)NOUTP * NH;
  __hip_bfloat16* dechb  = q; q += (size_t)NL * NB * NH;

  // prep (independent)
  k_cvt_pad<<<4096, 256, 0, stream>>>(X, Xb, 4096, NVIN, KP1);
  k_cvt_pad<<<G3, 256, 0, stream>>>(enc_Wih, Wencb, G3, NVIN, KP1);
  k_cvt_pad<<<NOUTP, 256, 0, stream>>>(out_W, Woutb, NVOUT, NH, NH);
  k_wpack<<<768, 256, 0, stream>>>(enc_Whh, NH, enc_Whh, NH, Wcat_e, 3 * 65536);
  k_wpack<<<1536, 256, 0, stream>>>(dec_Wih, NH + NVOUT, dec_Whh, NH, Wcat_d, 6 * 65536);
  k_pregather<<<NL * NB, 256, 0, stream>>>(dec_Wih, dec_bih, gt, Gdec);

  k_gemm_enc_mfma<<<dim3(6, 32), 256, 0, stream>>>(Xb, Wencb, enc_bih, Gienc);
  k_encoder2<<<8, 1024, 0, stream>>>(Gienc, Wcat_e, enc_bhh, att_w, enchB, escoreT);
  k_decoder2<<<8, 1024, 0, stream>>>(Gdec, Wcat_d, dec_bhh, enchB, escoreT,
                                     att_w, att_b, dechb);
  k_gemm_out_mfma<<<dim3(79, 32), 256, 0, stream>>>(dechb, Woutb, out_b, out);
  k_logsoftmax<<<NB * NL, 256, 0, stream>>>(out);
}

// Round 5
// 2084.956 us; speedup vs baseline: 1.2937x; 1.2937x over previous
//
#include <hip/hip_runtime.h>
#include <hip/hip_bf16.h>
#include <math.h>

// Problem dims (fixed by the reference)
#define NB 64      // batch
#define NS 64      // encoder steps
#define NL 64      // decoder steps
#define NH 256     // hidden
#define G3 768     // 3*NH (gates r,z,n)
#define NVIN 10000
#define NVOUT 10000
#define KP1 10016   // NVIN padded to multiple of 32 (BK) for enc GEMM
#define NOUTP 10112 // NVOUT padded to multiple of 128 (BN) for out GEMM

typedef __attribute__((ext_vector_type(8))) short bf16x8;  // 8 bf16 (4 VGPRs)
typedef __attribute__((ext_vector_type(4))) float f32x4;   // MFMA accumulator

// async global->LDS, 16B per lane (dest must be wave-uniform base + lane*16)
__device__ __forceinline__ void gld_lds16(const __hip_bfloat16* g, __hip_bfloat16* l) {
  __builtin_amdgcn_global_load_lds(
      (const __attribute__((address_space(1))) unsigned int*)(const void*)g,
      (__attribute__((address_space(3))) unsigned int*)(void*)l, 16, 0, 0);
}

__device__ __forceinline__ unsigned int f2bf(float f) {  // RNE fp32->bf16 bits
  unsigned int u = __float_as_uint(f);
  return (u + 0x7fff + ((u >> 16) & 1)) >> 16;
}

// ---------------------------------------------------------------------------
// fp32 -> bf16 row-wise convert with row/col zero-padding.
// ---------------------------------------------------------------------------
__global__ __launch_bounds__(256) void k_cvt_pad(
    const float* __restrict__ in, __hip_bfloat16* __restrict__ out,
    int in_rows, int in_cols, int out_cols) {
  int r = blockIdx.x;
  const float* src = in + (size_t)r * in_cols;
  __hip_bfloat16* dst = out + (size_t)r * out_cols;
  bool live = r < in_rows;
  for (int c = threadIdx.x * 4; c < out_cols; c += 1024) {
    __hip_bfloat16 v[4];
    if (live && c < in_cols) {
      float4 f = *(const float4*)(src + c);
      v[0] = __float2bfloat16(f.x); v[1] = __float2bfloat16(f.y);
      v[2] = __float2bfloat16(f.z); v[3] = __float2bfloat16(f.w);
    } else {
      v[0] = v[1] = v[2] = v[3] = __float2bfloat16(0.f);
    }
    *(ushort4*)(dst + c) = *(const ushort4*)v;
  }
}

// ---------------------------------------------------------------------------
// Pack recurrent weights to bf16 Wcat[f][c][k]: f<3 from A (gate f, stride
// strideA), f>=3 from B (gate f-3, stride strideB). c,k in [0,256).
// ---------------------------------------------------------------------------
__global__ __launch_bounds__(256) void k_wpack(
    const float* __restrict__ srcA, int strideA,
    const float* __restrict__ srcB, int strideB,
    __hip_bfloat16* __restrict__ out, int total) {
  int idx = blockIdx.x * 256 + threadIdx.x;
  if (idx >= total) return;
  int k = idx & 255, c = (idx >> 8) & 255, f = idx >> 16;
  float v = (f < 3) ? srcA[(size_t)(f * 256 + c) * strideA + k]
                    : srcB[(size_t)((f - 3) * 256 + c) * strideB + k];
  out[idx] = __float2bfloat16(v);
}

// ---------------------------------------------------------------------------
// MFMA GEMM (NT): C[m][n] = sum_k A[m][k]*B[n][k] + bias[n]
// A [4096][KP1] bf16 (row = b*64+s, X order), B [768][KP1] bf16.
// ---------------------------------------------------------------------------
__global__ __launch_bounds__(256) void k_gemm_enc_mfma(
    const __hip_bfloat16* __restrict__ A, const __hip_bfloat16* __restrict__ B,
    const float* __restrict__ bias, float* __restrict__ C) {
  __shared__ __hip_bfloat16 As[128][32];
  __shared__ __hip_bfloat16 Bs[128][32];
  int t = threadIdx.x;
  int wid = t >> 6, lane = t & 63;
  int m0 = blockIdx.y * 128, n0 = blockIdx.x * 128;
  int wr = wid >> 1, wc = wid & 1;
  f32x4 acc[4][4] = {};
  for (int k0 = 0; k0 < KP1; k0 += 32) {
    __syncthreads();
#pragma unroll
    for (int is = 0; is < 2; ++is) {
      int off = is * 4096 + wid * 1024 + lane * 16;
      int r = off >> 6, cb = (off & 63) >> 1;
      gld_lds16(A + (size_t)(m0 + r) * KP1 + k0 + cb, &As[r][cb]);
      gld_lds16(B + (size_t)(n0 + r) * KP1 + k0 + cb, &Bs[r][cb]);
    }
    __syncthreads();
    int r16 = lane & 15, kb = (lane >> 4) * 8;
    bf16x8 af[4], bfr[4];
#pragma unroll
    for (int i = 0; i < 4; ++i) {
      af[i]  = *(const bf16x8*)&As[wr * 64 + i * 16 + r16][kb];
      bfr[i] = *(const bf16x8*)&Bs[wc * 64 + i * 16 + r16][kb];
    }
#pragma unroll
    for (int i = 0; i < 4; ++i)
#pragma unroll
      for (int j = 0; j < 4; ++j)
        acc[i][j] = __builtin_amdgcn_mfma_f32_16x16x32_bf16(af[i], bfr[j], acc[i][j], 0, 0, 0);
  }
  int r16 = lane & 15, rg = lane >> 4;
#pragma unroll
  for (int i = 0; i < 4; ++i)
#pragma unroll
    for (int j = 0; j < 4; ++j) {
      int ccol = n0 + wc * 64 + j * 16 + r16;
      float bs = bias[ccol];
#pragma unroll
      for (int q = 0; q < 4; ++q) {
        int crow = m0 + wr * 64 + i * 16 + rg * 4 + q;
        C[(size_t)crow * G3 + ccol] = acc[i][j][q] + bs;
      }
    }
}

// ---------------------------------------------------------------------------
// MFMA GEMM out: A dec_h bf16 [4096][256] (row = l*64+b), B out_W bf16
// [10112][256] zero-padded. C row (b*NL+l), col guard < NVOUT.
// ---------------------------------------------------------------------------
__global__ __launch_bounds__(256) void k_gemm_out_mfma(
    const __hip_bfloat16* __restrict__ A, const __hip_bfloat16* __restrict__ B,
    const float* __restrict__ bias, float* __restrict__ C) {
  __shared__ __hip_bfloat16 As[128][32];
  __shared__ __hip_bfloat16 Bs[128][32];
  int t = threadIdx.x;
  int wid = t >> 6, lane = t & 63;
  int m0 = blockIdx.y * 128, n0 = blockIdx.x * 128;
  int wr = wid >> 1, wc = wid & 1;
  f32x4 acc[4][4] = {};
  for (int k0 = 0; k0 < NH; k0 += 32) {
    __syncthreads();
#pragma unroll
    for (int is = 0; is < 2; ++is) {
      int off = is * 4096 + wid * 1024 + lane * 16;
      int r = off >> 6, cb = (off & 63) >> 1;
      gld_lds16(A + (size_t)(m0 + r) * NH + k0 + cb, &As[r][cb]);
      gld_lds16(B + (size_t)(n0 + r) * NH + k0 + cb, &Bs[r][cb]);
    }
    __syncthreads();
    int r16 = lane & 15, kb = (lane >> 4) * 8;
    bf16x8 af[4], bfr[4];
#pragma unroll
    for (int i = 0; i < 4; ++i) {
      af[i]  = *(const bf16x8*)&As[wr * 64 + i * 16 + r16][kb];
      bfr[i] = *(const bf16x8*)&Bs[wc * 64 + i * 16 + r16][kb];
    }
#pragma unroll
    for (int i = 0; i < 4; ++i)
#pragma unroll
      for (int j = 0; j < 4; ++j)
        acc[i][j] = __builtin_amdgcn_mfma_f32_16x16x32_bf16(af[i], bfr[j], acc[i][j], 0, 0, 0);
  }
  int r16 = lane & 15, rg = lane >> 4;
#pragma unroll
  for (int i = 0; i < 4; ++i)
#pragma unroll
    for (int j = 0; j < 4; ++j) {
      int ccol = n0 + wc * 64 + j * 16 + r16;
      if (ccol < NVOUT) {
        float bs = bias[ccol];
#pragma unroll
        for (int q = 0; q < 4; ++q) {
          int crow = m0 + wr * 64 + i * 16 + rg * 4 + q;  // = l*64+b
          int l = crow >> 6, b = crow & 63;
          C[((size_t)b * NL + l) * NVOUT + ccol] = acc[i][j][q] + bs;
        }
      }
    }
}

// ---------------------------------------------------------------------------
// Pre-gather decoder one-hot input term: Gdec = bih + onehot column.
// ---------------------------------------------------------------------------
__global__ __launch_bounds__(256) void k_pregather(
    const float* __restrict__ Wih, const float* __restrict__ bih,
    const int* __restrict__ gt, float* __restrict__ Gdec) {
  int ib = blockIdx.x;              // i*64+b
  int i = ib >> 6, b = ib & 63;
  int tok = (i > 0) ? gt[b * NL + (i - 1)] : -1;
  for (int g = threadIdx.x; g < G3; g += 256) {
    float v = bih[g];
    if (tok >= 0) v += Wih[(size_t)g * (NH + NVOUT) + NH + tok];
    Gdec[(size_t)ib * G3 + g] = v;
  }
}

// ---------------------------------------------------------------------------
// Encoder scan, weight-stationary MFMA. 8 WGs x 1024 thr; WG handles batches
// b0..b0+7. Wave w owns gate-cols [w*16,w*16+16) of all 3 Whh panels as 24
// bf16x8 B-frags in VGPRs (loaded once). Per step: 8 swizzled ds_read_b128
// A-frags, 24 MFMA, gates on lanes<32, ONE barrier. escore fused.
// NOTE: plain __launch_bounds__(1024) — a min-waves arg caps VGPRs and
// spills the weight fragments (R4: VGPR_Count=64, 2.5x regression).
// ---------------------------------------------------------------------------
__global__ __launch_bounds__(1024) void k_encoder3(
    const float* __restrict__ Gi, const __hip_bfloat16* __restrict__ Wcat,
    const float* __restrict__ bhh, const float* __restrict__ att_w,
    __hip_bfloat16* __restrict__ enchB, float* __restrict__ escoreT) {
  __shared__ float h32[2][8][256];
  __shared__ __hip_bfloat16 hbf[2][16][256];
  int t = threadIdx.x, w = t >> 6, lane = t & 63;
  int b0 = blockIdx.x * 8;
  int row = lane & 15, hi16 = lane >> 4;
  bf16x8 wv[3][8];
#pragma unroll
  for (int f = 0; f < 3; ++f)
#pragma unroll
    for (int kf = 0; kf < 8; ++kf)
      wv[f][kf] = *(const bf16x8*)(Wcat + (((size_t)f * 256 + w * 16 + row) * 256 + kf * 32 + hi16 * 8));
  int c = w * 16 + row;
  bool live = lane < 32;
  float bh[3];
#pragma unroll
  for (int g = 0; g < 3; ++g) bh[g] = bhh[g * 256 + c];
  float aw[4];
#pragma unroll
  for (int q = 0; q < 4; ++q) aw[q] = att_w[256 + lane + q * 64];   // w_enc
  // init: h=0
  for (int e = t; e < 2048; e += 1024) h32[0][e >> 8][e & 255] = 0.f;
  {
    unsigned int* hz = (unsigned int*)&hbf[0][0][0];   // zero both buffers
    for (int e = t; e < 4096; e += 1024) hz[e] = 0u;
  }
  __syncthreads();
  int cur = 0;
  int xr = (row & 7) << 4;
  int abase = row * 512 + hi16 * 16;
  for (int s = 0; s < NS; ++s) {
    float gd[3][4];
    if (live) {
#pragma unroll
      for (int g = 0; g < 3; ++g)
#pragma unroll
        for (int q = 0; q < 4; ++q) {
          int b = hi16 * 4 + q;
          gd[g][q] = Gi[((size_t)(b0 + b) * 64 + s) * G3 + g * 256 + c];
        }
    }
    const char* hb = (const char*)&hbf[cur][0][0];
    bf16x8 ah[8];
#pragma unroll
    for (int kf = 0; kf < 8; ++kf)
      ah[kf] = *(const bf16x8*)(hb + ((abase + kf * 64) ^ xr));
    f32x4 acc[3] = {};
#pragma unroll
    for (int f = 0; f < 3; ++f)
#pragma unroll
      for (int kf = 0; kf < 8; ++kf)
        acc[f] = __builtin_amdgcn_mfma_f32_16x16x32_bf16(ah[kf], wv[f][kf], acc[f], 0, 0, 0);
    if (live) {
      int nxt = cur ^ 1;
      char* hbw = (char*)&hbf[nxt][0][0];
#pragma unroll
      for (int q = 0; q < 4; ++q) {
        int b = hi16 * 4 + q;
        float rr = 1.f / (1.f + __expf(-(gd[0][q] + acc[0][q] + bh[0])));
        float zz = 1.f / (1.f + __expf(-(gd[1][q] + acc[1][q] + bh[1])));
        float nn = tanhf(gd[2][q] + rr * (acc[2][q] + bh[2]));
        float ho = h32[cur][b][c];
        float hn = (1.f - zz) * nn + zz * ho;
        h32[nxt][b][c] = hn;
        *(__hip_bfloat16*)(hbw + ((b * 512 + c * 2) ^ ((b & 7) << 4))) = __float2bfloat16(hn);
        enchB[((size_t)(b0 + b) * 64 + s) * 256 + c] = __float2bfloat16(hn);
      }
    }
    __syncthreads();
    cur ^= 1;
    // escore for step s on just-written h (one wave per batch)
    if (w < 8) {
      float p = h32[cur][w][lane] * aw[0] + h32[cur][w][lane + 64] * aw[1]
              + h32[cur][w][lane + 128] * aw[2] + h32[cur][w][lane + 192] * aw[3];
#pragma unroll
      for (int off = 32; off; off >>= 1) p += __shfl_xor(p, off, 64);
      if (lane == 0) escoreT[(size_t)(b0 + w) * 64 + s] = p;
    }
  }
}

// ---------------------------------------------------------------------------
// Decoder scan, weight-stationary MFMA + LDS-resident encoder state.
// 32 WGs x 1024 thr, 2 batches/WG. Wave w owns 16 cols of 6 panels
// (gi r,z,n from Wih-ctx; gh r,z,n from Whh) = 48 B-frags in VGPRs.
// ench (2 batches x 64 s x 256 j, bf16) staged into LDS ONCE; ctx phase is
// pure LDS. Per step: [gh MFMA + softmax] bar [ctx] bar [gi MFMA + gates] bar.
// ---------------------------------------------------------------------------
__global__ __launch_bounds__(1024) void k_decoder3(
    const float* __restrict__ Gdec, const __hip_bfloat16* __restrict__ Wcat6,
    const float* __restrict__ bhh, const __hip_bfloat16* __restrict__ enchB,
    const float* __restrict__ escoreT, const float* __restrict__ att_w,
    const float* __restrict__ att_b, __hip_bfloat16* __restrict__ dechb) {
  __shared__ __hip_bfloat16 ench_l[2][64][256];   // 64 KB
  __shared__ __hip_bfloat16 hbf[2][16][256];      // 16 KB
  __shared__ __hip_bfloat16 ctxbf[16][256];       // 8 KB
  __shared__ float h32[2][2][256];                // 4 KB
  __shared__ float wts[2][64];
  int t = threadIdx.x, w = t >> 6, lane = t & 63;
  int b0 = blockIdx.x * 2;
  int row = lane & 15, hi16 = lane >> 4;
  bf16x8 wv[6][8];
#pragma unroll
  for (int f = 0; f < 6; ++f)
#pragma unroll
    for (int kf = 0; kf < 8; ++kf)
      wv[f][kf] = *(const bf16x8*)(Wcat6 + (((size_t)f * 256 + w * 16 + row) * 256 + kf * 32 + hi16 * 8));
  int c = w * 16 + row;
  float bh[3];
#pragma unroll
  for (int g = 0; g < 3; ++g) bh[g] = bhh[g * 256 + c];
  float aw[4];
#pragma unroll
  for (int q = 0; q < 4; ++q) aw[q] = att_w[lane + q * 64];         // w_dec
  float attb = att_b[0];
  // stage ench (2 batches, bf16, linear) + zero hbf/ctxbf
  {
    const unsigned int* eg = (const unsigned int*)(enchB + (size_t)b0 * 64 * 256);
    unsigned int* el = (unsigned int*)&ench_l[0][0][0];
    for (int e = t; e < 16384; e += 1024) el[e] = eg[e];
    unsigned int* hz = (unsigned int*)&hbf[0][0][0];
    for (int e = t; e < 4096; e += 1024) hz[e] = 0u;
    unsigned int* cz = (unsigned int*)&ctxbf[0][0];
    for (int e = t; e < 2048; e += 1024) cz[e] = 0u;
  }
  __syncthreads();
  // h0 = enc h at s=63 (from LDS copy)
  if (t < 512) {
    int bl = t >> 8, j = t & 255;
    float v = __bfloat162float(ench_l[bl][63][j]);
    h32[0][bl][j] = v;
    *(__hip_bfloat16*)((char*)&hbf[0][0][0] + ((bl * 512 + j * 2) ^ (bl << 4))) = __float2bfloat16(v);
  }
  __syncthreads();
  int cur = 0;
  int xr = (row & 7) << 4;
  int abase = row * 512 + hi16 * 16;
  for (int i = 0; i < NL; ++i) {
    // Gdec loads issue first (latency hides under MFMA/softmax)
    float gd[3][2];
    if (hi16 == 0) {
#pragma unroll
      for (int g = 0; g < 3; ++g)
#pragma unroll
        for (int q = 0; q < 2; ++q)
          gd[g][q] = Gdec[((size_t)i * 64 + b0 + q) * G3 + g * 256 + c];
    }
    // phase 1: gh = h @ Whh^T (frags 3..5) + softmax (waves 0,1)
    const char* hb = (const char*)&hbf[cur][0][0];
    bf16x8 ah[8];
#pragma unroll
    for (int kf = 0; kf < 8; ++kf)
      ah[kf] = *(const bf16x8*)(hb + ((abase + kf * 64) ^ xr));
    f32x4 acch[3] = {};
#pragma unroll
    for (int f = 0; f < 3; ++f)
#pragma unroll
      for (int kf = 0; kf < 8; ++kf)
        acch[f] = __builtin_amdgcn_mfma_f32_16x16x32_bf16(ah[kf], wv[3 + f][kf], acch[f], 0, 0, 0);
    if (w < 2) {
      float p = h32[cur][w][lane] * aw[0] + h32[cur][w][lane + 64] * aw[1]
              + h32[cur][w][lane + 128] * aw[2] + h32[cur][w][lane + 192] * aw[3];
#pragma unroll
      for (int off = 32; off; off >>= 1) p += __shfl_xor(p, off, 64);
      float lg = fmaxf(escoreT[(size_t)(b0 + w) * 64 + lane] + p + attb, 0.f);
      float mx = lg;
#pragma unroll
      for (int off = 32; off; off >>= 1) mx = fmaxf(mx, __shfl_xor(mx, off, 64));
      float e = __expf(lg - mx);
      float sm = e;
#pragma unroll
      for (int off = 32; off; off >>= 1) sm += __shfl_xor(sm, off, 64);
      wts[w][lane] = e / sm;
    }
    __syncthreads();
    // phase 2: ctx[b][j] = sum_s wts[b][s] * ench_l[b][s][j]  (LDS only)
    if (t < 256) {
      int bl = t >> 7, jp = t & 127;   // j-pair (u32 of 2 bf16)
      const unsigned int* eb = (const unsigned int*)&ench_l[bl][0][0];
      float cx = 0.f, cy = 0.f;
#pragma unroll 8
      for (int s_ = 0; s_ < NS; ++s_) {
        unsigned int u = eb[s_ * 128 + jp];
        float wt = wts[bl][s_];
        cx = fmaf(wt, __uint_as_float(u << 16), cx);
        cy = fmaf(wt, __uint_as_float(u & 0xffff0000u), cy);
      }
      unsigned int uo = f2bf(cx) | (f2bf(cy) << 16);
      *(unsigned int*)((char*)&ctxbf[0][0] + ((bl * 512 + jp * 4) ^ (bl << 4))) = uo;
    }
    __syncthreads();
    // phase 3: gi = ctx @ Wih^T (frags 0..2) + gates + h update
    const char* cb = (const char*)&ctxbf[0][0];
    bf16x8 ac[8];
#pragma unroll
    for (int kf = 0; kf < 8; ++kf)
      ac[kf] = *(const bf16x8*)(cb + ((abase + kf * 64) ^ xr));
    f32x4 acci[3] = {};
#pragma unroll
    for (int f = 0; f < 3; ++f)
#pragma unroll
      for (int kf = 0; kf < 8; ++kf)
        acci[f] = __builtin_amdgcn_mfma_f32_16x16x32_bf16(ac[kf], wv[f][kf], acci[f], 0, 0, 0);
    if (hi16 == 0) {
      int nxt = cur ^ 1;
      char* hbw = (char*)&hbf[nxt][0][0];
#pragma unroll
      for (int q = 0; q < 2; ++q) {     // C row q = batch q (rows 2+ garbage)
        float rr = 1.f / (1.f + __expf(-(gd[0][q] + acci[0][q] + acch[0][q] + bh[0])));
        float zz = 1.f / (1.f + __expf(-(gd[1][q] + acci[1][q] + acch[1][q] + bh[1])));
        float nn = tanhf(gd[2][q] + acci[2][q] + rr * (acch[2][q] + bh[2]));
        float ho = h32[cur][q][c];
        float hn = (1.f - zz) * nn + zz * ho;
        h32[nxt][q][c] = hn;
        *(__hip_bfloat16*)(hbw + ((q * 512 + c * 2) ^ (q << 4))) = __float2bfloat16(hn);
        dechb[((size_t)i * 64 + b0 + q) * 256 + c] = __float2bfloat16(hn);
      }
    }
    __syncthreads();
    cur ^= 1;
  }
}

// In-place row log-softmax over VOUT (one WG per (b,l) row).
__global__ __launch_bounds__(256) void k_logsoftmax(float* __restrict__ out) {
  float* x = out + (size_t)blockIdx.x * NVOUT;
  __shared__ float red[256];
  int t = threadIdx.x;
  float mx = -1e30f;
  for (int v = t; v < NVOUT; v += 256) mx = fmaxf(mx, x[v]);
  red[t] = mx; __syncthreads();
  for (int off = 128; off; off >>= 1) {
    if (t < off) red[t] = fmaxf(red[t], red[t + off]);
    __syncthreads();
  }
  mx = red[0]; __syncthreads();
  float sm = 0.f;
  for (int v = t; v < NVOUT; v += 256) sm += __expf(x[v] - mx);
  red[t] = sm; __syncthreads();
  for (int off = 128; off; off >>= 1) {
    if (t < off) red[t] += red[t + off];
    __syncthreads();
  }
  float lse = mx + logf(red[0]);
  for (int v = t; v < NVOUT; v += 256) x[v] -= lse;
}

// ---------------------------------------------------------------------------
extern "C" void kernel_launch(void* const* d_in, const int* in_sizes, int n_in,
                              void* d_out, int out_size, void* d_ws, size_t ws_size,
                              hipStream_t stream) {
  const float* X        = (const float*)d_in[0];
  const int*   gt       = (const int*)  d_in[1];
  const float* enc_Wih  = (const float*)d_in[2];
  const float* enc_Whh  = (const float*)d_in[3];
  const float* enc_bih  = (const float*)d_in[4];
  const float* enc_bhh  = (const float*)d_in[5];
  const float* att_w    = (const float*)d_in[6];
  const float* att_b    = (const float*)d_in[7];
  const float* dec_Wih  = (const float*)d_in[8];
  const float* dec_Whh  = (const float*)d_in[9];
  const float* dec_bih  = (const float*)d_in[10];
  const float* dec_bhh  = (const float*)d_in[11];
  const float* out_W    = (const float*)d_in[12];
  const float* out_b    = (const float*)d_in[13];
  float* out = (float*)d_out;

  // workspace carve-up
  float* p = (float*)d_ws;
  float* Gienc  = p; p += NS * NB * G3;          // [b*64+s][768] fp32
  float* Gdec   = p; p += NL * NB * G3;          // [i*64+b][768] fp32
  float* escoreT = p; p += NB * NS;              // [b][s] fp32
  __hip_bfloat16* q = (__hip_bfloat16*)p;
  __hip_bfloat16* enchBb = q; q += (size_t)NB * NS * NH;   // [b][s][j] bf16
  __hip_bfloat16* Wcat_e = q; q += (size_t)3 * 256 * 256;  // enc Whh r,z,n
  __hip_bfloat16* Wcat_d = q; q += (size_t)6 * 256 * 256;  // dec Wih(ctx)+Whh
  __hip_bfloat16* Xb     = q; q += (size_t)4096 * KP1;
  __hip_bfloat16* Wencb  = q; q += (size_t)G3 * KP1;
  __hip_bfloat16* Woutb  = q; q += (size_t)NOUTP * NH;
  __hip_bfloat16* dechb  = q; q += (size_t)NL * NB * NH;

  // prep (independent)
  k_cvt_pad<<<4096, 256, 0, stream>>>(X, Xb, 4096, NVIN, KP1);
  k_cvt_pad<<<G3, 256, 0, stream>>>(enc_Wih, Wencb, G3, NVIN, KP1);
  k_cvt_pad<<<NOUTP, 256, 0, stream>>>(out_W, Woutb, NVOUT, NH, NH);
  k_wpack<<<768, 256, 0, stream>>>(enc_Whh, NH, enc_Whh, NH, Wcat_e, 3 * 65536);
  k_wpack<<<1536, 256, 0, stream>>>(dec_Wih, NH + NVOUT, dec_Whh, NH, Wcat_d, 6 * 65536);
  k_pregather<<<NL * NB, 256, 0, stream>>>(dec_Wih, dec_bih, gt, Gdec);

  k_gemm_enc_mfma<<<dim3(6, 32), 256, 0, stream>>>(Xb, Wencb, enc_bih, Gienc);
  k_encoder3<<<8, 1024, 0, stream>>>(Gienc, Wcat_e, enc_bhh, att_w, enchBb, escoreT);
  k_decoder3<<<32, 1024, 0, stream>>>(Gdec, Wcat_d, dec_bhh, enchBb, escoreT,
                                      att_w, att_b, dechb);
  k_gemm_out_mfma<<<dim3(79, 32), 256, 0, stream>>>(dechb, Woutb, out_b, out);
  k_logsoftmax<<<NB * NL, 256, 0, stream>>>(out);
}

// Round 6
// 1086.701 us; speedup vs baseline: 2.4821x; 1.9186x over previous
//
#include <hip/hip_runtime.h>
#include <hip/hip_bf16.h>
#include <math.h>

// Problem dims (fixed by the reference)
#define NB 64      // batch
#define NS 64      // encoder steps
#define NL 64      // decoder steps
#define NH 256     // hidden
#define G3 768     // 3*NH (gates r,z,n)
#define NVIN 10000
#define NVOUT 10000
#define KP1 10016   // NVIN padded to multiple of 32 (BK) for enc GEMM
#define NOUTP 10112 // NVOUT padded to multiple of 128 (BN) for out GEMM

typedef __attribute__((ext_vector_type(8))) short bf16x8;  // 8 bf16 (4 VGPRs)
typedef __attribute__((ext_vector_type(4))) float f32x4;   // MFMA accumulator

// async global->LDS, 16B per lane (dest must be wave-uniform base + lane*16)
__device__ __forceinline__ void gld_lds16(const __hip_bfloat16* g, __hip_bfloat16* l) {
  __builtin_amdgcn_global_load_lds(
      (const __attribute__((address_space(1))) unsigned int*)(const void*)g,
      (__attribute__((address_space(3))) unsigned int*)(void*)l, 16, 0, 0);
}

__device__ __forceinline__ unsigned int f2bf(float f) {  // RNE fp32->bf16 bits
  unsigned int u = __float_as_uint(f);
  return (u + 0x7fff + ((u >> 16) & 1)) >> 16;
}

// ---------------------------------------------------------------------------
// fp32 -> bf16 row-wise convert with row/col zero-padding.
// ---------------------------------------------------------------------------
__global__ __launch_bounds__(256) void k_cvt_pad(
    const float* __restrict__ in, __hip_bfloat16* __restrict__ out,
    int in_rows, int in_cols, int out_cols) {
  int r = blockIdx.x;
  const float* src = in + (size_t)r * in_cols;
  __hip_bfloat16* dst = out + (size_t)r * out_cols;
  bool live = r < in_rows;
  for (int c = threadIdx.x * 4; c < out_cols; c += 1024) {
    __hip_bfloat16 v[4];
    if (live && c < in_cols) {
      float4 f = *(const float4*)(src + c);
      v[0] = __float2bfloat16(f.x); v[1] = __float2bfloat16(f.y);
      v[2] = __float2bfloat16(f.z); v[3] = __float2bfloat16(f.w);
    } else {
      v[0] = v[1] = v[2] = v[3] = __float2bfloat16(0.f);
    }
    *(ushort4*)(dst + c) = *(const ushort4*)v;
  }
}

// ---------------------------------------------------------------------------
// Pack recurrent weights to bf16 Wcat[f][c][k]: f<3 from A (gate f, stride
// strideA), f>=3 from B (gate f-3, stride strideB). c,k in [0,256).
// ---------------------------------------------------------------------------
__global__ __launch_bounds__(256) void k_wpack(
    const float* __restrict__ srcA, int strideA,
    const float* __restrict__ srcB, int strideB,
    __hip_bfloat16* __restrict__ out, int total) {
  int idx = blockIdx.x * 256 + threadIdx.x;
  if (idx >= total) return;
  int k = idx & 255, c = (idx >> 8) & 255, f = idx >> 16;
  float v = (f < 3) ? srcA[(size_t)(f * 256 + c) * strideA + k]
                    : srcB[(size_t)((f - 3) * 256 + c) * strideB + k];
  out[idx] = __float2bfloat16(v);
}

// ---------------------------------------------------------------------------
// MFMA GEMM (NT): C[m][n] = sum_k A[m][k]*B[n][k] + bias[n]
// A [4096][KP1] bf16 (row = b*64+s, X order), B [768][KP1] bf16.
// ---------------------------------------------------------------------------
__global__ __launch_bounds__(256) void k_gemm_enc_mfma(
    const __hip_bfloat16* __restrict__ A, const __hip_bfloat16* __restrict__ B,
    const float* __restrict__ bias, float* __restrict__ C) {
  __shared__ __hip_bfloat16 As[128][32];
  __shared__ __hip_bfloat16 Bs[128][32];
  int t = threadIdx.x;
  int wid = t >> 6, lane = t & 63;
  int m0 = blockIdx.y * 128, n0 = blockIdx.x * 128;
  int wr = wid >> 1, wc = wid & 1;
  f32x4 acc[4][4] = {};
  for (int k0 = 0; k0 < KP1; k0 += 32) {
    __syncthreads();
#pragma unroll
    for (int is = 0; is < 2; ++is) {
      int off = is * 4096 + wid * 1024 + lane * 16;
      int r = off >> 6, cb = (off & 63) >> 1;
      gld_lds16(A + (size_t)(m0 + r) * KP1 + k0 + cb, &As[r][cb]);
      gld_lds16(B + (size_t)(n0 + r) * KP1 + k0 + cb, &Bs[r][cb]);
    }
    __syncthreads();
    int r16 = lane & 15, kb = (lane >> 4) * 8;
    bf16x8 af[4], bfr[4];
#pragma unroll
    for (int i = 0; i < 4; ++i) {
      af[i]  = *(const bf16x8*)&As[wr * 64 + i * 16 + r16][kb];
      bfr[i] = *(const bf16x8*)&Bs[wc * 64 + i * 16 + r16][kb];
    }
#pragma unroll
    for (int i = 0; i < 4; ++i)
#pragma unroll
      for (int j = 0; j < 4; ++j)
        acc[i][j] = __builtin_amdgcn_mfma_f32_16x16x32_bf16(af[i], bfr[j], acc[i][j], 0, 0, 0);
  }
  int r16 = lane & 15, rg = lane >> 4;
#pragma unroll
  for (int i = 0; i < 4; ++i)
#pragma unroll
    for (int j = 0; j < 4; ++j) {
      int ccol = n0 + wc * 64 + j * 16 + r16;
      float bs = bias[ccol];
#pragma unroll
      for (int q = 0; q < 4; ++q) {
        int crow = m0 + wr * 64 + i * 16 + rg * 4 + q;
        C[(size_t)crow * G3 + ccol] = acc[i][j][q] + bs;
      }
    }
}

// ---------------------------------------------------------------------------
// MFMA GEMM out: A dec_h bf16 [4096][256] (row = l*64+b), B out_W bf16
// [10112][256] zero-padded. C row (b*NL+l), col guard < NVOUT.
// ---------------------------------------------------------------------------
__global__ __launch_bounds__(256) void k_gemm_out_mfma(
    const __hip_bfloat16* __restrict__ A, const __hip_bfloat16* __restrict__ B,
    const float* __restrict__ bias, float* __restrict__ C) {
  __shared__ __hip_bfloat16 As[128][32];
  __shared__ __hip_bfloat16 Bs[128][32];
  int t = threadIdx.x;
  int wid = t >> 6, lane = t & 63;
  int m0 = blockIdx.y * 128, n0 = blockIdx.x * 128;
  int wr = wid >> 1, wc = wid & 1;
  f32x4 acc[4][4] = {};
  for (int k0 = 0; k0 < NH; k0 += 32) {
    __syncthreads();
#pragma unroll
    for (int is = 0; is < 2; ++is) {
      int off = is * 4096 + wid * 1024 + lane * 16;
      int r = off >> 6, cb = (off & 63) >> 1;
      gld_lds16(A + (size_t)(m0 + r) * NH + k0 + cb, &As[r][cb]);
      gld_lds16(B + (size_t)(n0 + r) * NH + k0 + cb, &Bs[r][cb]);
    }
    __syncthreads();
    int r16 = lane & 15, kb = (lane >> 4) * 8;
    bf16x8 af[4], bfr[4];
#pragma unroll
    for (int i = 0; i < 4; ++i) {
      af[i]  = *(const bf16x8*)&As[wr * 64 + i * 16 + r16][kb];
      bfr[i] = *(const bf16x8*)&Bs[wc * 64 + i * 16 + r16][kb];
    }
#pragma unroll
    for (int i = 0; i < 4; ++i)
#pragma unroll
      for (int j = 0; j < 4; ++j)
        acc[i][j] = __builtin_amdgcn_mfma_f32_16x16x32_bf16(af[i], bfr[j], acc[i][j], 0, 0, 0);
  }
  int r16 = lane & 15, rg = lane >> 4;
#pragma unroll
  for (int i = 0; i < 4; ++i)
#pragma unroll
    for (int j = 0; j < 4; ++j) {
      int ccol = n0 + wc * 64 + j * 16 + r16;
      if (ccol < NVOUT) {
        float bs = bias[ccol];
#pragma unroll
        for (int q = 0; q < 4; ++q) {
          int crow = m0 + wr * 64 + i * 16 + rg * 4 + q;  // = l*64+b
          int l = crow >> 6, b = crow & 63;
          C[((size_t)b * NL + l) * NVOUT + ccol] = acc[i][j][q] + bs;
        }
      }
    }
}

// ---------------------------------------------------------------------------
// ENCW GEMM: ENCW[m][n] = sum_k ench[m][k] * Wih_ctx[n][k]  (no bias)
// m = b*64+s (4096), n = gate col (768), K = 256. Output bf16.
// This makes the decoder's gi a per-step weighted sum over s:
//   gi[b,i][c] = sum_s wts[b,i][s] * ENCW[b][s][c]   (linearity of attention)
// ---------------------------------------------------------------------------
__global__ __launch_bounds__(256) void k_gemm_encw(
    const __hip_bfloat16* __restrict__ A, const __hip_bfloat16* __restrict__ B,
    __hip_bfloat16* __restrict__ C) {
  __shared__ __hip_bfloat16 As[128][32];
  __shared__ __hip_bfloat16 Bs[128][32];
  int t = threadIdx.x;
  int wid = t >> 6, lane = t & 63;
  int m0 = blockIdx.y * 128, n0 = blockIdx.x * 128;
  int wr = wid >> 1, wc = wid & 1;
  f32x4 acc[4][4] = {};
  for (int k0 = 0; k0 < NH; k0 += 32) {
    __syncthreads();
#pragma unroll
    for (int is = 0; is < 2; ++is) {
      int off = is * 4096 + wid * 1024 + lane * 16;
      int r = off >> 6, cb = (off & 63) >> 1;
      gld_lds16(A + (size_t)(m0 + r) * NH + k0 + cb, &As[r][cb]);
      gld_lds16(B + (size_t)(n0 + r) * NH + k0 + cb, &Bs[r][cb]);
    }
    __syncthreads();
    int r16 = lane & 15, kb = (lane >> 4) * 8;
    bf16x8 af[4], bfr[4];
#pragma unroll
    for (int i = 0; i < 4; ++i) {
      af[i]  = *(const bf16x8*)&As[wr * 64 + i * 16 + r16][kb];
      bfr[i] = *(const bf16x8*)&Bs[wc * 64 + i * 16 + r16][kb];
    }
#pragma unroll
    for (int i = 0; i < 4; ++i)
#pragma unroll
      for (int j = 0; j < 4; ++j)
        acc[i][j] = __builtin_amdgcn_mfma_f32_16x16x32_bf16(af[i], bfr[j], acc[i][j], 0, 0, 0);
  }
  int r16 = lane & 15, rg = lane >> 4;
#pragma unroll
  for (int i = 0; i < 4; ++i)
#pragma unroll
    for (int j = 0; j < 4; ++j) {
      int ccol = n0 + wc * 64 + j * 16 + r16;
#pragma unroll
      for (int q = 0; q < 4; ++q) {
        int crow = m0 + wr * 64 + i * 16 + rg * 4 + q;
        C[(size_t)crow * G3 + ccol] = __float2bfloat16(acc[i][j][q]);
      }
    }
}

// ---------------------------------------------------------------------------
// Pre-gather decoder one-hot input term: Gdec = bih + onehot column.
// ---------------------------------------------------------------------------
__global__ __launch_bounds__(256) void k_pregather(
    const float* __restrict__ Wih, const float* __restrict__ bih,
    const int* __restrict__ gt, float* __restrict__ Gdec) {
  int ib = blockIdx.x;              // i*64+b
  int i = ib >> 6, b = ib & 63;
  int tok = (i > 0) ? gt[b * NL + (i - 1)] : -1;
  for (int g = threadIdx.x; g < G3; g += 256) {
    float v = bih[g];
    if (tok >= 0) v += Wih[(size_t)g * (NH + NVOUT) + NH + tok];
    Gdec[(size_t)ib * G3 + g] = v;
  }
}

// ---------------------------------------------------------------------------
// Encoder scan: 64 WGs x 512 thr (8 waves = 2/SIMD -> 256 VGPR cap), ONE
// batch per WG. Wave w owns cols [w*32, w*32+32) of all 3 Whh panels =
// 48 bf16x8 B-frags = 192 VGPRs, loaded ONCE (fits under the 256 cap;
// 1024-thr WGs cap at 128 and spill — R4/R5 lesson). Per step: 8 swizzled
// ds_read A-frags (h in row 0, rows 1-15 zero), 48 MFMA, gates on lanes<16,
// 1 barrier; escore by wave 0 overlapping next step.
// ---------------------------------------------------------------------------
__global__ __launch_bounds__(512) void k_encoder4(
    const float* __restrict__ Gi, const __hip_bfloat16* __restrict__ Wcat,
    const float* __restrict__ bhh, const float* __restrict__ att_w,
    __hip_bfloat16* __restrict__ enchB, float* __restrict__ escoreT) {
  __shared__ float h32[2][256];
  __shared__ __hip_bfloat16 hbf[2][16][256];
  int t = threadIdx.x, w = t >> 6, lane = t & 63;
  int b = blockIdx.x;
  int row = lane & 15, hi16 = lane >> 4;
  bf16x8 wv[3][2][8];
#pragma unroll
  for (int f = 0; f < 3; ++f)
#pragma unroll
    for (int fc = 0; fc < 2; ++fc)
#pragma unroll
      for (int kf = 0; kf < 8; ++kf)
        wv[f][fc][kf] = *(const bf16x8*)(Wcat +
            (((size_t)f * 256 + w * 32 + fc * 16 + row) * 256 + kf * 32 + hi16 * 8));
  float aw[4];
#pragma unroll
  for (int q = 0; q < 4; ++q) aw[q] = att_w[256 + lane + q * 64];   // w_enc
  // init: zero h32 + hbf (both buffers)
  h32[t >> 8][t & 255] = 0.f;
  for (int e = t; e < 4096; e += 512) ((unsigned int*)hbf)[e] = 0u;
  __syncthreads();
  int cur = 0;
  int xr = (row & 7) << 4;
  int abase = row * 512 + hi16 * 16;
  for (int s = 0; s < NS; ++s) {
    // Gi loads (lanes 0-15 of each wave), issue early
    float gd[3][2];
    if (hi16 == 0) {
#pragma unroll
      for (int f = 0; f < 3; ++f)
#pragma unroll
        for (int fc = 0; fc < 2; ++fc)
          gd[f][fc] = Gi[((size_t)b * 64 + s) * G3 + f * 256 + w * 32 + fc * 16 + lane];
    }
    const char* hb = (const char*)&hbf[cur][0][0];
    f32x4 acc[3][2] = {};
    bf16x8 ah[4];
#pragma unroll
    for (int half = 0; half < 2; ++half) {
#pragma unroll
      for (int kf = 0; kf < 4; ++kf)
        ah[kf] = *(const bf16x8*)(hb + ((abase + (half * 4 + kf) * 64) ^ xr));
#pragma unroll
      for (int f = 0; f < 3; ++f)
#pragma unroll
        for (int fc = 0; fc < 2; ++fc)
#pragma unroll
          for (int kf = 0; kf < 4; ++kf)
            acc[f][fc] = __builtin_amdgcn_mfma_f32_16x16x32_bf16(
                ah[kf], wv[f][fc][half * 4 + kf], acc[f][fc], 0, 0, 0);
    }
    if (hi16 == 0) {
      int nxt = cur ^ 1;
#pragma unroll
      for (int fc = 0; fc < 2; ++fc) {
        int c = w * 32 + fc * 16 + lane;
        float rr = 1.f / (1.f + __expf(-(gd[0][fc] + acc[0][fc][0] + bhh[c])));
        float zz = 1.f / (1.f + __expf(-(gd[1][fc] + acc[1][fc][0] + bhh[256 + c])));
        float nn = tanhf(gd[2][fc] + rr * (acc[2][fc][0] + bhh[512 + c]));
        float hn = (1.f - zz) * nn + zz * h32[cur][c];
        h32[nxt][c] = hn;
        hbf[nxt][0][c] = __float2bfloat16(hn);
        enchB[((size_t)b * 64 + s) * 256 + c] = __float2bfloat16(hn);
      }
    }
    __syncthreads();
    cur ^= 1;
    // escore for step s on just-written h (wave 0; overlaps next phase A)
    if (w == 0) {
      float p = h32[cur][lane] * aw[0] + h32[cur][lane + 64] * aw[1]
              + h32[cur][lane + 128] * aw[2] + h32[cur][lane + 192] * aw[3];
#pragma unroll
      for (int off = 32; off; off >>= 1) p += __shfl_xor(p, off, 64);
      if (lane == 0) escoreT[(size_t)b * 64 + s] = p;
    }
  }
}

// ---------------------------------------------------------------------------
// Decoder scan: 64 WGs x 512 thr, ONE batch per WG. Whh (3 panels) VGPR-
// resident (192 regs/wave). ENCW batch slice [64 s][768 c] bf16 (98 KB)
// staged into LDS once via global_load_lds; gi = sum_s wts[s]*ENCW[s][c]
// replaces the ctx+gi-GEMV path entirely (linearity). Per step:
// [gh MFMA || softmax] bar [gi weighted sum] bar [gates] bar.
// ---------------------------------------------------------------------------
__global__ __launch_bounds__(512) void k_decoder4(
    const float* __restrict__ Gdec, const __hip_bfloat16* __restrict__ Wcat6,
    const float* __restrict__ bhh, const __hip_bfloat16* __restrict__ enchB,
    const __hip_bfloat16* __restrict__ ENCW, const float* __restrict__ escoreT,
    const float* __restrict__ att_w, const float* __restrict__ att_b,
    __hip_bfloat16* __restrict__ dechb) {
  __shared__ __hip_bfloat16 encw_l[64][G3];   // 96 KB  ([s][c], u32 view [64][384])
  __shared__ __hip_bfloat16 hbf[2][16][256];  // 16 KB
  __shared__ float ghbuf[G3];                 // 3 KB
  __shared__ float gibuf[G3];                 // 3 KB
  __shared__ float h32[2][256];               // 2 KB
  __shared__ float wts[64];
  int t = threadIdx.x, w = t >> 6, lane = t & 63;
  int b = blockIdx.x;
  int row = lane & 15, hi16 = lane >> 4;
  // stage ENCW rows b*64..b*64+63 (linear, 12 x 8KB issues)
  {
    const char* srcb = (const char*)(ENCW + (size_t)b * 64 * G3);
    char* dstb = (char*)&encw_l[0][0];
#pragma unroll
    for (int is = 0; is < 12; ++is) {
      int off = is * 8192 + w * 1024 + lane * 16;
      gld_lds16((const __hip_bfloat16*)(srcb + off), (__hip_bfloat16*)(dstb + off));
    }
  }
  // Whh fragments (panels 3..5 of Wcat6)
  bf16x8 wv[3][2][8];
#pragma unroll
  for (int f = 0; f < 3; ++f)
#pragma unroll
    for (int fc = 0; fc < 2; ++fc)
#pragma unroll
      for (int kf = 0; kf < 8; ++kf)
        wv[f][fc][kf] = *(const bf16x8*)(Wcat6 +
            (((size_t)(3 + f) * 256 + w * 32 + fc * 16 + row) * 256 + kf * 32 + hi16 * 8));
  float aw[4];
#pragma unroll
  for (int q = 0; q < 4; ++q) aw[q] = att_w[lane + q * 64];         // w_dec
  float attb = att_b[0];
  float esc = 0.f;
  if (w == 0) esc = escoreT[(size_t)b * 64 + lane];
  // zero hbf (both buffers)
  for (int e = t; e < 4096; e += 512) ((unsigned int*)hbf)[e] = 0u;
  __syncthreads();                 // drains staging vmcnt + orders zeroing
  // h0 = enc h at s=63
  if (t < 256) {
    float v = __bfloat162float(enchB[((size_t)b * 64 + 63) * 256 + t]);
    h32[0][t] = v;
    hbf[0][0][t] = __float2bfloat16(v);
  }
  __syncthreads();
  int cur = 0;
  int xr = (row & 7) << 4;
  int abase = row * 512 + hi16 * 16;
  for (int i = 0; i < NL; ++i) {
    // Gdec prefetch (threads 0-255; consumed in phase C)
    float gdv0 = 0.f, gdv1 = 0.f, gdv2 = 0.f;
    if (t < 256) {
      const float* gp = Gdec + ((size_t)i * 64 + b) * G3 + t;
      gdv0 = gp[0]; gdv1 = gp[256]; gdv2 = gp[512];
    }
    // phase A: gh = h @ Whh^T (MFMA) || softmax (wave 0)
    const char* hb = (const char*)&hbf[cur][0][0];
    f32x4 acc[3][2] = {};
    bf16x8 ah[4];
#pragma unroll
    for (int half = 0; half < 2; ++half) {
#pragma unroll
      for (int kf = 0; kf < 4; ++kf)
        ah[kf] = *(const bf16x8*)(hb + ((abase + (half * 4 + kf) * 64) ^ xr));
#pragma unroll
      for (int f = 0; f < 3; ++f)
#pragma unroll
        for (int fc = 0; fc < 2; ++fc)
#pragma unroll
          for (int kf = 0; kf < 4; ++kf)
            acc[f][fc] = __builtin_amdgcn_mfma_f32_16x16x32_bf16(
                ah[kf], wv[f][fc][half * 4 + kf], acc[f][fc], 0, 0, 0);
    }
    if (hi16 == 0) {
#pragma unroll
      for (int f = 0; f < 3; ++f)
#pragma unroll
        for (int fc = 0; fc < 2; ++fc)
          ghbuf[f * 256 + w * 32 + fc * 16 + lane] = acc[f][fc][0];
    }
    if (w == 0) {
      float p = h32[cur][lane] * aw[0] + h32[cur][lane + 64] * aw[1]
              + h32[cur][lane + 128] * aw[2] + h32[cur][lane + 192] * aw[3];
#pragma unroll
      for (int off = 32; off; off >>= 1) p += __shfl_xor(p, off, 64);
      float lg = fmaxf(esc + p + attb, 0.f);
      float mx = lg;
#pragma unroll
      for (int off = 32; off; off >>= 1) mx = fmaxf(mx, __shfl_xor(mx, off, 64));
      float e = __expf(lg - mx);
      float sm = e;
#pragma unroll
      for (int off = 32; off; off >>= 1) sm += __shfl_xor(sm, off, 64);
      wts[lane] = e / sm;
    }
    __syncthreads();
    // phase B: gi[c] = sum_s wts[s] * ENCW[s][c]   (pure LDS, conflict-free)
    if (t < 384) {
      const unsigned int* eb = (const unsigned int*)&encw_l[0][0];
      float cx = 0.f, cy = 0.f;
#pragma unroll 8
      for (int s_ = 0; s_ < NS; ++s_) {
        unsigned int u = eb[s_ * 384 + t];
        float wt = wts[s_];
        cx = fmaf(wt, __uint_as_float(u << 16), cx);
        cy = fmaf(wt, __uint_as_float(u & 0xffff0000u), cy);
      }
      *(float2*)&gibuf[2 * t] = make_float2(cx, cy);
    }
    __syncthreads();
    // phase C: gates + h update (threads 0-255)
    if (t < 256) {
      int nxt = cur ^ 1;
      float gir = gibuf[t]       + gdv0;
      float giz = gibuf[256 + t] + gdv1;
      float gin = gibuf[512 + t] + gdv2;
      float rr = 1.f / (1.f + __expf(-(gir + ghbuf[t]       + bhh[t])));
      float zz = 1.f / (1.f + __expf(-(giz + ghbuf[256 + t] + bhh[256 + t])));
      float nn = tanhf(gin + rr * (ghbuf[512 + t] + bhh[512 + t]));
      float hn = (1.f - zz) * nn + zz * h32[cur][t];
      h32[nxt][t] = hn;
      hbf[nxt][0][t] = __float2bfloat16(hn);
      dechb[((size_t)i * 64 + b) * 256 + t] = __float2bfloat16(hn);
    }
    __syncthreads();
    cur ^= 1;
  }
}

// In-place row log-softmax over VOUT (one WG per (b,l) row).
__global__ __launch_bounds__(256) void k_logsoftmax(float* __restrict__ out) {
  float* x = out + (size_t)blockIdx.x * NVOUT;
  __shared__ float red[256];
  int t = threadIdx.x;
  float mx = -1e30f;
  for (int v = t; v < NVOUT; v += 256) mx = fmaxf(mx, x[v]);
  red[t] = mx; __syncthreads();
  for (int off = 128; off; off >>= 1) {
    if (t < off) red[t] = fmaxf(red[t], red[t + off]);
    __syncthreads();
  }
  mx = red[0]; __syncthreads();
  float sm = 0.f;
  for (int v = t; v < NVOUT; v += 256) sm += __expf(x[v] - mx);
  red[t] = sm; __syncthreads();
  for (int off = 128; off; off >>= 1) {
    if (t < off) red[t] += red[t + off];
    __syncthreads();
  }
  float lse = mx + logf(red[0]);
  for (int v = t; v < NVOUT; v += 256) x[v] -= lse;
}

// ---------------------------------------------------------------------------
extern "C" void kernel_launch(void* const* d_in, const int* in_sizes, int n_in,
                              void* d_out, int out_size, void* d_ws, size_t ws_size,
                              hipStream_t stream) {
  const float* X        = (const float*)d_in[0];
  const int*   gt       = (const int*)  d_in[1];
  const float* enc_Wih  = (const float*)d_in[2];
  const float* enc_Whh  = (const float*)d_in[3];
  const float* enc_bih  = (const float*)d_in[4];
  const float* enc_bhh  = (const float*)d_in[5];
  const float* att_w    = (const float*)d_in[6];
  const float* att_b    = (const float*)d_in[7];
  const float* dec_Wih  = (const float*)d_in[8];
  const float* dec_Whh  = (const float*)d_in[9];
  const float* dec_bih  = (const float*)d_in[10];
  const float* dec_bhh  = (const float*)d_in[11];
  const float* out_W    = (const float*)d_in[12];
  const float* out_b    = (const float*)d_in[13];
  float* out = (float*)d_out;

  // workspace carve-up
  float* p = (float*)d_ws;
  float* Gienc  = p; p += NS * NB * G3;          // [b*64+s][768] fp32
  float* Gdec   = p; p += NL * NB * G3;          // [i*64+b][768] fp32
  float* escoreT = p; p += NB * NS;              // [b][s] fp32
  __hip_bfloat16* q = (__hip_bfloat16*)p;
  __hip_bfloat16* enchBb = q; q += (size_t)NB * NS * NH;   // [b][s][j] bf16
  __hip_bfloat16* Wcat_e = q; q += (size_t)3 * 256 * 256;  // enc Whh r,z,n
  __hip_bfloat16* Wcat_d = q; q += (size_t)6 * 256 * 256;  // dec Wih(ctx)+Whh
  __hip_bfloat16* Xb     = q; q += (size_t)4096 * KP1;
  __hip_bfloat16* Wencb  = q; q += (size_t)G3 * KP1;
  __hip_bfloat16* Woutb  = q; q += (size_t)NOUTP * NH;
  __hip_bfloat16* dechb  = q; q += (size_t)NL * NB * NH;
  // ENCW [4096][768] bf16 (6.3 MB) aliases Gienc (12.6 MB, dead after encoder)
  __hip_bfloat16* ENCW   = (__hip_bfloat16*)Gienc;

  // prep (independent)
  k_cvt_pad<<<4096, 256, 0, stream>>>(X, Xb, 4096, NVIN, KP1);
  k_cvt_pad<<<G3, 256, 0, stream>>>(enc_Wih, Wencb, G3, NVIN, KP1);
  k_cvt_pad<<<NOUTP, 256, 0, stream>>>(out_W, Woutb, NVOUT, NH, NH);
  k_wpack<<<768, 256, 0, stream>>>(enc_Whh, NH, enc_Whh, NH, Wcat_e, 3 * 65536);
  k_wpack<<<1536, 256, 0, stream>>>(dec_Wih, NH + NVOUT, dec_Whh, NH, Wcat_d, 6 * 65536);
  k_pregather<<<NL * NB, 256, 0, stream>>>(dec_Wih, dec_bih, gt, Gdec);

  k_gemm_enc_mfma<<<dim3(6, 32), 256, 0, stream>>>(Xb, Wencb, enc_bih, Gienc);
  k_encoder4<<<64, 512, 0, stream>>>(Gienc, Wcat_e, enc_bhh, att_w, enchBb, escoreT);
  // ENCW = ench @ Wih_ctx^T  (overwrites Gienc space — Gienc is consumed)
  k_gemm_encw<<<dim3(6, 32), 256, 0, stream>>>(enchBb, Wcat_d, ENCW);
  k_decoder4<<<64, 512, 0, stream>>>(Gdec, Wcat_d, dec_bhh, enchBb, ENCW,
                                     escoreT, att_w, att_b, dechb);
  k_gemm_out_mfma<<<dim3(79, 32), 256, 0, stream>>>(dechb, Woutb, out_b, out);
  k_logsoftmax<<<NB * NL, 256, 0, stream>>>(out);
}

// Round 7
// 921.531 us; speedup vs baseline: 2.9270x; 1.1792x over previous
//
#include <hip/hip_runtime.h>
#include <hip/hip_bf16.h>
#include <math.h>

// Problem dims (fixed by the reference)
#define NB 64      // batch
#define NS 64      // encoder steps
#define NL 64      // decoder steps
#define NH 256     // hidden
#define G3 768     // 3*NH (gates r,z,n)
#define NVIN 10000
#define NVOUT 10000
#define KP2 10240   // NVIN padded to multiple of 256 (4 splits x 40 x BK=64)
#define NOUTP 10112 // NVOUT padded to multiple of 128 (BN) for out GEMM

typedef __attribute__((ext_vector_type(8))) short bf16x8;  // 8 bf16 (4 VGPRs)
typedef __attribute__((ext_vector_type(4))) float f32x4;   // MFMA accumulator

// async global->LDS, 16B per lane (dest must be wave-uniform base + lane*16)
__device__ __forceinline__ void gld_lds16(const __hip_bfloat16* g, __hip_bfloat16* l) {
  __builtin_amdgcn_global_load_lds(
      (const __attribute__((address_space(1))) unsigned int*)(const void*)g,
      (__attribute__((address_space(3))) unsigned int*)(void*)l, 16, 0, 0);
}

// ---------------------------------------------------------------------------
// fp32 -> bf16 row-wise convert with row/col zero-padding.
// swz=1: permute columns within each 64-elem group by ((row&7)<<3) so that
// linear global_load_lds staging + XOR'd ds_read yields conflict-free LDS
// (T2/m173: swizzle the SOURCE, keep LDS dest linear).
// ---------------------------------------------------------------------------
__global__ __launch_bounds__(256) void k_cvt_pad(
    const float* __restrict__ in, __hip_bfloat16* __restrict__ out,
    int in_rows, int in_cols, int out_cols, int swz) {
  int r = blockIdx.x;
  const float* src = in + (size_t)r * in_cols;
  __hip_bfloat16* dst = out + (size_t)r * out_cols;
  bool live = r < in_rows;
  int sx = swz ? ((r & 7) << 3) : 0;
  for (int c = threadIdx.x * 4; c < out_cols; c += 1024) {
    int cc = (c & ~63) | ((c & 63) ^ sx);   // sx hits bits 3-5 only; c stays 4-aligned
    __hip_bfloat16 v[4];
    if (live && cc + 3 < in_cols) {
      float4 f = *(const float4*)(src + cc);
      v[0] = __float2bfloat16(f.x); v[1] = __float2bfloat16(f.y);
      v[2] = __float2bfloat16(f.z); v[3] = __float2bfloat16(f.w);
    } else {
      v[0] = v[1] = v[2] = v[3] = __float2bfloat16(0.f);
    }
    *(ushort4*)(dst + c) = *(const ushort4*)v;
  }
}

// ---------------------------------------------------------------------------
// Pack recurrent weights to bf16 Wcat[f][c][k]: f<3 from A (gate f, stride
// strideA), f>=3 from B (gate f-3, stride strideB). c,k in [0,256).
// ---------------------------------------------------------------------------
__global__ __launch_bounds__(256) void k_wpack(
    const float* __restrict__ srcA, int strideA,
    const float* __restrict__ srcB, int strideB,
    __hip_bfloat16* __restrict__ out, int total) {
  int idx = blockIdx.x * 256 + threadIdx.x;
  if (idx >= total) return;
  int k = idx & 255, c = (idx >> 8) & 255, f = idx >> 16;
  float v = (f < 3) ? srcA[(size_t)(f * 256 + c) * strideA + k]
                    : srcB[(size_t)((f - 3) * 256 + c) * strideB + k];
  out[idx] = __float2bfloat16(v);
}

// ---------------------------------------------------------------------------
// Enc GEMM, split-K: P[z][m][n] = sum_{k in slice z} A[m][k]*B[n][k]
// A [4096][KP2], B [768][KP2], both bf16 PRE-SWIZZLED (k_cvt_pad swz=1).
// BK=64, 128x128 tile, 4 waves. grid (6, 32, 4); z owns K slice of 2560.
// LDS reads XOR-swizzled -> 8 rows hit 8 distinct 16B slots (2-way residual
// aliasing is free, m136). Partials are reduced (+bias) by k_reduce4.
// ---------------------------------------------------------------------------
__global__ __launch_bounds__(256) void k_gemm_encS(
    const __hip_bfloat16* __restrict__ A, const __hip_bfloat16* __restrict__ B,
    float* __restrict__ P) {
  __shared__ __hip_bfloat16 As[128][64];   // 16 KB, 128B rows
  __shared__ __hip_bfloat16 Bs[128][64];
  int t = threadIdx.x;
  int wid = t >> 6, lane = t & 63;
  int m0 = blockIdx.y * 128, n0 = blockIdx.x * 128;
  int wr = wid >> 1, wc = wid & 1;
  int r16 = lane & 15, hi16 = lane >> 4;
  int xr = (r16 & 7) << 4;
  f32x4 acc[4][4] = {};
  int kbeg = blockIdx.z * 2560;
  for (int ks = 0; ks < 40; ++ks) {
    int k0 = kbeg + ks * 64;
    __syncthreads();
#pragma unroll
    for (int is = 0; is < 4; ++is) {        // 16KB tile = 4 x (256thr x 16B)
      int off = is * 4096 + t * 16;
      int r = off >> 7, e = (off & 127) >> 1;
      gld_lds16(A + (size_t)(m0 + r) * KP2 + k0 + e, &As[r][e]);
      gld_lds16(B + (size_t)(n0 + r) * KP2 + k0 + e, &Bs[r][e]);
    }
    __syncthreads();
    const char* ab = (const char*)As;
    const char* bb = (const char*)Bs;
#pragma unroll
    for (int kk = 0; kk < 2; ++kk) {
      int ko = kk * 64 + hi16 * 16;
      bf16x8 af[4], bfr[4];
#pragma unroll
      for (int i = 0; i < 4; ++i) {
        af[i]  = *(const bf16x8*)(ab + (wr * 64 + i * 16 + r16) * 128 + (ko ^ xr));
        bfr[i] = *(const bf16x8*)(bb + (wc * 64 + i * 16 + r16) * 128 + (ko ^ xr));
      }
#pragma unroll
      for (int i = 0; i < 4; ++i)
#pragma unroll
        for (int j = 0; j < 4; ++j)
          acc[i][j] = __builtin_amdgcn_mfma_f32_16x16x32_bf16(af[i], bfr[j], acc[i][j], 0, 0, 0);
    }
  }
  float* Pz = P + (size_t)blockIdx.z * 4096 * G3;
#pragma unroll
  for (int i = 0; i < 4; ++i)
#pragma unroll
    for (int j = 0; j < 4; ++j) {
      int ccol = n0 + wc * 64 + j * 16 + r16;
#pragma unroll
      for (int q = 0; q < 4; ++q) {
        int crow = m0 + wr * 64 + i * 16 + hi16 * 4 + q;
        Pz[(size_t)crow * G3 + ccol] = acc[i][j][q];
      }
    }
}

// Gienc = P0+P1+P2+P3 + bias  (float4 over 4096x768)
__global__ __launch_bounds__(256) void k_reduce4(
    const float4* __restrict__ P, const float* __restrict__ bias,
    float4* __restrict__ G) {
  int idx = blockIdx.x * 256 + threadIdx.x;      // [0, 786432)
  float4 a = P[idx], b = P[idx + 786432], c = P[idx + 2 * 786432],
         d = P[idx + 3 * 786432];
  float4 bs = *(const float4*)(bias + (idx % 192) * 4);
  float4 o;
  o.x = a.x + b.x + c.x + d.x + bs.x;
  o.y = a.y + b.y + c.y + d.y + bs.y;
  o.z = a.z + b.z + c.z + d.z + bs.z;
  o.w = a.w + b.w + c.w + d.w + bs.w;
  G[idx] = o;
}

// ---------------------------------------------------------------------------
// Out GEMM: A dechb [4096][256] (row = l*64+b, PRE-SWIZZLED cols), B Woutb
// [10112][256] (zero-padded rows, PRE-SWIZZLED). BK=64 + XOR'd reads.
// C row (b*NL+l), col guard < NVOUT, + bias.
// ---------------------------------------------------------------------------
__global__ __launch_bounds__(256) void k_gemm_outS(
    const __hip_bfloat16* __restrict__ A, const __hip_bfloat16* __restrict__ B,
    const float* __restrict__ bias, float* __restrict__ C) {
  __shared__ __hip_bfloat16 As[128][64];
  __shared__ __hip_bfloat16 Bs[128][64];
  int t = threadIdx.x;
  int wid = t >> 6, lane = t & 63;
  int m0 = blockIdx.y * 128, n0 = blockIdx.x * 128;
  int wr = wid >> 1, wc = wid & 1;
  int r16 = lane & 15, hi16 = lane >> 4;
  int xr = (r16 & 7) << 4;
  f32x4 acc[4][4] = {};
  for (int k0 = 0; k0 < NH; k0 += 64) {
    __syncthreads();
#pragma unroll
    for (int is = 0; is < 4; ++is) {
      int off = is * 4096 + t * 16;
      int r = off >> 7, e = (off & 127) >> 1;
      gld_lds16(A + (size_t)(m0 + r) * NH + k0 + e, &As[r][e]);
      gld_lds16(B + (size_t)(n0 + r) * NH + k0 + e, &Bs[r][e]);
    }
    __syncthreads();
    const char* ab = (const char*)As;
    const char* bb = (const char*)Bs;
#pragma unroll
    for (int kk = 0; kk < 2; ++kk) {
      int ko = kk * 64 + hi16 * 16;
      bf16x8 af[4], bfr[4];
#pragma unroll
      for (int i = 0; i < 4; ++i) {
        af[i]  = *(const bf16x8*)(ab + (wr * 64 + i * 16 + r16) * 128 + (ko ^ xr));
        bfr[i] = *(const bf16x8*)(bb + (wc * 64 + i * 16 + r16) * 128 + (ko ^ xr));
      }
#pragma unroll
      for (int i = 0; i < 4; ++i)
#pragma unroll
        for (int j = 0; j < 4; ++j)
          acc[i][j] = __builtin_amdgcn_mfma_f32_16x16x32_bf16(af[i], bfr[j], acc[i][j], 0, 0, 0);
    }
  }
#pragma unroll
  for (int i = 0; i < 4; ++i)
#pragma unroll
    for (int j = 0; j < 4; ++j) {
      int ccol = n0 + wc * 64 + j * 16 + r16;
      if (ccol < NVOUT) {
        float bs = bias[ccol];
#pragma unroll
        for (int q = 0; q < 4; ++q) {
          int crow = m0 + wr * 64 + i * 16 + hi16 * 4 + q;  // = l*64+b
          int l = crow >> 6, b = crow & 63;
          C[((size_t)b * NL + l) * NVOUT + ccol] = acc[i][j][q] + bs;
        }
      }
    }
}

// ---------------------------------------------------------------------------
// ENCW GEMM: ENCW[m][n] = sum_k ench[m][k] * Wih_ctx[n][k]  (no bias)
// m = b*64+s (4096), n = gate col (768), K = 256. Output bf16.
// ---------------------------------------------------------------------------
__global__ __launch_bounds__(256) void k_gemm_encw(
    const __hip_bfloat16* __restrict__ A, const __hip_bfloat16* __restrict__ B,
    __hip_bfloat16* __restrict__ C) {
  __shared__ __hip_bfloat16 As[128][32];
  __shared__ __hip_bfloat16 Bs[128][32];
  int t = threadIdx.x;
  int wid = t >> 6, lane = t & 63;
  int m0 = blockIdx.y * 128, n0 = blockIdx.x * 128;
  int wr = wid >> 1, wc = wid & 1;
  f32x4 acc[4][4] = {};
  for (int k0 = 0; k0 < NH; k0 += 32) {
    __syncthreads();
#pragma unroll
    for (int is = 0; is < 2; ++is) {
      int off = is * 4096 + wid * 1024 + lane * 16;
      int r = off >> 6, cb = (off & 63) >> 1;
      gld_lds16(A + (size_t)(m0 + r) * NH + k0 + cb, &As[r][cb]);
      gld_lds16(B + (size_t)(n0 + r) * NH + k0 + cb, &Bs[r][cb]);
    }
    __syncthreads();
    int r16 = lane & 15, kb = (lane >> 4) * 8;
    bf16x8 af[4], bfr[4];
#pragma unroll
    for (int i = 0; i < 4; ++i) {
      af[i]  = *(const bf16x8*)&As[wr * 64 + i * 16 + r16][kb];
      bfr[i] = *(const bf16x8*)&Bs[wc * 64 + i * 16 + r16][kb];
    }
#pragma unroll
    for (int i = 0; i < 4; ++i)
#pragma unroll
      for (int j = 0; j < 4; ++j)
        acc[i][j] = __builtin_amdgcn_mfma_f32_16x16x32_bf16(af[i], bfr[j], acc[i][j], 0, 0, 0);
  }
  int r16 = lane & 15, rg = lane >> 4;
#pragma unroll
  for (int i = 0; i < 4; ++i)
#pragma unroll
    for (int j = 0; j < 4; ++j) {
      int ccol = n0 + wc * 64 + j * 16 + r16;
#pragma unroll
      for (int q = 0; q < 4; ++q) {
        int crow = m0 + wr * 64 + i * 16 + rg * 4 + q;
        C[(size_t)crow * G3 + ccol] = __float2bfloat16(acc[i][j][q]);
      }
    }
}

// ---------------------------------------------------------------------------
// Pre-gather decoder one-hot input term: Gdec = bih + onehot column.
// ---------------------------------------------------------------------------
__global__ __launch_bounds__(256) void k_pregather(
    const float* __restrict__ Wih, const float* __restrict__ bih,
    const int* __restrict__ gt, float* __restrict__ Gdec) {
  int ib = blockIdx.x;              // i*64+b
  int i = ib >> 6, b = ib & 63;
  int tok = (i > 0) ? gt[b * NL + (i - 1)] : -1;
  for (int g = threadIdx.x; g < G3; g += 256) {
    float v = bih[g];
    if (tok >= 0) v += Wih[(size_t)g * (NH + NVOUT) + NH + tok];
    Gdec[(size_t)ib * G3 + g] = v;
  }
}

// ---------------------------------------------------------------------------
// Encoder scan: 64 WGs x 512 thr (8 waves = 2/SIMD -> 256 VGPR cap), ONE
// batch per WG. Wave w owns cols [w*32, w*32+32) of all 3 Whh panels =
// 48 bf16x8 B-frags = 192 VGPRs, loaded ONCE. (1024-thr WGs cap at 128 VGPR
// and spill — R4/R5 lesson.)
// ---------------------------------------------------------------------------
__global__ __launch_bounds__(512) void k_encoder4(
    const float* __restrict__ Gi, const __hip_bfloat16* __restrict__ Wcat,
    const float* __restrict__ bhh, const float* __restrict__ att_w,
    __hip_bfloat16* __restrict__ enchB, float* __restrict__ escoreT) {
  __shared__ float h32[2][256];
  __shared__ __hip_bfloat16 hbf[2][16][256];
  int t = threadIdx.x, w = t >> 6, lane = t & 63;
  int b = blockIdx.x;
  int row = lane & 15, hi16 = lane >> 4;
  bf16x8 wv[3][2][8];
#pragma unroll
  for (int f = 0; f < 3; ++f)
#pragma unroll
    for (int fc = 0; fc < 2; ++fc)
#pragma unroll
      for (int kf = 0; kf < 8; ++kf)
        wv[f][fc][kf] = *(const bf16x8*)(Wcat +
            (((size_t)f * 256 + w * 32 + fc * 16 + row) * 256 + kf * 32 + hi16 * 8));
  float aw[4];
#pragma unroll
  for (int q = 0; q < 4; ++q) aw[q] = att_w[256 + lane + q * 64];   // w_enc
  h32[t >> 8][t & 255] = 0.f;
  for (int e = t; e < 4096; e += 512) ((unsigned int*)hbf)[e] = 0u;
  __syncthreads();
  int cur = 0;
  int xr = (row & 7) << 4;
  int abase = row * 512 + hi16 * 16;
  for (int s = 0; s < NS; ++s) {
    float gd[3][2];
    if (hi16 == 0) {
#pragma unroll
      for (int f = 0; f < 3; ++f)
#pragma unroll
        for (int fc = 0; fc < 2; ++fc)
          gd[f][fc] = Gi[((size_t)b * 64 + s) * G3 + f * 256 + w * 32 + fc * 16 + lane];
    }
    const char* hb = (const char*)&hbf[cur][0][0];
    f32x4 acc[3][2] = {};
    bf16x8 ah[4];
#pragma unroll
    for (int half = 0; half < 2; ++half) {
#pragma unroll
      for (int kf = 0; kf < 4; ++kf)
        ah[kf] = *(const bf16x8*)(hb + ((abase + (half * 4 + kf) * 64) ^ xr));
#pragma unroll
      for (int f = 0; f < 3; ++f)
#pragma unroll
        for (int fc = 0; fc < 2; ++fc)
#pragma unroll
          for (int kf = 0; kf < 4; ++kf)
            acc[f][fc] = __builtin_amdgcn_mfma_f32_16x16x32_bf16(
                ah[kf], wv[f][fc][half * 4 + kf], acc[f][fc], 0, 0, 0);
    }
    if (hi16 == 0) {
      int nxt = cur ^ 1;
#pragma unroll
      for (int fc = 0; fc < 2; ++fc) {
        int c = w * 32 + fc * 16 + lane;
        float rr = 1.f / (1.f + __expf(-(gd[0][fc] + acc[0][fc][0] + bhh[c])));
        float zz = 1.f / (1.f + __expf(-(gd[1][fc] + acc[1][fc][0] + bhh[256 + c])));
        float nn = tanhf(gd[2][fc] + rr * (acc[2][fc][0] + bhh[512 + c]));
        float hn = (1.f - zz) * nn + zz * h32[cur][c];
        h32[nxt][c] = hn;
        hbf[nxt][0][c] = __float2bfloat16(hn);
        enchB[((size_t)b * 64 + s) * 256 + c] = __float2bfloat16(hn);
      }
    }
    __syncthreads();
    cur ^= 1;
    if (w == 0) {
      float p = h32[cur][lane] * aw[0] + h32[cur][lane + 64] * aw[1]
              + h32[cur][lane + 128] * aw[2] + h32[cur][lane + 192] * aw[3];
#pragma unroll
      for (int off = 32; off; off >>= 1) p += __shfl_xor(p, off, 64);
      if (lane == 0) escoreT[(size_t)b * 64 + s] = p;
    }
  }
}

// ---------------------------------------------------------------------------
// Decoder scan: 64 WGs x 512 thr, ONE batch per WG. Whh VGPR-resident.
// ENCW batch slice staged to LDS once; gi = sum_s wts[s]*ENCW[s][c].
// dechb written with PRE-SWIZZLED columns for k_gemm_outS.
// ---------------------------------------------------------------------------
__global__ __launch_bounds__(512) void k_decoder4(
    const float* __restrict__ Gdec, const __hip_bfloat16* __restrict__ Wcat6,
    const float* __restrict__ bhh, const __hip_bfloat16* __restrict__ enchB,
    const __hip_bfloat16* __restrict__ ENCW, const float* __restrict__ escoreT,
    const float* __restrict__ att_w, const float* __restrict__ att_b,
    __hip_bfloat16* __restrict__ dechb) {
  __shared__ __hip_bfloat16 encw_l[64][G3];   // 96 KB
  __shared__ __hip_bfloat16 hbf[2][16][256];  // 16 KB
  __shared__ float ghbuf[G3];
  __shared__ float gibuf[G3];
  __shared__ float h32[2][256];
  __shared__ float wts[64];
  int t = threadIdx.x, w = t >> 6, lane = t & 63;
  int b = blockIdx.x;
  int row = lane & 15, hi16 = lane >> 4;
  {
    const char* srcb = (const char*)(ENCW + (size_t)b * 64 * G3);
    char* dstb = (char*)&encw_l[0][0];
#pragma unroll
    for (int is = 0; is < 12; ++is) {
      int off = is * 8192 + w * 1024 + lane * 16;
      gld_lds16((const __hip_bfloat16*)(srcb + off), (__hip_bfloat16*)(dstb + off));
    }
  }
  bf16x8 wv[3][2][8];
#pragma unroll
  for (int f = 0; f < 3; ++f)
#pragma unroll
    for (int fc = 0; fc < 2; ++fc)
#pragma unroll
      for (int kf = 0; kf < 8; ++kf)
        wv[f][fc][kf] = *(const bf16x8*)(Wcat6 +
            (((size_t)(3 + f) * 256 + w * 32 + fc * 16 + row) * 256 + kf * 32 + hi16 * 8));
  float aw[4];
#pragma unroll
  for (int q = 0; q < 4; ++q) aw[q] = att_w[lane + q * 64];         // w_dec
  float attb = att_b[0];
  float esc = 0.f;
  if (w == 0) esc = escoreT[(size_t)b * 64 + lane];
  for (int e = t; e < 4096; e += 512) ((unsigned int*)hbf)[e] = 0u;
  __syncthreads();
  if (t < 256) {
    float v = __bfloat162float(enchB[((size_t)b * 64 + 63) * 256 + t]);
    h32[0][t] = v;
    hbf[0][0][t] = __float2bfloat16(v);
  }
  __syncthreads();
  int cur = 0;
  int xr = (row & 7) << 4;
  int abase = row * 512 + hi16 * 16;
  int bs3 = (b & 7) << 3;
  for (int i = 0; i < NL; ++i) {
    float gdv0 = 0.f, gdv1 = 0.f, gdv2 = 0.f;
    if (t < 256) {
      const float* gp = Gdec + ((size_t)i * 64 + b) * G3 + t;
      gdv0 = gp[0]; gdv1 = gp[256]; gdv2 = gp[512];
    }
    // phase A: gh = h @ Whh^T (MFMA) || softmax (wave 0)
    const char* hb = (const char*)&hbf[cur][0][0];
    f32x4 acc[3][2] = {};
    bf16x8 ah[4];
#pragma unroll
    for (int half = 0; half < 2; ++half) {
#pragma unroll
      for (int kf = 0; kf < 4; ++kf)
        ah[kf] = *(const bf16x8*)(hb + ((abase + (half * 4 + kf) * 64) ^ xr));
#pragma unroll
      for (int f = 0; f < 3; ++f)
#pragma unroll
        for (int fc = 0; fc < 2; ++fc)
#pragma unroll
          for (int kf = 0; kf < 4; ++kf)
            acc[f][fc] = __builtin_amdgcn_mfma_f32_16x16x32_bf16(
                ah[kf], wv[f][fc][half * 4 + kf], acc[f][fc], 0, 0, 0);
    }
    if (hi16 == 0) {
#pragma unroll
      for (int f = 0; f < 3; ++f)
#pragma unroll
        for (int fc = 0; fc < 2; ++fc)
          ghbuf[f * 256 + w * 32 + fc * 16 + lane] = acc[f][fc][0];
    }
    if (w == 0) {
      float p = h32[cur][lane] * aw[0] + h32[cur][lane + 64] * aw[1]
              + h32[cur][lane + 128] * aw[2] + h32[cur][lane + 192] * aw[3];
#pragma unroll
      for (int off = 32; off; off >>= 1) p += __shfl_xor(p, off, 64);
      float lg = fmaxf(esc + p + attb, 0.f);
      float mx = lg;
#pragma unroll
      for (int off = 32; off; off >>= 1) mx = fmaxf(mx, __shfl_xor(mx, off, 64));
      float e = __expf(lg - mx);
      float sm = e;
#pragma unroll
      for (int off = 32; off; off >>= 1) sm += __shfl_xor(sm, off, 64);
      wts[lane] = e / sm;
    }
    __syncthreads();
    // phase B: gi[c] = sum_s wts[s] * ENCW[s][c]   (pure LDS)
    if (t < 384) {
      const unsigned int* eb = (const unsigned int*)&encw_l[0][0];
      float cx = 0.f, cy = 0.f;
#pragma unroll 8
      for (int s_ = 0; s_ < NS; ++s_) {
        unsigned int u = eb[s_ * 384 + t];
        float wt = wts[s_];
        cx = fmaf(wt, __uint_as_float(u << 16), cx);
        cy = fmaf(wt, __uint_as_float(u & 0xffff0000u), cy);
      }
      *(float2*)&gibuf[2 * t] = make_float2(cx, cy);
    }
    __syncthreads();
    // phase C: gates + h update (threads 0-255)
    if (t < 256) {
      int nxt = cur ^ 1;
      float gir = gibuf[t]       + gdv0;
      float giz = gibuf[256 + t] + gdv1;
      float gin = gibuf[512 + t] + gdv2;
      float rr = 1.f / (1.f + __expf(-(gir + ghbuf[t]       + bhh[t])));
      float zz = 1.f / (1.f + __expf(-(giz + ghbuf[256 + t] + bhh[256 + t])));
      float nn = tanhf(gin + rr * (ghbuf[512 + t] + bhh[512 + t]));
      float hn = (1.f - zz) * nn + zz * h32[cur][t];
      h32[nxt][t] = hn;
      hbf[nxt][0][t] = __float2bfloat16(hn);
      int cs = (t & ~63) | ((t & 63) ^ bs3);   // pre-swizzle col for out GEMM
      dechb[((size_t)i * 64 + b) * 256 + cs] = __float2bfloat16(hn);
    }
    __syncthreads();
    cur ^= 1;
  }
}

// In-place row log-softmax over VOUT (one WG per (b,l) row).
__global__ __launch_bounds__(256) void k_logsoftmax(float* __restrict__ out) {
  float* x = out + (size_t)blockIdx.x * NVOUT;
  __shared__ float red[256];
  int t = threadIdx.x;
  float mx = -1e30f;
  for (int v = t; v < NVOUT; v += 256) mx = fmaxf(mx, x[v]);
  red[t] = mx; __syncthreads();
  for (int off = 128; off; off >>= 1) {
    if (t < off) red[t] = fmaxf(red[t], red[t + off]);
    __syncthreads();
  }
  mx = red[0]; __syncthreads();
  float sm = 0.f;
  for (int v = t; v < NVOUT; v += 256) sm += __expf(x[v] - mx);
  red[t] = sm; __syncthreads();
  for (int off = 128; off; off >>= 1) {
    if (t < off) red[t] += red[t + off];
    __syncthreads();
  }
  float lse = mx + logf(red[0]);
  for (int v = t; v < NVOUT; v += 256) x[v] -= lse;
}

// ---------------------------------------------------------------------------
extern "C" void kernel_launch(void* const* d_in, const int* in_sizes, int n_in,
                              void* d_out, int out_size, void* d_ws, size_t ws_size,
                              hipStream_t stream) {
  const float* X        = (const float*)d_in[0];
  const int*   gt       = (const int*)  d_in[1];
  const float* enc_Wih  = (const float*)d_in[2];
  const float* enc_Whh  = (const float*)d_in[3];
  const float* enc_bih  = (const float*)d_in[4];
  const float* enc_bhh  = (const float*)d_in[5];
  const float* att_w    = (const float*)d_in[6];
  const float* att_b    = (const float*)d_in[7];
  const float* dec_Wih  = (const float*)d_in[8];
  const float* dec_Whh  = (const float*)d_in[9];
  const float* dec_bih  = (const float*)d_in[10];
  const float* dec_bhh  = (const float*)d_in[11];
  const float* out_W    = (const float*)d_in[12];
  const float* out_b    = (const float*)d_in[13];
  float* out = (float*)d_out;

  // workspace carve-up (~135 MB; R2 proved >=136 available)
  float* p = (float*)d_ws;
  float* Gienc  = p; p += NS * NB * G3;          // [b*64+s][768] fp32
  float* Gdec   = p; p += NL * NB * G3;          // [i*64+b][768] fp32
  float* escoreT = p; p += NB * NS;              // [b][s] fp32
  __hip_bfloat16* q = (__hip_bfloat16*)p;
  __hip_bfloat16* enchBb = q; q += (size_t)NB * NS * NH;   // [b][s][j] bf16
  __hip_bfloat16* Wcat_e = q; q += (size_t)3 * 256 * 256;  // enc Whh r,z,n
  __hip_bfloat16* Wcat_d = q; q += (size_t)6 * 256 * 256;  // dec Wih(ctx)+Whh
  __hip_bfloat16* Xb     = q; q += (size_t)4096 * KP2;     // pre-swizzled
  __hip_bfloat16* Wencb  = q; q += (size_t)G3 * KP2;       // pre-swizzled
  __hip_bfloat16* Woutb  = q; q += (size_t)NOUTP * NH;     // pre-swizzled
  __hip_bfloat16* dechb  = q; q += (size_t)NL * NB * NH;   // pre-swizzled cols
  // ENCW [4096][768] bf16 aliases Gienc (dead after encoder)
  __hip_bfloat16* ENCW   = (__hip_bfloat16*)Gienc;
  // split-K partials (4 x 4096 x 768 fp32 = 50 MB) live in d_out scratch:
  // fully overwritten later by k_gemm_outS + k_logsoftmax. No atomics.
  float* Pout = (float*)d_out;

  // prep (independent)
  k_cvt_pad<<<4096, 256, 0, stream>>>(X, Xb, 4096, NVIN, KP2, 1);
  k_cvt_pad<<<G3, 256, 0, stream>>>(enc_Wih, Wencb, G3, NVIN, KP2, 1);
  k_cvt_pad<<<NOUTP, 256, 0, stream>>>(out_W, Woutb, NVOUT, NH, NH, 1);
  k_wpack<<<768, 256, 0, stream>>>(enc_Whh, NH, enc_Whh, NH, Wcat_e, 3 * 65536);
  k_wpack<<<1536, 256, 0, stream>>>(dec_Wih, NH + NVOUT, dec_Whh, NH, Wcat_d, 6 * 65536);
  k_pregather<<<NL * NB, 256, 0, stream>>>(dec_Wih, dec_bih, gt, Gdec);

  k_gemm_encS<<<dim3(6, 32, 4), 256, 0, stream>>>(Xb, Wencb, Pout);
  k_reduce4<<<3072, 256, 0, stream>>>((const float4*)Pout, enc_bih, (float4*)Gienc);
  k_encoder4<<<64, 512, 0, stream>>>(Gienc, Wcat_e, enc_bhh, att_w, enchBb, escoreT);
  k_gemm_encw<<<dim3(6, 32), 256, 0, stream>>>(enchBb, Wcat_d, ENCW);
  k_decoder4<<<64, 512, 0, stream>>>(Gdec, Wcat_d, dec_bhh, enchBb, ENCW,
                                     escoreT, att_w, att_b, dechb);
  k_gemm_outS<<<dim3(79, 32), 256, 0, stream>>>(dechb, Woutb, out_b, out);
  k_logsoftmax<<<NB * NL, 256, 0, stream>>>(out);
}

// Round 8
// 868.775 us; speedup vs baseline: 3.1048x; 1.0607x over previous
//
#include <hip/hip_runtime.h>
#include <hip/hip_bf16.h>
#include <math.h>

// Problem dims (fixed by the reference)
#define NB 64      // batch
#define NS 64      // encoder steps
#define NL 64      // decoder steps
#define NH 256     // hidden
#define G3 768     // 3*NH (gates r,z,n)
#define NVIN 10000
#define NVOUT 10000
#define KP2 10240   // NVIN padded (4 splits x 40 x BK=64)
#define NOUTP 10112 // NVOUT padded to 128 for out GEMM

typedef __attribute__((ext_vector_type(8))) short bf16x8;  // 8 bf16 (4 VGPRs)
typedef __attribute__((ext_vector_type(4))) float f32x4;   // MFMA accumulator
typedef __attribute__((ext_vector_type(4))) unsigned int u32x4;

// async global->LDS, 16B per lane (dest must be wave-uniform base + lane*16)
__device__ __forceinline__ void gld_lds16(const __hip_bfloat16* g, __hip_bfloat16* l) {
  __builtin_amdgcn_global_load_lds(
      (const __attribute__((address_space(1))) unsigned int*)(const void*)g,
      (__attribute__((address_space(3))) unsigned int*)(void*)l, 16, 0, 0);
}

__device__ __forceinline__ unsigned int f2bf(float f) {  // RNE fp32->bf16 bits
  unsigned int u = __float_as_uint(f);
  return (u + 0x7fff + ((u >> 16) & 1)) >> 16;
}

// ---------------------------------------------------------------------------
// fp32 -> bf16 convert with padding; swz=1 pre-swizzles columns within each
// 64-group by ((row&7)<<3) so linear global_load_lds + XOR'd ds_read is
// conflict-free (T2/m173: swizzle the SOURCE, keep LDS dest linear).
// ---------------------------------------------------------------------------
__global__ __launch_bounds__(256) void k_cvt_pad(
    const float* __restrict__ in, __hip_bfloat16* __restrict__ out,
    int in_rows, int in_cols, int out_cols, int swz) {
  int r = blockIdx.x;
  const float* src = in + (size_t)r * in_cols;
  __hip_bfloat16* dst = out + (size_t)r * out_cols;
  bool live = r < in_rows;
  int sx = swz ? ((r & 7) << 3) : 0;
  for (int c = threadIdx.x * 4; c < out_cols; c += 1024) {
    int cc = (c & ~63) | ((c & 63) ^ sx);
    __hip_bfloat16 v[4];
    if (live && cc + 3 < in_cols) {
      float4 f = *(const float4*)(src + cc);
      v[0] = __float2bfloat16(f.x); v[1] = __float2bfloat16(f.y);
      v[2] = __float2bfloat16(f.z); v[3] = __float2bfloat16(f.w);
    } else {
      v[0] = v[1] = v[2] = v[3] = __float2bfloat16(0.f);
    }
    *(ushort4*)(dst + c) = *(const ushort4*)v;
  }
}

// ---------------------------------------------------------------------------
// Pack recurrent weights to bf16 Wcat[f][c][k].
// ---------------------------------------------------------------------------
__global__ __launch_bounds__(256) void k_wpack(
    const float* __restrict__ srcA, int strideA,
    const float* __restrict__ srcB, int strideB,
    __hip_bfloat16* __restrict__ out, int total) {
  int idx = blockIdx.x * 256 + threadIdx.x;
  if (idx >= total) return;
  int k = idx & 255, c = (idx >> 8) & 255, f = idx >> 16;
  float v = (f < 3) ? srcA[(size_t)(f * 256 + c) * strideA + k]
                    : srcB[(size_t)((f - 3) * 256 + c) * strideB + k];
  out[idx] = __float2bfloat16(v);
}

// ---------------------------------------------------------------------------
// Enc GEMM, split-K (see R7): P[z] partials, reduced by k_reduce4.
// ---------------------------------------------------------------------------
__global__ __launch_bounds__(256) void k_gemm_encS(
    const __hip_bfloat16* __restrict__ A, const __hip_bfloat16* __restrict__ B,
    float* __restrict__ P) {
  __shared__ __hip_bfloat16 As[128][64];
  __shared__ __hip_bfloat16 Bs[128][64];
  int t = threadIdx.x;
  int wid = t >> 6, lane = t & 63;
  int m0 = blockIdx.y * 128, n0 = blockIdx.x * 128;
  int wr = wid >> 1, wc = wid & 1;
  int r16 = lane & 15, hi16 = lane >> 4;
  int xr = (r16 & 7) << 4;
  f32x4 acc[4][4] = {};
  int kbeg = blockIdx.z * 2560;
  for (int ks = 0; ks < 40; ++ks) {
    int k0 = kbeg + ks * 64;
    __syncthreads();
#pragma unroll
    for (int is = 0; is < 4; ++is) {
      int off = is * 4096 + t * 16;
      int r = off >> 7, e = (off & 127) >> 1;
      gld_lds16(A + (size_t)(m0 + r) * KP2 + k0 + e, &As[r][e]);
      gld_lds16(B + (size_t)(n0 + r) * KP2 + k0 + e, &Bs[r][e]);
    }
    __syncthreads();
    const char* ab = (const char*)As;
    const char* bb = (const char*)Bs;
#pragma unroll
    for (int kk = 0; kk < 2; ++kk) {
      int ko = kk * 64 + hi16 * 16;
      bf16x8 af[4], bfr[4];
#pragma unroll
      for (int i = 0; i < 4; ++i) {
        af[i]  = *(const bf16x8*)(ab + (wr * 64 + i * 16 + r16) * 128 + (ko ^ xr));
        bfr[i] = *(const bf16x8*)(bb + (wc * 64 + i * 16 + r16) * 128 + (ko ^ xr));
      }
#pragma unroll
      for (int i = 0; i < 4; ++i)
#pragma unroll
        for (int j = 0; j < 4; ++j)
          acc[i][j] = __builtin_amdgcn_mfma_f32_16x16x32_bf16(af[i], bfr[j], acc[i][j], 0, 0, 0);
    }
  }
  float* Pz = P + (size_t)blockIdx.z * 4096 * G3;
#pragma unroll
  for (int i = 0; i < 4; ++i)
#pragma unroll
    for (int j = 0; j < 4; ++j) {
      int ccol = n0 + wc * 64 + j * 16 + r16;
#pragma unroll
      for (int q = 0; q < 4; ++q) {
        int crow = m0 + wr * 64 + i * 16 + hi16 * 4 + q;
        Pz[(size_t)crow * G3 + ccol] = acc[i][j][q];
      }
    }
}

// Gienc = P0+P1+P2+P3 + bias
__global__ __launch_bounds__(256) void k_reduce4(
    const float4* __restrict__ P, const float* __restrict__ bias,
    float4* __restrict__ G) {
  int idx = blockIdx.x * 256 + threadIdx.x;
  float4 a = P[idx], b = P[idx + 786432], c = P[idx + 2 * 786432],
         d = P[idx + 3 * 786432];
  float4 bs = *(const float4*)(bias + (idx % 192) * 4);
  float4 o;
  o.x = a.x + b.x + c.x + d.x + bs.x;
  o.y = a.y + b.y + c.y + d.y + bs.y;
  o.z = a.z + b.z + c.z + d.z + bs.z;
  o.w = a.w + b.w + c.w + d.w + bs.w;
  G[idx] = o;
}

// ---------------------------------------------------------------------------
// Out GEMM (BK=64 + swizzle, see R7).
// ---------------------------------------------------------------------------
__global__ __launch_bounds__(256) void k_gemm_outS(
    const __hip_bfloat16* __restrict__ A, const __hip_bfloat16* __restrict__ B,
    const float* __restrict__ bias, float* __restrict__ C) {
  __shared__ __hip_bfloat16 As[128][64];
  __shared__ __hip_bfloat16 Bs[128][64];
  int t = threadIdx.x;
  int wid = t >> 6, lane = t & 63;
  int m0 = blockIdx.y * 128, n0 = blockIdx.x * 128;
  int wr = wid >> 1, wc = wid & 1;
  int r16 = lane & 15, hi16 = lane >> 4;
  int xr = (r16 & 7) << 4;
  f32x4 acc[4][4] = {};
  for (int k0 = 0; k0 < NH; k0 += 64) {
    __syncthreads();
#pragma unroll
    for (int is = 0; is < 4; ++is) {
      int off = is * 4096 + t * 16;
      int r = off >> 7, e = (off & 127) >> 1;
      gld_lds16(A + (size_t)(m0 + r) * NH + k0 + e, &As[r][e]);
      gld_lds16(B + (size_t)(n0 + r) * NH + k0 + e, &Bs[r][e]);
    }
    __syncthreads();
    const char* ab = (const char*)As;
    const char* bb = (const char*)Bs;
#pragma unroll
    for (int kk = 0; kk < 2; ++kk) {
      int ko = kk * 64 + hi16 * 16;
      bf16x8 af[4], bfr[4];
#pragma unroll
      for (int i = 0; i < 4; ++i) {
        af[i]  = *(const bf16x8*)(ab + (wr * 64 + i * 16 + r16) * 128 + (ko ^ xr));
        bfr[i] = *(const bf16x8*)(bb + (wc * 64 + i * 16 + r16) * 128 + (ko ^ xr));
      }
#pragma unroll
      for (int i = 0; i < 4; ++i)
#pragma unroll
        for (int j = 0; j < 4; ++j)
          acc[i][j] = __builtin_amdgcn_mfma_f32_16x16x32_bf16(af[i], bfr[j], acc[i][j], 0, 0, 0);
    }
  }
#pragma unroll
  for (int i = 0; i < 4; ++i)
#pragma unroll
    for (int j = 0; j < 4; ++j) {
      int ccol = n0 + wc * 64 + j * 16 + r16;
      if (ccol < NVOUT) {
        float bs = bias[ccol];
#pragma unroll
        for (int q = 0; q < 4; ++q) {
          int crow = m0 + wr * 64 + i * 16 + hi16 * 4 + q;  // = l*64+b
          int l = crow >> 6, b = crow & 63;
          C[((size_t)b * NL + l) * NVOUT + ccol] = acc[i][j][q] + bs;
        }
      }
    }
}

// ---------------------------------------------------------------------------
// ENCW GEMM -> TRANSPOSED, swizzled output: ENCWT[b][c][s ^ ((c&7)<<3)] =
// sum_k ench[b*64+s][k] * Wih_ctx[c][k]. Decoder stages [c][s] slices
// linearly and reads with the matching XOR (bank-conflict-free B-frags).
// ---------------------------------------------------------------------------
__global__ __launch_bounds__(256) void k_gemm_encw(
    const __hip_bfloat16* __restrict__ A, const __hip_bfloat16* __restrict__ B,
    __hip_bfloat16* __restrict__ CT) {
  __shared__ __hip_bfloat16 As[128][32];
  __shared__ __hip_bfloat16 Bs[128][32];
  int t = threadIdx.x;
  int wid = t >> 6, lane = t & 63;
  int m0 = blockIdx.y * 128, n0 = blockIdx.x * 128;
  int wr = wid >> 1, wc = wid & 1;
  f32x4 acc[4][4] = {};
  for (int k0 = 0; k0 < NH; k0 += 32) {
    __syncthreads();
#pragma unroll
    for (int is = 0; is < 2; ++is) {
      int off = is * 4096 + wid * 1024 + lane * 16;
      int r = off >> 6, cb = (off & 63) >> 1;
      gld_lds16(A + (size_t)(m0 + r) * NH + k0 + cb, &As[r][cb]);
      gld_lds16(B + (size_t)(n0 + r) * NH + k0 + cb, &Bs[r][cb]);
    }
    __syncthreads();
    int r16 = lane & 15, kb = (lane >> 4) * 8;
    bf16x8 af[4], bfr[4];
#pragma unroll
    for (int i = 0; i < 4; ++i) {
      af[i]  = *(const bf16x8*)&As[wr * 64 + i * 16 + r16][kb];
      bfr[i] = *(const bf16x8*)&Bs[wc * 64 + i * 16 + r16][kb];
    }
#pragma unroll
    for (int i = 0; i < 4; ++i)
#pragma unroll
      for (int j = 0; j < 4; ++j)
        acc[i][j] = __builtin_amdgcn_mfma_f32_16x16x32_bf16(af[i], bfr[j], acc[i][j], 0, 0, 0);
  }
  int r16 = lane & 15, rg = lane >> 4;
#pragma unroll
  for (int i = 0; i < 4; ++i)
#pragma unroll
    for (int j = 0; j < 4; ++j) {
      int ccol = n0 + wc * 64 + j * 16 + r16;
#pragma unroll
      for (int q = 0; q < 4; ++q) {
        int crow = m0 + wr * 64 + i * 16 + rg * 4 + q;   // = b*64+s
        int bb = crow >> 6, ss = crow & 63;
        CT[((size_t)bb * G3 + ccol) * 64 + (ss ^ ((ccol & 7) << 3))] =
            __float2bfloat16(acc[i][j][q]);
      }
    }
}

// ---------------------------------------------------------------------------
// Pre-gather decoder one-hot input term: Gdec = bih + onehot column.
// ---------------------------------------------------------------------------
__global__ __launch_bounds__(256) void k_pregather(
    const float* __restrict__ Wih, const float* __restrict__ bih,
    const int* __restrict__ gt, float* __restrict__ Gdec) {
  int ib = blockIdx.x;              // i*64+b
  int i = ib >> 6, b = ib & 63;
  int tok = (i > 0) ? gt[b * NL + (i - 1)] : -1;
  for (int g = threadIdx.x; g < G3; g += 256) {
    float v = bih[g];
    if (tok >= 0) v += Wih[(size_t)g * (NH + NVOUT) + NH + tok];
    Gdec[(size_t)ib * G3 + g] = v;
  }
}

// ---------------------------------------------------------------------------
// Encoder scan: 64 WGs x 512 thr, one batch/WG, Whh VGPR-resident (192 regs).
// h kept as a single 256-elem LDS row read by ALL lanes (A rows 1-15 are
// don't-cares -> broadcast reads, no swizzle, 1 KB instead of 16 KB).
// ---------------------------------------------------------------------------
__global__ __launch_bounds__(512) void k_encoder4(
    const float* __restrict__ Gi, const __hip_bfloat16* __restrict__ Wcat,
    const float* __restrict__ bhh, const float* __restrict__ att_w,
    __hip_bfloat16* __restrict__ enchB, float* __restrict__ escoreT) {
  __shared__ float h32[2][256];
  __shared__ __hip_bfloat16 hbf[2][256];
  int t = threadIdx.x, w = t >> 6, lane = t & 63;
  int b = blockIdx.x;
  int r16 = lane & 15, hi16 = lane >> 4;
  bf16x8 wv[3][2][8];
#pragma unroll
  for (int f = 0; f < 3; ++f)
#pragma unroll
    for (int fc = 0; fc < 2; ++fc)
#pragma unroll
      for (int kf = 0; kf < 8; ++kf)
        wv[f][fc][kf] = *(const bf16x8*)(Wcat +
            (((size_t)f * 256 + w * 32 + fc * 16 + r16) * 256 + kf * 32 + hi16 * 8));
  float aw[4];
#pragma unroll
  for (int q = 0; q < 4; ++q) aw[q] = att_w[256 + lane + q * 64];   // w_enc
  if (t < 256) {
    h32[0][t] = 0.f; h32[1][t] = 0.f;
    hbf[0][t] = __float2bfloat16(0.f); hbf[1][t] = __float2bfloat16(0.f);
  }
  __syncthreads();
  int cur = 0;
  for (int s = 0; s < NS; ++s) {
    float gd[3][2];
    if (hi16 == 0) {
#pragma unroll
      for (int f = 0; f < 3; ++f)
#pragma unroll
        for (int fc = 0; fc < 2; ++fc)
          gd[f][fc] = Gi[((size_t)b * 64 + s) * G3 + f * 256 + w * 32 + fc * 16 + lane];
    }
    const char* hb = (const char*)&hbf[cur][0];
    f32x4 acc[3][2] = {};
#pragma unroll
    for (int half = 0; half < 2; ++half) {
      bf16x8 ah[4];
#pragma unroll
      for (int kf = 0; kf < 4; ++kf)
        ah[kf] = *(const bf16x8*)(hb + (half * 4 + kf) * 64 + hi16 * 16);  // broadcast
#pragma unroll
      for (int f = 0; f < 3; ++f)
#pragma unroll
        for (int fc = 0; fc < 2; ++fc)
#pragma unroll
          for (int kf = 0; kf < 4; ++kf)
            acc[f][fc] = __builtin_amdgcn_mfma_f32_16x16x32_bf16(
                ah[kf], wv[f][fc][half * 4 + kf], acc[f][fc], 0, 0, 0);
    }
    if (hi16 == 0) {
      int nxt = cur ^ 1;
#pragma unroll
      for (int fc = 0; fc < 2; ++fc) {
        int c = w * 32 + fc * 16 + lane;
        float rr = 1.f / (1.f + __expf(-(gd[0][fc] + acc[0][fc][0] + bhh[c])));
        float zz = 1.f / (1.f + __expf(-(gd[1][fc] + acc[1][fc][0] + bhh[256 + c])));
        float nn = tanhf(gd[2][fc] + rr * (acc[2][fc][0] + bhh[512 + c]));
        float hn = (1.f - zz) * nn + zz * h32[cur][c];
        h32[nxt][c] = hn;
        hbf[nxt][c] = __float2bfloat16(hn);
        enchB[((size_t)b * 64 + s) * 256 + c] = __float2bfloat16(hn);
      }
    }
    __syncthreads();
    cur ^= 1;
    if (w == 0) {   // escore on just-written h
      float p = h32[cur][lane] * aw[0] + h32[cur][lane + 64] * aw[1]
              + h32[cur][lane + 128] * aw[2] + h32[cur][lane + 192] * aw[3];
#pragma unroll
      for (int off = 32; off; off >>= 1) p += __shfl_xor(p, off, 64);
      if (lane == 0) escoreT[(size_t)b * 64 + s] = p;
    }
  }
}

// ---------------------------------------------------------------------------
// Decoder scan, 1 barrier/step. 64 WGs x 512 thr, one batch/WG.
// Per step: replicated softmax (all waves, shfl-only) -> wts shuffled into an
// MFMA A-frag -> gi = wts x ENCWT (12 MFMA, B from swizzled LDS) accumulated
// INTO the r/z gh accumulators via the C operand -> gh MFMA (r,z panels
// VGPR-resident; n panel streamed from L2, LICM defeated via asm) -> gates
// in-register on lanes<16 -> write h -> barrier.
// ---------------------------------------------------------------------------
__global__ __launch_bounds__(512) void k_decoder5(
    const float* __restrict__ Gdec, const __hip_bfloat16* __restrict__ Wcat6,
    const float* __restrict__ bhh, const __hip_bfloat16* __restrict__ enchB,
    const __hip_bfloat16* __restrict__ ENCWT, const float* __restrict__ escoreT,
    const float* __restrict__ att_w, const float* __restrict__ att_b,
    __hip_bfloat16* __restrict__ dechb) {
  __shared__ __hip_bfloat16 encwT[G3][64];    // 96 KB, [c][s^((c&7)<<3)]
  __shared__ __hip_bfloat16 hbf[2][256];      // 1 KB
  __shared__ float h32[2][256];               // 2 KB
  int t = threadIdx.x, w = t >> 6, lane = t & 63;
  int b = blockIdx.x;
  int r16 = lane & 15, hi16 = lane >> 4;
  int cw = w * 32;
  // stage ENCWT b-slice (96 KB contiguous, swizzle pre-baked in global)
  {
    const char* srcb = (const char*)(ENCWT + (size_t)b * G3 * 64);
    char* dstb = (char*)&encwT[0][0];
#pragma unroll
    for (int is = 0; is < 12; ++is) {
      int off = is * 8192 + t * 16;
      gld_lds16((const __hip_bfloat16*)(srcb + off), (__hip_bfloat16*)(dstb + off));
    }
  }
  // r,z Whh panels resident (panels 3,4 of Wcat6) = 128 VGPRs
  bf16x8 wv[2][2][8];
#pragma unroll
  for (int f = 0; f < 2; ++f)
#pragma unroll
    for (int fc = 0; fc < 2; ++fc)
#pragma unroll
      for (int kf = 0; kf < 8; ++kf)
        wv[f][fc][kf] = *(const bf16x8*)(Wcat6 +
            (((size_t)(3 + f) * 256 + cw + fc * 16 + r16) * 256 + kf * 32 + hi16 * 8));
  float aw[4];
#pragma unroll
  for (int q = 0; q < 4; ++q) aw[q] = att_w[lane + q * 64];   // w_dec
  float attb = att_b[0];
  float esc = escoreT[(size_t)b * 64 + lane];
  float bh0[2], bh1[2], bh2[2];
#pragma unroll
  for (int fc = 0; fc < 2; ++fc) {
    bh0[fc] = bhh[cw + fc * 16 + r16];
    bh1[fc] = bhh[256 + cw + fc * 16 + r16];
    bh2[fc] = bhh[512 + cw + fc * 16 + r16];
  }
  if (t < 256) {
    float v = __bfloat162float(enchB[((size_t)b * 64 + 63) * 256 + t]);
    h32[0][t] = v;  hbf[0][t] = __float2bfloat16(v);
    h32[1][t] = 0.f; hbf[1][t] = __float2bfloat16(0.f);
  }
  __syncthreads();
  float hp[2];   // h kept in-register on lanes<16 (col = cw + fc*16 + r16)
  hp[0] = h32[0][cw + r16];
  hp[1] = h32[0][cw + 16 + r16];
  int bs3 = (b & 7) << 3;
  unsigned long long wna = (unsigned long long)(Wcat6 + (size_t)5 * 256 * 256);
  int cur = 0;
  for (int i = 0; i < NL; ++i) {
    asm volatile("" : "+v"(wna));   // opaque pointer: stop LICM hoisting wn loads
    const __hip_bfloat16* wnp = (const __hip_bfloat16*)wna;
    // Gdec prefetch (lanes<16)
    float gd0[2], gd1[2], gd2[2];
    if (hi16 == 0) {
      const float* gp = Gdec + ((size_t)i * 64 + b) * G3;
#pragma unroll
      for (int fc = 0; fc < 2; ++fc) {
        gd0[fc] = gp[cw + fc * 16 + r16];
        gd1[fc] = gp[256 + cw + fc * 16 + r16];
        gd2[fc] = gp[512 + cw + fc * 16 + r16];
      }
    }
    // --- softmax, replicated on every wave (no LDS, no barrier) ---
    float p = h32[cur][lane] * aw[0] + h32[cur][lane + 64] * aw[1]
            + h32[cur][lane + 128] * aw[2] + h32[cur][lane + 192] * aw[3];
#pragma unroll
    for (int off = 32; off; off >>= 1) p += __shfl_xor(p, off, 64);
    float lg = fmaxf(esc + p + attb, 0.f);
    float mx = lg;
#pragma unroll
    for (int off = 32; off; off >>= 1) mx = fmaxf(mx, __shfl_xor(mx, off, 64));
    float e = __expf(lg - mx);
    float sm = e;
#pragma unroll
    for (int off = 32; off; off >>= 1) sm += __shfl_xor(sm, off, 64);
    float wl = e / sm;               // = wts[lane]
    // --- wts -> A-frags (row-broadcast: all 16 rows get the same k-slice) ---
    bf16x8 af_[2];
#pragma unroll
    for (int kf = 0; kf < 2; ++kf) {
      u32x4 tmp;
#pragma unroll
      for (int j = 0; j < 4; ++j) {
        int src = hi16 * 8 + kf * 32 + 2 * j;
        tmp[j] = f2bf(__shfl(wl, src, 64)) | (f2bf(__shfl(wl, src + 1, 64)) << 16);
      }
      af_[kf] = __builtin_bit_cast(bf16x8, tmp);
    }
    // --- gi MFMAs (B from swizzled LDS), fused into r/z accumulators ---
    f32x4 acc_rz[2][2] = {};
    f32x4 ghn2[2] = {};
    f32x4 gin2[2] = {};
    const char* eb = (const char*)&encwT[0][0];
#pragma unroll
    for (int g = 0; g < 3; ++g)
#pragma unroll
      for (int fc = 0; fc < 2; ++fc) {
        int cloc = g * 256 + cw + fc * 16 + r16;
        int xb = (cloc & 7) << 4;
#pragma unroll
        for (int kf = 0; kf < 2; ++kf) {
          bf16x8 bfrag = *(const bf16x8*)(eb + cloc * 128 + ((kf * 64 + hi16 * 16) ^ xb));
          if (g < 2) acc_rz[g][fc] = __builtin_amdgcn_mfma_f32_16x16x32_bf16(af_[kf], bfrag, acc_rz[g][fc], 0, 0, 0);
          else       gin2[fc]     = __builtin_amdgcn_mfma_f32_16x16x32_bf16(af_[kf], bfrag, gin2[fc], 0, 0, 0);
        }
      }
    // --- gh MFMAs: r,z from resident panels; n streamed from L2 ---
    const char* hb = (const char*)&hbf[cur][0];
#pragma unroll
    for (int half = 0; half < 2; ++half) {
      bf16x8 ah[4];
#pragma unroll
      for (int kf = 0; kf < 4; ++kf)
        ah[kf] = *(const bf16x8*)(hb + (half * 4 + kf) * 64 + hi16 * 16);  // broadcast
      bf16x8 wn[2][4];
#pragma unroll
      for (int fc = 0; fc < 2; ++fc)
#pragma unroll
        for (int kf = 0; kf < 4; ++kf)
          wn[fc][kf] = *(const bf16x8*)(wnp +
              ((size_t)(cw + fc * 16 + r16) * 256 + (half * 4 + kf) * 32 + hi16 * 8));
#pragma unroll
      for (int f = 0; f < 2; ++f)
#pragma unroll
        for (int fc = 0; fc < 2; ++fc)
#pragma unroll
          for (int kf = 0; kf < 4; ++kf)
            acc_rz[f][fc] = __builtin_amdgcn_mfma_f32_16x16x32_bf16(
                ah[kf], wv[f][fc][half * 4 + kf], acc_rz[f][fc], 0, 0, 0);
#pragma unroll
      for (int fc = 0; fc < 2; ++fc)
#pragma unroll
        for (int kf = 0; kf < 4; ++kf)
          ghn2[fc] = __builtin_amdgcn_mfma_f32_16x16x32_bf16(
              ah[kf], wn[fc][kf], ghn2[fc], 0, 0, 0);
    }
    // --- gates + h update, all in-register (lanes<16) ---
    if (hi16 == 0) {
      int nxt = cur ^ 1;
#pragma unroll
      for (int fc = 0; fc < 2; ++fc) {
        int c = cw + fc * 16 + r16;
        float rr = 1.f / (1.f + __expf(-(gd0[fc] + acc_rz[0][fc][0] + bh0[fc])));
        float zz = 1.f / (1.f + __expf(-(gd1[fc] + acc_rz[1][fc][0] + bh1[fc])));
        float nn = tanhf(gd2[fc] + gin2[fc][0] + rr * (ghn2[fc][0] + bh2[fc]));
        float hn = (1.f - zz) * nn + zz * hp[fc];
        hp[fc] = hn;
        h32[nxt][c] = hn;
        hbf[nxt][c] = __float2bfloat16(hn);
        int cs = (c & ~63) | ((c & 63) ^ bs3);   // pre-swizzle for out GEMM
        dechb[((size_t)i * 64 + b) * 256 + cs] = __float2bfloat16(hn);
      }
    }
    __syncthreads();
    cur ^= 1;
  }
}

// ---------------------------------------------------------------------------
// Log-softmax, register-resident single read + single write (one WG/row).
// ---------------------------------------------------------------------------
__global__ __launch_bounds__(256) void k_logsoftmax(float* __restrict__ out) {
  float* x = out + (size_t)blockIdx.x * NVOUT;
  __shared__ float red[256];
  int t = threadIdx.x;
  float4 v[10];
  float mx = -1e30f;
#pragma unroll
  for (int ii = 0; ii < 10; ++ii) {
    int slot = ii * 256 + t;
    if (slot < 2500) {
      v[ii] = *(const float4*)(x + slot * 4);
      mx = fmaxf(mx, fmaxf(fmaxf(v[ii].x, v[ii].y), fmaxf(v[ii].z, v[ii].w)));
    }
  }
  red[t] = mx; __syncthreads();
  for (int off = 128; off; off >>= 1) {
    if (t < off) red[t] = fmaxf(red[t], red[t + off]);
    __syncthreads();
  }
  mx = red[0]; __syncthreads();
  float sm = 0.f;
#pragma unroll
  for (int ii = 0; ii < 10; ++ii) {
    int slot = ii * 256 + t;
    if (slot < 2500)
      sm += __expf(v[ii].x - mx) + __expf(v[ii].y - mx)
          + __expf(v[ii].z - mx) + __expf(v[ii].w - mx);
  }
  red[t] = sm; __syncthreads();
  for (int off = 128; off; off >>= 1) {
    if (t < off) red[t] += red[t + off];
    __syncthreads();
  }
  float lse = mx + logf(red[0]);
#pragma unroll
  for (int ii = 0; ii < 10; ++ii) {
    int slot = ii * 256 + t;
    if (slot < 2500) {
      float4 o; o.x = v[ii].x - lse; o.y = v[ii].y - lse;
      o.z = v[ii].z - lse; o.w = v[ii].w - lse;
      *(float4*)(x + slot * 4) = o;
    }
  }
}

// ---------------------------------------------------------------------------
extern "C" void kernel_launch(void* const* d_in, const int* in_sizes, int n_in,
                              void* d_out, int out_size, void* d_ws, size_t ws_size,
                              hipStream_t stream) {
  const float* X        = (const float*)d_in[0];
  const int*   gt       = (const int*)  d_in[1];
  const float* enc_Wih  = (const float*)d_in[2];
  const float* enc_Whh  = (const float*)d_in[3];
  const float* enc_bih  = (const float*)d_in[4];
  const float* enc_bhh  = (const float*)d_in[5];
  const float* att_w    = (const float*)d_in[6];
  const float* att_b    = (const float*)d_in[7];
  const float* dec_Wih  = (const float*)d_in[8];
  const float* dec_Whh  = (const float*)d_in[9];
  const float* dec_bih  = (const float*)d_in[10];
  const float* dec_bhh  = (const float*)d_in[11];
  const float* out_W    = (const float*)d_in[12];
  const float* out_b    = (const float*)d_in[13];
  float* out = (float*)d_out;

  // workspace carve-up
  float* p = (float*)d_ws;
  float* Gienc  = p; p += NS * NB * G3;          // fp32, dead after encoder
  float* Gdec   = p; p += NL * NB * G3;
  float* escoreT = p; p += NB * NS;
  __hip_bfloat16* q = (__hip_bfloat16*)p;
  __hip_bfloat16* enchBb = q; q += (size_t)NB * NS * NH;
  __hip_bfloat16* Wcat_e = q; q += (size_t)3 * 256 * 256;
  __hip_bfloat16* Wcat_d = q; q += (size_t)6 * 256 * 256;
  __hip_bfloat16* Xb     = q; q += (size_t)4096 * KP2;
  __hip_bfloat16* Wencb  = q; q += (size_t)G3 * KP2;
  __hip_bfloat16* Woutb  = q; q += (size_t)NOUTP * NH;
  __hip_bfloat16* dechb  = q; q += (size_t)NL * NB * NH;
  // ENCWT [64 b][768 c][64 s] bf16 (6.3 MB) aliases Gienc (12.6 MB)
  __hip_bfloat16* ENCWT  = (__hip_bfloat16*)Gienc;
  // split-K partials (50 MB fp32) in d_out scratch (overwritten later)
  float* Pout = (float*)d_out;

  // prep (independent)
  k_cvt_pad<<<4096, 256, 0, stream>>>(X, Xb, 4096, NVIN, KP2, 1);
  k_cvt_pad<<<G3, 256, 0, stream>>>(enc_Wih, Wencb, G3, NVIN, KP2, 1);
  k_cvt_pad<<<NOUTP, 256, 0, stream>>>(out_W, Woutb, NVOUT, NH, NH, 1);
  k_wpack<<<768, 256, 0, stream>>>(enc_Whh, NH, enc_Whh, NH, Wcat_e, 3 * 65536);
  k_wpack<<<1536, 256, 0, stream>>>(dec_Wih, NH + NVOUT, dec_Whh, NH, Wcat_d, 6 * 65536);
  k_pregather<<<NL * NB, 256, 0, stream>>>(dec_Wih, dec_bih, gt, Gdec);

  k_gemm_encS<<<dim3(6, 32, 4), 256, 0, stream>>>(Xb, Wencb, Pout);
  k_reduce4<<<3072, 256, 0, stream>>>((const float4*)Pout, enc_bih, (float4*)Gienc);
  k_encoder4<<<64, 512, 0, stream>>>(Gienc, Wcat_e, enc_bhh, att_w, enchBb, escoreT);
  k_gemm_encw<<<dim3(6, 32), 256, 0, stream>>>(enchBb, Wcat_d, ENCWT);
  k_decoder5<<<64, 512, 0, stream>>>(Gdec, Wcat_d, dec_bhh, enchBb, ENCWT,
                                     escoreT, att_w, att_b, dechb);
  k_gemm_outS<<<dim3(79, 32), 256, 0, stream>>>(dechb, Woutb, out_b, out);
  k_logsoftmax<<<NB * NL, 256, 0, stream>>>(out);
}

// Round 9
// 838.770 us; speedup vs baseline: 3.2158x; 1.0358x over previous
//
#include <hip/hip_runtime.h>
#include <hip/hip_bf16.h>
#include <math.h>

// Problem dims (fixed by the reference)
#define NB 64      // batch
#define NS 64      // encoder steps
#define NL 64      // decoder steps
#define NH 256     // hidden
#define G3 768     // 3*NH (gates r,z,n)
#define NVIN 10000
#define NVOUT 10000
#define KP2 10240   // NVIN padded (4 splits x 40 x BK=64)
#define NOUTP 10112 // NVOUT padded to 128 for out GEMM

typedef __attribute__((ext_vector_type(8))) short bf16x8;  // 8 bf16 (4 VGPRs)
typedef __attribute__((ext_vector_type(4))) float f32x4;   // MFMA accumulator
typedef __attribute__((ext_vector_type(4))) unsigned int u32x4;

// async global->LDS, 16B per lane (dest must be wave-uniform base + lane*16)
__device__ __forceinline__ void gld_lds16(const __hip_bfloat16* g, __hip_bfloat16* l) {
  __builtin_amdgcn_global_load_lds(
      (const __attribute__((address_space(1))) unsigned int*)(const void*)g,
      (__attribute__((address_space(3))) unsigned int*)(void*)l, 16, 0, 0);
}

__device__ __forceinline__ unsigned int f2bf(float f) {  // RNE fp32->bf16 bits
  unsigned int u = __float_as_uint(f);
  return (u + 0x7fff + ((u >> 16) & 1)) >> 16;
}

__device__ __forceinline__ float fast_tanh(float x) {   // tanh via v_exp_f32
  float e = __expf(-2.f * x);
  return (1.f - e) / (1.f + e);
}

// ---------------------------------------------------------------------------
// fp32 -> bf16 convert with padding; swz=1 pre-swizzles columns within each
// 64-group by ((row&7)<<3) so linear global_load_lds + XOR'd ds_read is
// conflict-free (T2/m173: swizzle the SOURCE, keep LDS dest linear).
// ---------------------------------------------------------------------------
__global__ __launch_bounds__(256) void k_cvt_pad(
    const float* __restrict__ in, __hip_bfloat16* __restrict__ out,
    int in_rows, int in_cols, int out_cols, int swz) {
  int r = blockIdx.x;
  const float* src = in + (size_t)r * in_cols;
  __hip_bfloat16* dst = out + (size_t)r * out_cols;
  bool live = r < in_rows;
  int sx = swz ? ((r & 7) << 3) : 0;
  for (int c = threadIdx.x * 4; c < out_cols; c += 1024) {
    int cc = (c & ~63) | ((c & 63) ^ sx);
    __hip_bfloat16 v[4];
    if (live && cc + 3 < in_cols) {
      float4 f = *(const float4*)(src + cc);
      v[0] = __float2bfloat16(f.x); v[1] = __float2bfloat16(f.y);
      v[2] = __float2bfloat16(f.z); v[3] = __float2bfloat16(f.w);
    } else {
      v[0] = v[1] = v[2] = v[3] = __float2bfloat16(0.f);
    }
    *(ushort4*)(dst + c) = *(const ushort4*)v;
  }
}

// ---------------------------------------------------------------------------
// Pack recurrent weights to bf16 Wcat[f][c][k].
// ---------------------------------------------------------------------------
__global__ __launch_bounds__(256) void k_wpack(
    const float* __restrict__ srcA, int strideA,
    const float* __restrict__ srcB, int strideB,
    __hip_bfloat16* __restrict__ out, int total) {
  int idx = blockIdx.x * 256 + threadIdx.x;
  if (idx >= total) return;
  int k = idx & 255, c = (idx >> 8) & 255, f = idx >> 16;
  float v = (f < 3) ? srcA[(size_t)(f * 256 + c) * strideA + k]
                    : srcB[(size_t)((f - 3) * 256 + c) * strideB + k];
  out[idx] = __float2bfloat16(v);
}

// ---------------------------------------------------------------------------
// Enc GEMM, split-K (see R7): P[z] partials, reduced by k_reduce4.
// ---------------------------------------------------------------------------
__global__ __launch_bounds__(256) void k_gemm_encS(
    const __hip_bfloat16* __restrict__ A, const __hip_bfloat16* __restrict__ B,
    float* __restrict__ P) {
  __shared__ __hip_bfloat16 As[128][64];
  __shared__ __hip_bfloat16 Bs[128][64];
  int t = threadIdx.x;
  int wid = t >> 6, lane = t & 63;
  int m0 = blockIdx.y * 128, n0 = blockIdx.x * 128;
  int wr = wid >> 1, wc = wid & 1;
  int r16 = lane & 15, hi16 = lane >> 4;
  int xr = (r16 & 7) << 4;
  f32x4 acc[4][4] = {};
  int kbeg = blockIdx.z * 2560;
  for (int ks = 0; ks < 40; ++ks) {
    int k0 = kbeg + ks * 64;
    __syncthreads();
#pragma unroll
    for (int is = 0; is < 4; ++is) {
      int off = is * 4096 + t * 16;
      int r = off >> 7, e = (off & 127) >> 1;
      gld_lds16(A + (size_t)(m0 + r) * KP2 + k0 + e, &As[r][e]);
      gld_lds16(B + (size_t)(n0 + r) * KP2 + k0 + e, &Bs[r][e]);
    }
    __syncthreads();
    const char* ab = (const char*)As;
    const char* bb = (const char*)Bs;
#pragma unroll
    for (int kk = 0; kk < 2; ++kk) {
      int ko = kk * 64 + hi16 * 16;
      bf16x8 af[4], bfr[4];
#pragma unroll
      for (int i = 0; i < 4; ++i) {
        af[i]  = *(const bf16x8*)(ab + (wr * 64 + i * 16 + r16) * 128 + (ko ^ xr));
        bfr[i] = *(const bf16x8*)(bb + (wc * 64 + i * 16 + r16) * 128 + (ko ^ xr));
      }
#pragma unroll
      for (int i = 0; i < 4; ++i)
#pragma unroll
        for (int j = 0; j < 4; ++j)
          acc[i][j] = __builtin_amdgcn_mfma_f32_16x16x32_bf16(af[i], bfr[j], acc[i][j], 0, 0, 0);
    }
  }
  float* Pz = P + (size_t)blockIdx.z * 4096 * G3;
#pragma unroll
  for (int i = 0; i < 4; ++i)
#pragma unroll
    for (int j = 0; j < 4; ++j) {
      int ccol = n0 + wc * 64 + j * 16 + r16;
#pragma unroll
      for (int q = 0; q < 4; ++q) {
        int crow = m0 + wr * 64 + i * 16 + hi16 * 4 + q;
        Pz[(size_t)crow * G3 + ccol] = acc[i][j][q];
      }
    }
}

// Gienc = P0+P1+P2+P3 + bias
__global__ __launch_bounds__(256) void k_reduce4(
    const float4* __restrict__ P, const float* __restrict__ bias,
    float4* __restrict__ G) {
  int idx = blockIdx.x * 256 + threadIdx.x;
  float4 a = P[idx], b = P[idx + 786432], c = P[idx + 2 * 786432],
         d = P[idx + 3 * 786432];
  float4 bs = *(const float4*)(bias + (idx % 192) * 4);
  float4 o;
  o.x = a.x + b.x + c.x + d.x + bs.x;
  o.y = a.y + b.y + c.y + d.y + bs.y;
  o.z = a.z + b.z + c.z + d.z + bs.z;
  o.w = a.w + b.w + c.w + d.w + bs.w;
  G[idx] = o;
}

// ---------------------------------------------------------------------------
// Out GEMM (BK=64 + swizzle, see R7).
// ---------------------------------------------------------------------------
__global__ __launch_bounds__(256) void k_gemm_outS(
    const __hip_bfloat16* __restrict__ A, const __hip_bfloat16* __restrict__ B,
    const float* __restrict__ bias, float* __restrict__ C) {
  __shared__ __hip_bfloat16 As[128][64];
  __shared__ __hip_bfloat16 Bs[128][64];
  int t = threadIdx.x;
  int wid = t >> 6, lane = t & 63;
  int m0 = blockIdx.y * 128, n0 = blockIdx.x * 128;
  int wr = wid >> 1, wc = wid & 1;
  int r16 = lane & 15, hi16 = lane >> 4;
  int xr = (r16 & 7) << 4;
  f32x4 acc[4][4] = {};
  for (int k0 = 0; k0 < NH; k0 += 64) {
    __syncthreads();
#pragma unroll
    for (int is = 0; is < 4; ++is) {
      int off = is * 4096 + t * 16;
      int r = off >> 7, e = (off & 127) >> 1;
      gld_lds16(A + (size_t)(m0 + r) * NH + k0 + e, &As[r][e]);
      gld_lds16(B + (size_t)(n0 + r) * NH + k0 + e, &Bs[r][e]);
    }
    __syncthreads();
    const char* ab = (const char*)As;
    const char* bb = (const char*)Bs;
#pragma unroll
    for (int kk = 0; kk < 2; ++kk) {
      int ko = kk * 64 + hi16 * 16;
      bf16x8 af[4], bfr[4];
#pragma unroll
      for (int i = 0; i < 4; ++i) {
        af[i]  = *(const bf16x8*)(ab + (wr * 64 + i * 16 + r16) * 128 + (ko ^ xr));
        bfr[i] = *(const bf16x8*)(bb + (wc * 64 + i * 16 + r16) * 128 + (ko ^ xr));
      }
#pragma unroll
      for (int i = 0; i < 4; ++i)
#pragma unroll
        for (int j = 0; j < 4; ++j)
          acc[i][j] = __builtin_amdgcn_mfma_f32_16x16x32_bf16(af[i], bfr[j], acc[i][j], 0, 0, 0);
    }
  }
#pragma unroll
  for (int i = 0; i < 4; ++i)
#pragma unroll
    for (int j = 0; j < 4; ++j) {
      int ccol = n0 + wc * 64 + j * 16 + r16;
      if (ccol < NVOUT) {
        float bs = bias[ccol];
#pragma unroll
        for (int q = 0; q < 4; ++q) {
          int crow = m0 + wr * 64 + i * 16 + hi16 * 4 + q;  // = l*64+b
          int l = crow >> 6, b = crow & 63;
          C[((size_t)b * NL + l) * NVOUT + ccol] = acc[i][j][q] + bs;
        }
      }
    }
}

// ---------------------------------------------------------------------------
// ENCW GEMM -> TRANSPOSED, swizzled output: ENCWT[b][c][s ^ ((c&7)<<3)] =
// sum_k ench[b*64+s][k] * Wih_ctx[c][k]. Decoder stages [c][s] slices
// linearly and reads with the matching XOR (bank-conflict-free B-frags).
// ---------------------------------------------------------------------------
__global__ __launch_bounds__(256) void k_gemm_encw(
    const __hip_bfloat16* __restrict__ A, const __hip_bfloat16* __restrict__ B,
    __hip_bfloat16* __restrict__ CT) {
  __shared__ __hip_bfloat16 As[128][32];
  __shared__ __hip_bfloat16 Bs[128][32];
  int t = threadIdx.x;
  int wid = t >> 6, lane = t & 63;
  int m0 = blockIdx.y * 128, n0 = blockIdx.x * 128;
  int wr = wid >> 1, wc = wid & 1;
  f32x4 acc[4][4] = {};
  for (int k0 = 0; k0 < NH; k0 += 32) {
    __syncthreads();
#pragma unroll
    for (int is = 0; is < 2; ++is) {
      int off = is * 4096 + wid * 1024 + lane * 16;
      int r = off >> 6, cb = (off & 63) >> 1;
      gld_lds16(A + (size_t)(m0 + r) * NH + k0 + cb, &As[r][cb]);
      gld_lds16(B + (size_t)(n0 + r) * NH + k0 + cb, &Bs[r][cb]);
    }
    __syncthreads();
    int r16 = lane & 15, kb = (lane >> 4) * 8;
    bf16x8 af[4], bfr[4];
#pragma unroll
    for (int i = 0; i < 4; ++i) {
      af[i]  = *(const bf16x8*)&As[wr * 64 + i * 16 + r16][kb];
      bfr[i] = *(const bf16x8*)&Bs[wc * 64 + i * 16 + r16][kb];
    }
#pragma unroll
    for (int i = 0; i < 4; ++i)
#pragma unroll
      for (int j = 0; j < 4; ++j)
        acc[i][j] = __builtin_amdgcn_mfma_f32_16x16x32_bf16(af[i], bfr[j], acc[i][j], 0, 0, 0);
  }
  int r16 = lane & 15, rg = lane >> 4;
#pragma unroll
  for (int i = 0; i < 4; ++i)
#pragma unroll
    for (int j = 0; j < 4; ++j) {
      int ccol = n0 + wc * 64 + j * 16 + r16;
#pragma unroll
      for (int q = 0; q < 4; ++q) {
        int crow = m0 + wr * 64 + i * 16 + rg * 4 + q;   // = b*64+s
        int bb = crow >> 6, ss = crow & 63;
        CT[((size_t)bb * G3 + ccol) * 64 + (ss ^ ((ccol & 7) << 3))] =
            __float2bfloat16(acc[i][j][q]);
      }
    }
}

// ---------------------------------------------------------------------------
// Pre-gather decoder one-hot input term: Gdec = bih + onehot column.
// ---------------------------------------------------------------------------
__global__ __launch_bounds__(256) void k_pregather(
    const float* __restrict__ Wih, const float* __restrict__ bih,
    const int* __restrict__ gt, float* __restrict__ Gdec) {
  int ib = blockIdx.x;              // i*64+b
  int i = ib >> 6, b = ib & 63;
  int tok = (i > 0) ? gt[b * NL + (i - 1)] : -1;
  for (int g = threadIdx.x; g < G3; g += 256) {
    float v = bih[g];
    if (tok >= 0) v += Wih[(size_t)g * (NH + NVOUT) + NH + tok];
    Gdec[(size_t)ib * G3 + g] = v;
  }
}

// ---------------------------------------------------------------------------
// Encoder scan: 64 WGs x 512 thr, one batch/WG, Whh VGPR-resident (192 regs).
// __launch_bounds__(512, 2): min 2 waves/EU -> 256 VGPR cap. Plain (512) let
// the compiler's occupancy heuristic cap at 128 and SPILL the weight frags to
// scratch (R5-R8: VGPR_Count stuck at 64/128, step time scaled with spill).
// ---------------------------------------------------------------------------
__global__ __launch_bounds__(512, 2) void k_encoder4(
    const float* __restrict__ Gi, const __hip_bfloat16* __restrict__ Wcat,
    const float* __restrict__ bhh, const float* __restrict__ att_w,
    __hip_bfloat16* __restrict__ enchB, float* __restrict__ escoreT) {
  __shared__ float h32[2][256];
  __shared__ __hip_bfloat16 hbf[2][256];
  int t = threadIdx.x, w = t >> 6, lane = t & 63;
  int b = blockIdx.x;
  int r16 = lane & 15, hi16 = lane >> 4;
  bf16x8 wv[3][2][8];
#pragma unroll
  for (int f = 0; f < 3; ++f)
#pragma unroll
    for (int fc = 0; fc < 2; ++fc)
#pragma unroll
      for (int kf = 0; kf < 8; ++kf)
        wv[f][fc][kf] = *(const bf16x8*)(Wcat +
            (((size_t)f * 256 + w * 32 + fc * 16 + r16) * 256 + kf * 32 + hi16 * 8));
  float aw[4];
#pragma unroll
  for (int q = 0; q < 4; ++q) aw[q] = att_w[256 + lane + q * 64];   // w_enc
  if (t < 256) {
    h32[0][t] = 0.f; h32[1][t] = 0.f;
    hbf[0][t] = __float2bfloat16(0.f); hbf[1][t] = __float2bfloat16(0.f);
  }
  __syncthreads();
  int cur = 0;
  for (int s = 0; s < NS; ++s) {
    float gd[3][2];
    if (hi16 == 0) {
#pragma unroll
      for (int f = 0; f < 3; ++f)
#pragma unroll
        for (int fc = 0; fc < 2; ++fc)
          gd[f][fc] = Gi[((size_t)b * 64 + s) * G3 + f * 256 + w * 32 + fc * 16 + lane];
    }
    const char* hb = (const char*)&hbf[cur][0];
    f32x4 acc[3][2] = {};
#pragma unroll
    for (int half = 0; half < 2; ++half) {
      bf16x8 ah[4];
#pragma unroll
      for (int kf = 0; kf < 4; ++kf)
        ah[kf] = *(const bf16x8*)(hb + (half * 4 + kf) * 64 + hi16 * 16);  // broadcast
#pragma unroll
      for (int f = 0; f < 3; ++f)
#pragma unroll
        for (int fc = 0; fc < 2; ++fc)
#pragma unroll
          for (int kf = 0; kf < 4; ++kf)
            acc[f][fc] = __builtin_amdgcn_mfma_f32_16x16x32_bf16(
                ah[kf], wv[f][fc][half * 4 + kf], acc[f][fc], 0, 0, 0);
    }
    if (hi16 == 0) {
      int nxt = cur ^ 1;
#pragma unroll
      for (int fc = 0; fc < 2; ++fc) {
        int c = w * 32 + fc * 16 + lane;
        float rr = 1.f / (1.f + __expf(-(gd[0][fc] + acc[0][fc][0] + bhh[c])));
        float zz = 1.f / (1.f + __expf(-(gd[1][fc] + acc[1][fc][0] + bhh[256 + c])));
        float nn = fast_tanh(gd[2][fc] + rr * (acc[2][fc][0] + bhh[512 + c]));
        float hn = (1.f - zz) * nn + zz * h32[cur][c];
        h32[nxt][c] = hn;
        hbf[nxt][c] = __float2bfloat16(hn);
        enchB[((size_t)b * 64 + s) * 256 + c] = __float2bfloat16(hn);
      }
    }
    __syncthreads();
    cur ^= 1;
    if (w == 0) {   // escore on just-written h
      float p = h32[cur][lane] * aw[0] + h32[cur][lane + 64] * aw[1]
              + h32[cur][lane + 128] * aw[2] + h32[cur][lane + 192] * aw[3];
#pragma unroll
      for (int off = 32; off; off >>= 1) p += __shfl_xor(p, off, 64);
      if (lane == 0) escoreT[(size_t)b * 64 + s] = p;
    }
  }
}

// ---------------------------------------------------------------------------
// Decoder scan, 1 barrier/step. 64 WGs x 512 thr, one batch/WG.
// __launch_bounds__(512, 2) -> 256 VGPR cap (see encoder note). r,z Whh
// panels VGPR-resident (128); n panel streamed from L2 (LICM defeated);
// gi via MFMA from swizzled LDS fused into the r/z accumulators.
// ---------------------------------------------------------------------------
__global__ __launch_bounds__(512, 2) void k_decoder5(
    const float* __restrict__ Gdec, const __hip_bfloat16* __restrict__ Wcat6,
    const float* __restrict__ bhh, const __hip_bfloat16* __restrict__ enchB,
    const __hip_bfloat16* __restrict__ ENCWT, const float* __restrict__ escoreT,
    const float* __restrict__ att_w, const float* __restrict__ att_b,
    __hip_bfloat16* __restrict__ dechb) {
  __shared__ __hip_bfloat16 encwT[G3][64];    // 96 KB, [c][s^((c&7)<<3)]
  __shared__ __hip_bfloat16 hbf[2][256];      // 1 KB
  __shared__ float h32[2][256];               // 2 KB
  int t = threadIdx.x, w = t >> 6, lane = t & 63;
  int b = blockIdx.x;
  int r16 = lane & 15, hi16 = lane >> 4;
  int cw = w * 32;
  // stage ENCWT b-slice (96 KB contiguous, swizzle pre-baked in global)
  {
    const char* srcb = (const char*)(ENCWT + (size_t)b * G3 * 64);
    char* dstb = (char*)&encwT[0][0];
#pragma unroll
    for (int is = 0; is < 12; ++is) {
      int off = is * 8192 + t * 16;
      gld_lds16((const __hip_bfloat16*)(srcb + off), (__hip_bfloat16*)(dstb + off));
    }
  }
  // r,z Whh panels resident (panels 3,4 of Wcat6) = 128 VGPRs
  bf16x8 wv[2][2][8];
#pragma unroll
  for (int f = 0; f < 2; ++f)
#pragma unroll
    for (int fc = 0; fc < 2; ++fc)
#pragma unroll
      for (int kf = 0; kf < 8; ++kf)
        wv[f][fc][kf] = *(const bf16x8*)(Wcat6 +
            (((size_t)(3 + f) * 256 + cw + fc * 16 + r16) * 256 + kf * 32 + hi16 * 8));
  float aw[4];
#pragma unroll
  for (int q = 0; q < 4; ++q) aw[q] = att_w[lane + q * 64];   // w_dec
  float attb = att_b[0];
  float esc = escoreT[(size_t)b * 64 + lane];
  float bh0[2], bh1[2], bh2[2];
#pragma unroll
  for (int fc = 0; fc < 2; ++fc) {
    bh0[fc] = bhh[cw + fc * 16 + r16];
    bh1[fc] = bhh[256 + cw + fc * 16 + r16];
    bh2[fc] = bhh[512 + cw + fc * 16 + r16];
  }
  if (t < 256) {
    float v = __bfloat162float(enchB[((size_t)b * 64 + 63) * 256 + t]);
    h32[0][t] = v;  hbf[0][t] = __float2bfloat16(v);
    h32[1][t] = 0.f; hbf[1][t] = __float2bfloat16(0.f);
  }
  __syncthreads();
  float hp[2];   // h in-register on lanes<16 (col = cw + fc*16 + r16)
  hp[0] = h32[0][cw + r16];
  hp[1] = h32[0][cw + 16 + r16];
  int bs3 = (b & 7) << 3;
  unsigned long long wna = (unsigned long long)(Wcat6 + (size_t)5 * 256 * 256);
  int cur = 0;
  for (int i = 0; i < NL; ++i) {
    asm volatile("" : "+v"(wna));   // opaque pointer: stop LICM hoisting wn loads
    const __hip_bfloat16* wnp = (const __hip_bfloat16*)wna;
    // Gdec prefetch (lanes<16)
    float gd0[2], gd1[2], gd2[2];
    if (hi16 == 0) {
      const float* gp = Gdec + ((size_t)i * 64 + b) * G3;
#pragma unroll
      for (int fc = 0; fc < 2; ++fc) {
        gd0[fc] = gp[cw + fc * 16 + r16];
        gd1[fc] = gp[256 + cw + fc * 16 + r16];
        gd2[fc] = gp[512 + cw + fc * 16 + r16];
      }
    }
    // --- softmax, replicated on every wave (no LDS, no barrier) ---
    float p = h32[cur][lane] * aw[0] + h32[cur][lane + 64] * aw[1]
            + h32[cur][lane + 128] * aw[2] + h32[cur][lane + 192] * aw[3];
#pragma unroll
    for (int off = 32; off; off >>= 1) p += __shfl_xor(p, off, 64);
    float lg = fmaxf(esc + p + attb, 0.f);
    float mx = lg;
#pragma unroll
    for (int off = 32; off; off >>= 1) mx = fmaxf(mx, __shfl_xor(mx, off, 64));
    float e = __expf(lg - mx);
    float sm = e;
#pragma unroll
    for (int off = 32; off; off >>= 1) sm += __shfl_xor(sm, off, 64);
    float wl = e / sm;               // = wts[lane]
    // --- wts -> A-frags (row-broadcast: all 16 rows get the same k-slice) ---
    bf16x8 af_[2];
#pragma unroll
    for (int kf = 0; kf < 2; ++kf) {
      u32x4 tmp;
#pragma unroll
      for (int j = 0; j < 4; ++j) {
        int src = hi16 * 8 + kf * 32 + 2 * j;
        tmp[j] = f2bf(__shfl(wl, src, 64)) | (f2bf(__shfl(wl, src + 1, 64)) << 16);
      }
      af_[kf] = __builtin_bit_cast(bf16x8, tmp);
    }
    // --- gi MFMAs (B from swizzled LDS), fused into r/z accumulators ---
    f32x4 acc_rz[2][2] = {};
    f32x4 ghn2[2] = {};
    f32x4 gin2[2] = {};
    const char* eb = (const char*)&encwT[0][0];
#pragma unroll
    for (int g = 0; g < 3; ++g)
#pragma unroll
      for (int fc = 0; fc < 2; ++fc) {
        int cloc = g * 256 + cw + fc * 16 + r16;
        int xb = (cloc & 7) << 4;
#pragma unroll
        for (int kf = 0; kf < 2; ++kf) {
          bf16x8 bfrag = *(const bf16x8*)(eb + cloc * 128 + ((kf * 64 + hi16 * 16) ^ xb));
          if (g < 2) acc_rz[g][fc] = __builtin_amdgcn_mfma_f32_16x16x32_bf16(af_[kf], bfrag, acc_rz[g][fc], 0, 0, 0);
          else       gin2[fc]     = __builtin_amdgcn_mfma_f32_16x16x32_bf16(af_[kf], bfrag, gin2[fc], 0, 0, 0);
        }
      }
    // --- gh MFMAs: r,z from resident panels; n streamed from L2 ---
    const char* hb = (const char*)&hbf[cur][0];
#pragma unroll
    for (int half = 0; half < 2; ++half) {
      bf16x8 ah[4];
#pragma unroll
      for (int kf = 0; kf < 4; ++kf)
        ah[kf] = *(const bf16x8*)(hb + (half * 4 + kf) * 64 + hi16 * 16);  // broadcast
      bf16x8 wn[2][4];
#pragma unroll
      for (int fc = 0; fc < 2; ++fc)
#pragma unroll
        for (int kf = 0; kf < 4; ++kf)
          wn[fc][kf] = *(const bf16x8*)(wnp +
              ((size_t)(cw + fc * 16 + r16) * 256 + (half * 4 + kf) * 32 + hi16 * 8));
#pragma unroll
      for (int f = 0; f < 2; ++f)
#pragma unroll
        for (int fc = 0; fc < 2; ++fc)
#pragma unroll
          for (int kf = 0; kf < 4; ++kf)
            acc_rz[f][fc] = __builtin_amdgcn_mfma_f32_16x16x32_bf16(
                ah[kf], wv[f][fc][half * 4 + kf], acc_rz[f][fc], 0, 0, 0);
#pragma unroll
      for (int fc = 0; fc < 2; ++fc)
#pragma unroll
        for (int kf = 0; kf < 4; ++kf)
          ghn2[fc] = __builtin_amdgcn_mfma_f32_16x16x32_bf16(
              ah[kf], wn[fc][kf], ghn2[fc], 0, 0, 0);
    }
    // --- gates + h update, all in-register (lanes<16) ---
    if (hi16 == 0) {
      int nxt = cur ^ 1;
#pragma unroll
      for (int fc = 0; fc < 2; ++fc) {
        int c = cw + fc * 16 + r16;
        float rr = 1.f / (1.f + __expf(-(gd0[fc] + acc_rz[0][fc][0] + bh0[fc])));
        float zz = 1.f / (1.f + __expf(-(gd1[fc] + acc_rz[1][fc][0] + bh1[fc])));
        float nn = fast_tanh(gd2[fc] + gin2[fc][0] + rr * (ghn2[fc][0] + bh2[fc]));
        float hn = (1.f - zz) * nn + zz * hp[fc];
        hp[fc] = hn;
        h32[nxt][c] = hn;
        hbf[nxt][c] = __float2bfloat16(hn);
        int cs = (c & ~63) | ((c & 63) ^ bs3);   // pre-swizzle for out GEMM
        dechb[((size_t)i * 64 + b) * 256 + cs] = __float2bfloat16(hn);
      }
    }
    __syncthreads();
    cur ^= 1;
  }
}

// ---------------------------------------------------------------------------
// Log-softmax, register-resident single read + single write (one WG/row).
// ---------------------------------------------------------------------------
__global__ __launch_bounds__(256) void k_logsoftmax(float* __restrict__ out) {
  float* x = out + (size_t)blockIdx.x * NVOUT;
  __shared__ float red[256];
  int t = threadIdx.x;
  float4 v[10];
  float mx = -1e30f;
#pragma unroll
  for (int ii = 0; ii < 10; ++ii) {
    int slot = ii * 256 + t;
    if (slot < 2500) {
      v[ii] = *(const float4*)(x + slot * 4);
      mx = fmaxf(mx, fmaxf(fmaxf(v[ii].x, v[ii].y), fmaxf(v[ii].z, v[ii].w)));
    }
  }
  red[t] = mx; __syncthreads();
  for (int off = 128; off; off >>= 1) {
    if (t < off) red[t] = fmaxf(red[t], red[t + off]);
    __syncthreads();
  }
  mx = red[0]; __syncthreads();
  float sm = 0.f;
#pragma unroll
  for (int ii = 0; ii < 10; ++ii) {
    int slot = ii * 256 + t;
    if (slot < 2500)
      sm += __expf(v[ii].x - mx) + __expf(v[ii].y - mx)
          + __expf(v[ii].z - mx) + __expf(v[ii].w - mx);
  }
  red[t] = sm; __syncthreads();
  for (int off = 128; off; off >>= 1) {
    if (t < off) red[t] += red[t + off];
    __syncthreads();
  }
  float lse = mx + logf(red[0]);
#pragma unroll
  for (int ii = 0; ii < 10; ++ii) {
    int slot = ii * 256 + t;
    if (slot < 2500) {
      float4 o; o.x = v[ii].x - lse; o.y = v[ii].y - lse;
      o.z = v[ii].z - lse; o.w = v[ii].w - lse;
      *(float4*)(x + slot * 4) = o;
    }
  }
}

// ---------------------------------------------------------------------------
extern "C" void kernel_launch(void* const* d_in, const int* in_sizes, int n_in,
                              void* d_out, int out_size, void* d_ws, size_t ws_size,
                              hipStream_t stream) {
  const float* X        = (const float*)d_in[0];
  const int*   gt       = (const int*)  d_in[1];
  const float* enc_Wih  = (const float*)d_in[2];
  const float* enc_Whh  = (const float*)d_in[3];
  const float* enc_bih  = (const float*)d_in[4];
  const float* enc_bhh  = (const float*)d_in[5];
  const float* att_w    = (const float*)d_in[6];
  const float* att_b    = (const float*)d_in[7];
  const float* dec_Wih  = (const float*)d_in[8];
  const float* dec_Whh  = (const float*)d_in[9];
  const float* dec_bih  = (const float*)d_in[10];
  const float* dec_bhh  = (const float*)d_in[11];
  const float* out_W    = (const float*)d_in[12];
  const float* out_b    = (const float*)d_in[13];
  float* out = (float*)d_out;

  // workspace carve-up
  float* p = (float*)d_ws;
  float* Gienc  = p; p += NS * NB * G3;          // fp32, dead after encoder
  float* Gdec   = p; p += NL * NB * G3;
  float* escoreT = p; p += NB * NS;
  __hip_bfloat16* q = (__hip_bfloat16*)p;
  __hip_bfloat16* enchBb = q; q += (size_t)NB * NS * NH;
  __hip_bfloat16* Wcat_e = q; q += (size_t)3 * 256 * 256;
  __hip_bfloat16* Wcat_d = q; q += (size_t)6 * 256 * 256;
  __hip_bfloat16* Xb     = q; q += (size_t)4096 * KP2;
  __hip_bfloat16* Wencb  = q; q += (size_t)G3 * KP2;
  __hip_bfloat16* Woutb  = q; q += (size_t)NOUTP * NH;
  __hip_bfloat16* dechb  = q; q += (size_t)NL * NB * NH;
  // ENCWT [64 b][768 c][64 s] bf16 (6.3 MB) aliases Gienc (12.6 MB)
  __hip_bfloat16* ENCWT  = (__hip_bfloat16*)Gienc;
  // split-K partials (50 MB fp32) in d_out scratch (overwritten later)
  float* Pout = (float*)d_out;

  // prep (independent)
  k_cvt_pad<<<4096, 256, 0, stream>>>(X, Xb, 4096, NVIN, KP2, 1);
  k_cvt_pad<<<G3, 256, 0, stream>>>(enc_Wih, Wencb, G3, NVIN, KP2, 1);
  k_cvt_pad<<<NOUTP, 256, 0, stream>>>(out_W, Woutb, NVOUT, NH, NH, 1);
  k_wpack<<<768, 256, 0, stream>>>(enc_Whh, NH, enc_Whh, NH, Wcat_e, 3 * 65536);
  k_wpack<<<1536, 256, 0, stream>>>(dec_Wih, NH + NVOUT, dec_Whh, NH, Wcat_d, 6 * 65536);
  k_pregather<<<NL * NB, 256, 0, stream>>>(dec_Wih, dec_bih, gt, Gdec);

  k_gemm_encS<<<dim3(6, 32, 4), 256, 0, stream>>>(Xb, Wencb, Pout);
  k_reduce4<<<3072, 256, 0, stream>>>((const float4*)Pout, enc_bih, (float4*)Gienc);
  k_encoder4<<<64, 512, 0, stream>>>(Gienc, Wcat_e, enc_bhh, att_w, enchBb, escoreT);
  k_gemm_encw<<<dim3(6, 32), 256, 0, stream>>>(enchBb, Wcat_d, ENCWT);
  k_decoder5<<<64, 512, 0, stream>>>(Gdec, Wcat_d, dec_bhh, enchBb, ENCWT,
                                     escoreT, att_w, att_b, dechb);
  k_gemm_outS<<<dim3(79, 32), 256, 0, stream>>>(dechb, Woutb, out_b, out);
  k_logsoftmax<<<NB * NL, 256, 0, stream>>>(out);
}

// Round 10
// 789.375 us; speedup vs baseline: 3.4171x; 1.0626x over previous
//
#include <hip/hip_runtime.h>
#include <hip/hip_bf16.h>
#include <math.h>

// Problem dims (fixed by the reference)
#define NB 64      // batch
#define NS 64      // encoder steps
#define NL 64      // decoder steps
#define NH 256     // hidden
#define G3 768     // 3*NH (gates r,z,n)
#define NVIN 10000
#define NVOUT 10000
#define KP2 10240   // NVIN padded (4 splits x 40 x BK=64)
#define NOUTP 10112 // NVOUT padded to 128 for out GEMM

typedef __attribute__((ext_vector_type(8))) short bf16x8;  // 8 bf16 (4 VGPRs)
typedef __attribute__((ext_vector_type(4))) float f32x4;   // MFMA accumulator
typedef __attribute__((ext_vector_type(4))) unsigned int u32x4;

// async global->LDS, 16B per lane (dest must be wave-uniform base + lane*16)
__device__ __forceinline__ void gld_lds16(const __hip_bfloat16* g, __hip_bfloat16* l) {
  __builtin_amdgcn_global_load_lds(
      (const __attribute__((address_space(1))) unsigned int*)(const void*)g,
      (__attribute__((address_space(3))) unsigned int*)(void*)l, 16, 0, 0);
}

__device__ __forceinline__ unsigned int f2bf(float f) {  // RNE fp32->bf16 bits
  unsigned int u = __float_as_uint(f);
  return (u + 0x7fff + ((u >> 16) & 1)) >> 16;
}

__device__ __forceinline__ float fast_tanh(float x) {   // tanh via v_exp_f32
  float e = __expf(-2.f * x);
  return (1.f - e) / (1.f + e);
}

// ---------------------------------------------------------------------------
// fp32 -> bf16 convert with padding; swz=1 pre-swizzles columns within each
// 64-group by ((row&7)<<3) so linear global_load_lds + XOR'd ds_read is
// conflict-free (T2/m173: swizzle the SOURCE, keep LDS dest linear).
// ---------------------------------------------------------------------------
__global__ __launch_bounds__(256) void k_cvt_pad(
    const float* __restrict__ in, __hip_bfloat16* __restrict__ out,
    int in_rows, int in_cols, int out_cols, int swz) {
  int r = blockIdx.x;
  const float* src = in + (size_t)r * in_cols;
  __hip_bfloat16* dst = out + (size_t)r * out_cols;
  bool live = r < in_rows;
  int sx = swz ? ((r & 7) << 3) : 0;
  for (int c = threadIdx.x * 4; c < out_cols; c += 1024) {
    int cc = (c & ~63) | ((c & 63) ^ sx);
    __hip_bfloat16 v[4];
    if (live && cc + 3 < in_cols) {
      float4 f = *(const float4*)(src + cc);
      v[0] = __float2bfloat16(f.x); v[1] = __float2bfloat16(f.y);
      v[2] = __float2bfloat16(f.z); v[3] = __float2bfloat16(f.w);
    } else {
      v[0] = v[1] = v[2] = v[3] = __float2bfloat16(0.f);
    }
    *(ushort4*)(dst + c) = *(const ushort4*)v;
  }
}

// ---------------------------------------------------------------------------
// Pack recurrent weights to bf16 Wcat[f][c][k].
// ---------------------------------------------------------------------------
__global__ __launch_bounds__(256) void k_wpack(
    const float* __restrict__ srcA, int strideA,
    const float* __restrict__ srcB, int strideB,
    __hip_bfloat16* __restrict__ out, int total) {
  int idx = blockIdx.x * 256 + threadIdx.x;
  if (idx >= total) return;
  int k = idx & 255, c = (idx >> 8) & 255, f = idx >> 16;
  float v = (f < 3) ? srcA[(size_t)(f * 256 + c) * strideA + k]
                    : srcB[(size_t)((f - 3) * 256 + c) * strideB + k];
  out[idx] = __float2bfloat16(v);
}

// ---------------------------------------------------------------------------
// Enc GEMM, split-K (see R7): P[z] partials, reduced by k_reduce4.
// ---------------------------------------------------------------------------
__global__ __launch_bounds__(256) void k_gemm_encS(
    const __hip_bfloat16* __restrict__ A, const __hip_bfloat16* __restrict__ B,
    float* __restrict__ P) {
  __shared__ __hip_bfloat16 As[128][64];
  __shared__ __hip_bfloat16 Bs[128][64];
  int t = threadIdx.x;
  int wid = t >> 6, lane = t & 63;
  int m0 = blockIdx.y * 128, n0 = blockIdx.x * 128;
  int wr = wid >> 1, wc = wid & 1;
  int r16 = lane & 15, hi16 = lane >> 4;
  int xr = (r16 & 7) << 4;
  f32x4 acc[4][4] = {};
  int kbeg = blockIdx.z * 2560;
  for (int ks = 0; ks < 40; ++ks) {
    int k0 = kbeg + ks * 64;
    __syncthreads();
#pragma unroll
    for (int is = 0; is < 4; ++is) {
      int off = is * 4096 + t * 16;
      int r = off >> 7, e = (off & 127) >> 1;
      gld_lds16(A + (size_t)(m0 + r) * KP2 + k0 + e, &As[r][e]);
      gld_lds16(B + (size_t)(n0 + r) * KP2 + k0 + e, &Bs[r][e]);
    }
    __syncthreads();
    const char* ab = (const char*)As;
    const char* bb = (const char*)Bs;
#pragma unroll
    for (int kk = 0; kk < 2; ++kk) {
      int ko = kk * 64 + hi16 * 16;
      bf16x8 af[4], bfr[4];
#pragma unroll
      for (int i = 0; i < 4; ++i) {
        af[i]  = *(const bf16x8*)(ab + (wr * 64 + i * 16 + r16) * 128 + (ko ^ xr));
        bfr[i] = *(const bf16x8*)(bb + (wc * 64 + i * 16 + r16) * 128 + (ko ^ xr));
      }
#pragma unroll
      for (int i = 0; i < 4; ++i)
#pragma unroll
        for (int j = 0; j < 4; ++j)
          acc[i][j] = __builtin_amdgcn_mfma_f32_16x16x32_bf16(af[i], bfr[j], acc[i][j], 0, 0, 0);
    }
  }
  float* Pz = P + (size_t)blockIdx.z * 4096 * G3;
#pragma unroll
  for (int i = 0; i < 4; ++i)
#pragma unroll
    for (int j = 0; j < 4; ++j) {
      int ccol = n0 + wc * 64 + j * 16 + r16;
#pragma unroll
      for (int q = 0; q < 4; ++q) {
        int crow = m0 + wr * 64 + i * 16 + hi16 * 4 + q;
        Pz[(size_t)crow * G3 + ccol] = acc[i][j][q];
      }
    }
}

// Gienc = P0+P1+P2+P3 + bias
__global__ __launch_bounds__(256) void k_reduce4(
    const float4* __restrict__ P, const float* __restrict__ bias,
    float4* __restrict__ G) {
  int idx = blockIdx.x * 256 + threadIdx.x;
  float4 a = P[idx], b = P[idx + 786432], c = P[idx + 2 * 786432],
         d = P[idx + 3 * 786432];
  float4 bs = *(const float4*)(bias + (idx % 192) * 4);
  float4 o;
  o.x = a.x + b.x + c.x + d.x + bs.x;
  o.y = a.y + b.y + c.y + d.y + bs.y;
  o.z = a.z + b.z + c.z + d.z + bs.z;
  o.w = a.w + b.w + c.w + d.w + bs.w;
  G[idx] = o;
}

// ---------------------------------------------------------------------------
// Out GEMM (BK=64 + swizzle, see R7).
// ---------------------------------------------------------------------------
__global__ __launch_bounds__(256) void k_gemm_outS(
    const __hip_bfloat16* __restrict__ A, const __hip_bfloat16* __restrict__ B,
    const float* __restrict__ bias, float* __restrict__ C) {
  __shared__ __hip_bfloat16 As[128][64];
  __shared__ __hip_bfloat16 Bs[128][64];
  int t = threadIdx.x;
  int wid = t >> 6, lane = t & 63;
  int m0 = blockIdx.y * 128, n0 = blockIdx.x * 128;
  int wr = wid >> 1, wc = wid & 1;
  int r16 = lane & 15, hi16 = lane >> 4;
  int xr = (r16 & 7) << 4;
  f32x4 acc[4][4] = {};
  for (int k0 = 0; k0 < NH; k0 += 64) {
    __syncthreads();
#pragma unroll
    for (int is = 0; is < 4; ++is) {
      int off = is * 4096 + t * 16;
      int r = off >> 7, e = (off & 127) >> 1;
      gld_lds16(A + (size_t)(m0 + r) * NH + k0 + e, &As[r][e]);
      gld_lds16(B + (size_t)(n0 + r) * NH + k0 + e, &Bs[r][e]);
    }
    __syncthreads();
    const char* ab = (const char*)As;
    const char* bb = (const char*)Bs;
#pragma unroll
    for (int kk = 0; kk < 2; ++kk) {
      int ko = kk * 64 + hi16 * 16;
      bf16x8 af[4], bfr[4];
#pragma unroll
      for (int i = 0; i < 4; ++i) {
        af[i]  = *(const bf16x8*)(ab + (wr * 64 + i * 16 + r16) * 128 + (ko ^ xr));
        bfr[i] = *(const bf16x8*)(bb + (wc * 64 + i * 16 + r16) * 128 + (ko ^ xr));
      }
#pragma unroll
      for (int i = 0; i < 4; ++i)
#pragma unroll
        for (int j = 0; j < 4; ++j)
          acc[i][j] = __builtin_amdgcn_mfma_f32_16x16x32_bf16(af[i], bfr[j], acc[i][j], 0, 0, 0);
    }
  }
#pragma unroll
  for (int i = 0; i < 4; ++i)
#pragma unroll
    for (int j = 0; j < 4; ++j) {
      int ccol = n0 + wc * 64 + j * 16 + r16;
      if (ccol < NVOUT) {
        float bs = bias[ccol];
#pragma unroll
        for (int q = 0; q < 4; ++q) {
          int crow = m0 + wr * 64 + i * 16 + hi16 * 4 + q;  // = l*64+b
          int l = crow >> 6, b = crow & 63;
          C[((size_t)b * NL + l) * NVOUT + ccol] = acc[i][j][q] + bs;
        }
      }
    }
}

// ---------------------------------------------------------------------------
// ENCW GEMM -> TRANSPOSED, swizzled output: ENCWT[b][c][s ^ ((c&7)<<3)] =
// sum_k ench[b*64+s][k] * Wih_ctx[c][k].
// ---------------------------------------------------------------------------
__global__ __launch_bounds__(256) void k_gemm_encw(
    const __hip_bfloat16* __restrict__ A, const __hip_bfloat16* __restrict__ B,
    __hip_bfloat16* __restrict__ CT) {
  __shared__ __hip_bfloat16 As[128][32];
  __shared__ __hip_bfloat16 Bs[128][32];
  int t = threadIdx.x;
  int wid = t >> 6, lane = t & 63;
  int m0 = blockIdx.y * 128, n0 = blockIdx.x * 128;
  int wr = wid >> 1, wc = wid & 1;
  f32x4 acc[4][4] = {};
  for (int k0 = 0; k0 < NH; k0 += 32) {
    __syncthreads();
#pragma unroll
    for (int is = 0; is < 2; ++is) {
      int off = is * 4096 + wid * 1024 + lane * 16;
      int r = off >> 6, cb = (off & 63) >> 1;
      gld_lds16(A + (size_t)(m0 + r) * NH + k0 + cb, &As[r][cb]);
      gld_lds16(B + (size_t)(n0 + r) * NH + k0 + cb, &Bs[r][cb]);
    }
    __syncthreads();
    int r16 = lane & 15, kb = (lane >> 4) * 8;
    bf16x8 af[4], bfr[4];
#pragma unroll
    for (int i = 0; i < 4; ++i) {
      af[i]  = *(const bf16x8*)&As[wr * 64 + i * 16 + r16][kb];
      bfr[i] = *(const bf16x8*)&Bs[wc * 64 + i * 16 + r16][kb];
    }
#pragma unroll
    for (int i = 0; i < 4; ++i)
#pragma unroll
      for (int j = 0; j < 4; ++j)
        acc[i][j] = __builtin_amdgcn_mfma_f32_16x16x32_bf16(af[i], bfr[j], acc[i][j], 0, 0, 0);
  }
  int r16 = lane & 15, rg = lane >> 4;
#pragma unroll
  for (int i = 0; i < 4; ++i)
#pragma unroll
    for (int j = 0; j < 4; ++j) {
      int ccol = n0 + wc * 64 + j * 16 + r16;
#pragma unroll
      for (int q = 0; q < 4; ++q) {
        int crow = m0 + wr * 64 + i * 16 + rg * 4 + q;   // = b*64+s
        int bb = crow >> 6, ss = crow & 63;
        CT[((size_t)bb * G3 + ccol) * 64 + (ss ^ ((ccol & 7) << 3))] =
            __float2bfloat16(acc[i][j][q]);
      }
    }
}

// ---------------------------------------------------------------------------
// Pre-gather decoder one-hot input term: Gdec = bih + onehot column.
// ---------------------------------------------------------------------------
__global__ __launch_bounds__(256) void k_pregather(
    const float* __restrict__ Wih, const float* __restrict__ bih,
    const int* __restrict__ gt, float* __restrict__ Gdec) {
  int ib = blockIdx.x;              // i*64+b
  int i = ib >> 6, b = ib & 63;
  int tok = (i > 0) ? gt[b * NL + (i - 1)] : -1;
  for (int g = threadIdx.x; g < G3; g += 256) {
    float v = bih[g];
    if (tok >= 0) v += Wih[(size_t)g * (NH + NVOUT) + NH + tok];
    Gdec[(size_t)ib * G3 + g] = v;
  }
}

// ---------------------------------------------------------------------------
// Encoder scan: 64 WGs x 512 thr, one batch/WG, Whh VGPR-resident.
// ---------------------------------------------------------------------------
__global__ __launch_bounds__(512) void k_encoder4(
    const float* __restrict__ Gi, const __hip_bfloat16* __restrict__ Wcat,
    const float* __restrict__ bhh, const float* __restrict__ att_w,
    __hip_bfloat16* __restrict__ enchB, float* __restrict__ escoreT) {
  __shared__ float h32[2][256];
  __shared__ __hip_bfloat16 hbf[2][256];
  int t = threadIdx.x, w = t >> 6, lane = t & 63;
  int b = blockIdx.x;
  int r16 = lane & 15, hi16 = lane >> 4;
  bf16x8 wv[3][2][8];
#pragma unroll
  for (int f = 0; f < 3; ++f)
#pragma unroll
    for (int fc = 0; fc < 2; ++fc)
#pragma unroll
      for (int kf = 0; kf < 8; ++kf)
        wv[f][fc][kf] = *(const bf16x8*)(Wcat +
            (((size_t)f * 256 + w * 32 + fc * 16 + r16) * 256 + kf * 32 + hi16 * 8));
  float aw[4];
#pragma unroll
  for (int q = 0; q < 4; ++q) aw[q] = att_w[256 + lane + q * 64];   // w_enc
  if (t < 256) {
    h32[0][t] = 0.f; h32[1][t] = 0.f;
    hbf[0][t] = __float2bfloat16(0.f); hbf[1][t] = __float2bfloat16(0.f);
  }
  __syncthreads();
  int cur = 0;
  for (int s = 0; s < NS; ++s) {
    float gd[3][2];
    if (hi16 == 0) {
#pragma unroll
      for (int f = 0; f < 3; ++f)
#pragma unroll
        for (int fc = 0; fc < 2; ++fc)
          gd[f][fc] = Gi[((size_t)b * 64 + s) * G3 + f * 256 + w * 32 + fc * 16 + lane];
    }
    const char* hb = (const char*)&hbf[cur][0];
    f32x4 acc[3][2] = {};
#pragma unroll
    for (int half = 0; half < 2; ++half) {
      bf16x8 ah[4];
#pragma unroll
      for (int kf = 0; kf < 4; ++kf)
        ah[kf] = *(const bf16x8*)(hb + (half * 4 + kf) * 64 + hi16 * 16);  // broadcast
#pragma unroll
      for (int f = 0; f < 3; ++f)
#pragma unroll
        for (int fc = 0; fc < 2; ++fc)
#pragma unroll
          for (int kf = 0; kf < 4; ++kf)
            acc[f][fc] = __builtin_amdgcn_mfma_f32_16x16x32_bf16(
                ah[kf], wv[f][fc][half * 4 + kf], acc[f][fc], 0, 0, 0);
    }
    if (hi16 == 0) {
      int nxt = cur ^ 1;
#pragma unroll
      for (int fc = 0; fc < 2; ++fc) {
        int c = w * 32 + fc * 16 + lane;
        float rr = 1.f / (1.f + __expf(-(gd[0][fc] + acc[0][fc][0] + bhh[c])));
        float zz = 1.f / (1.f + __expf(-(gd[1][fc] + acc[1][fc][0] + bhh[256 + c])));
        float nn = fast_tanh(gd[2][fc] + rr * (acc[2][fc][0] + bhh[512 + c]));
        float hn = (1.f - zz) * nn + zz * h32[cur][c];
        h32[nxt][c] = hn;
        hbf[nxt][c] = __float2bfloat16(hn);
        enchB[((size_t)b * 64 + s) * 256 + c] = __float2bfloat16(hn);
      }
    }
    __syncthreads();
    cur ^= 1;
    if (w == 0) {   // escore on just-written h
      float p = h32[cur][lane] * aw[0] + h32[cur][lane + 64] * aw[1]
              + h32[cur][lane + 128] * aw[2] + h32[cur][lane + 192] * aw[3];
#pragma unroll
      for (int off = 32; off; off >>= 1) p += __shfl_xor(p, off, 64);
      if (lane == 0) escoreT[(size_t)b * 64 + s] = p;
    }
  }
}

// ---------------------------------------------------------------------------
// Decoder scan v6 — minimized serial DS chain. 64 WGs x 512 thr, 1 batch/WG.
// All 3 Whh panels VGPR-resident; gh MFMAs issued FIRST (overlap the softmax
// p-reduce on the DS/VALU pipes; separate accumulators keep them independent
// — R8's fusion serialized gh behind softmax, neutral result).
// Softmax: NO max-subtract (logits=relu(..)>=0, bounded -> exp safe);
// UNNORMALIZED e feeds the gi MFMA; sum computed via 2 MFMAs against an
// all-ones B-frag (removes 12 dependent DS shuffles from the chain);
// divide by sum at the gates.
// ---------------------------------------------------------------------------
__global__ __launch_bounds__(512) void k_decoder6(
    const float* __restrict__ Gdec, const __hip_bfloat16* __restrict__ Wcat6,
    const float* __restrict__ bhh, const __hip_bfloat16* __restrict__ enchB,
    const __hip_bfloat16* __restrict__ ENCWT, const float* __restrict__ escoreT,
    const float* __restrict__ att_w, const float* __restrict__ att_b,
    __hip_bfloat16* __restrict__ dechb) {
  __shared__ __hip_bfloat16 encwT[G3][64];    // 96 KB, [c][s^((c&7)<<3)]
  __shared__ __hip_bfloat16 hbf[2][256];      // 1 KB
  __shared__ float h32[2][256];               // 2 KB
  int t = threadIdx.x, w = t >> 6, lane = t & 63;
  int b = blockIdx.x;
  int r16 = lane & 15, hi16 = lane >> 4;
  int cw = w * 32;
  // stage ENCWT b-slice (96 KB contiguous, swizzle pre-baked in global)
  {
    const char* srcb = (const char*)(ENCWT + (size_t)b * G3 * 64);
    char* dstb = (char*)&encwT[0][0];
#pragma unroll
    for (int is = 0; is < 12; ++is) {
      int off = is * 8192 + t * 16;
      gld_lds16((const __hip_bfloat16*)(srcb + off), (__hip_bfloat16*)(dstb + off));
    }
  }
  // all 3 Whh panels resident (panels 3,4,5 of Wcat6) = 192 regs
  bf16x8 wv[3][2][8];
#pragma unroll
  for (int f = 0; f < 3; ++f)
#pragma unroll
    for (int fc = 0; fc < 2; ++fc)
#pragma unroll
      for (int kf = 0; kf < 8; ++kf)
        wv[f][fc][kf] = *(const bf16x8*)(Wcat6 +
            (((size_t)(3 + f) * 256 + cw + fc * 16 + r16) * 256 + kf * 32 + hi16 * 8));
  float aw[4];
#pragma unroll
  for (int q = 0; q < 4; ++q) aw[q] = att_w[lane + q * 64];   // w_dec
  float attb = att_b[0];
  float esc = escoreT[(size_t)b * 64 + lane];
  float bh0[2], bh1[2], bh2[2];
#pragma unroll
  for (int fc = 0; fc < 2; ++fc) {
    bh0[fc] = bhh[cw + fc * 16 + r16];
    bh1[fc] = bhh[256 + cw + fc * 16 + r16];
    bh2[fc] = bhh[512 + cw + fc * 16 + r16];
  }
  // all-ones B fragment for the MFMA row-sum (sum over s of e[s])
  u32x4 onesu = {0x3F803F80u, 0x3F803F80u, 0x3F803F80u, 0x3F803F80u};
  bf16x8 onesf = __builtin_bit_cast(bf16x8, onesu);
  if (t < 256) {
    float v = __bfloat162float(enchB[((size_t)b * 64 + 63) * 256 + t]);
    h32[0][t] = v;  hbf[0][t] = __float2bfloat16(v);
    h32[1][t] = 0.f; hbf[1][t] = __float2bfloat16(0.f);
  }
  __syncthreads();
  float hp[2];   // h in-register on lanes<16 (col = cw + fc*16 + r16)
  hp[0] = h32[0][cw + r16];
  hp[1] = h32[0][cw + 16 + r16];
  int bs3 = (b & 7) << 3;
  int cur = 0;
  for (int i = 0; i < NL; ++i) {
    // Gdec prefetch (lanes<16, independent global loads)
    float gd0[2], gd1[2], gd2[2];
    if (hi16 == 0) {
      const float* gp = Gdec + ((size_t)i * 64 + b) * G3;
#pragma unroll
      for (int fc = 0; fc < 2; ++fc) {
        gd0[fc] = gp[cw + fc * 16 + r16];
        gd1[fc] = gp[256 + cw + fc * 16 + r16];
        gd2[fc] = gp[512 + cw + fc * 16 + r16];
      }
    }
    // --- gh MFMAs FIRST (independent of softmax; MFMA pipe churns while
    //     the DS pipe walks the p-reduce chain) ---
    const char* hb = (const char*)&hbf[cur][0];
    f32x4 acch[3][2] = {};
#pragma unroll
    for (int half = 0; half < 2; ++half) {
      bf16x8 ah[4];
#pragma unroll
      for (int kf = 0; kf < 4; ++kf)
        ah[kf] = *(const bf16x8*)(hb + (half * 4 + kf) * 64 + hi16 * 16);  // broadcast
#pragma unroll
      for (int f = 0; f < 3; ++f)
#pragma unroll
        for (int fc = 0; fc < 2; ++fc)
#pragma unroll
          for (int kf = 0; kf < 4; ++kf)
            acch[f][fc] = __builtin_amdgcn_mfma_f32_16x16x32_bf16(
                ah[kf], wv[f][fc][half * 4 + kf], acch[f][fc], 0, 0, 0);
    }
    // --- softmax p-reduce (the one remaining dependent shuffle chain) ---
    float p = h32[cur][lane] * aw[0] + h32[cur][lane + 64] * aw[1]
            + h32[cur][lane + 128] * aw[2] + h32[cur][lane + 192] * aw[3];
#pragma unroll
    for (int off = 32; off; off >>= 1) p += __shfl_xor(p, off, 64);
    float lg = fmaxf(esc + p + attb, 0.f);
    float e = __expf(lg);            // no max-subtract: lg in [0, ~small]
    // --- pack UNNORMALIZED e -> A-frags (16 independent bpermutes) ---
    bf16x8 af_[2];
#pragma unroll
    for (int kf = 0; kf < 2; ++kf) {
      u32x4 tmp;
#pragma unroll
      for (int j = 0; j < 4; ++j) {
        int src = hi16 * 8 + kf * 32 + 2 * j;
        tmp[j] = f2bf(__shfl(e, src, 64)) | (f2bf(__shfl(e, src + 1, 64)) << 16);
      }
      af_[kf] = __builtin_bit_cast(bf16x8, tmp);
    }
    // --- sum via MFMA (every lane gets sm in all acc slots) ---
    f32x4 smacc = {};
    smacc = __builtin_amdgcn_mfma_f32_16x16x32_bf16(af_[0], onesf, smacc, 0, 0, 0);
    smacc = __builtin_amdgcn_mfma_f32_16x16x32_bf16(af_[1], onesf, smacc, 0, 0, 0);
    // --- gi MFMAs (B from swizzled LDS), separate accumulators ---
    f32x4 acci[3][2] = {};
    const char* eb = (const char*)&encwT[0][0];
#pragma unroll
    for (int g = 0; g < 3; ++g)
#pragma unroll
      for (int fc = 0; fc < 2; ++fc) {
        int cloc = g * 256 + cw + fc * 16 + r16;
        int xb = (cloc & 7) << 4;
#pragma unroll
        for (int kf = 0; kf < 2; ++kf) {
          bf16x8 bfrag = *(const bf16x8*)(eb + cloc * 128 + ((kf * 64 + hi16 * 16) ^ xb));
          acci[g][fc] = __builtin_amdgcn_mfma_f32_16x16x32_bf16(
              af_[kf], bfrag, acci[g][fc], 0, 0, 0);
        }
      }
    // --- gates + h update on lanes<16 (divide by sm here) ---
    if (hi16 == 0) {
      float rn = 1.f / smacc[0];
      int nxt = cur ^ 1;
#pragma unroll
      for (int fc = 0; fc < 2; ++fc) {
        int c = cw + fc * 16 + r16;
        float rr = 1.f / (1.f + __expf(-(gd0[fc] + acci[0][fc][0] * rn + acch[0][fc][0] + bh0[fc])));
        float zz = 1.f / (1.f + __expf(-(gd1[fc] + acci[1][fc][0] * rn + acch[1][fc][0] + bh1[fc])));
        float nn = fast_tanh(gd2[fc] + acci[2][fc][0] * rn + rr * (acch[2][fc][0] + bh2[fc]));
        float hn = (1.f - zz) * nn + zz * hp[fc];
        hp[fc] = hn;
        h32[nxt][c] = hn;
        hbf[nxt][c] = __float2bfloat16(hn);
        int cs = (c & ~63) | ((c & 63) ^ bs3);   // pre-swizzle for out GEMM
        dechb[((size_t)i * 64 + b) * 256 + cs] = __float2bfloat16(hn);
      }
    }
    __syncthreads();
    cur ^= 1;
  }
}

// ---------------------------------------------------------------------------
// Log-softmax, register-resident single read + single write (one WG/row).
// ---------------------------------------------------------------------------
__global__ __launch_bounds__(256) void k_logsoftmax(float* __restrict__ out) {
  float* x = out + (size_t)blockIdx.x * NVOUT;
  __shared__ float red[256];
  int t = threadIdx.x;
  float4 v[10];
  float mx = -1e30f;
#pragma unroll
  for (int ii = 0; ii < 10; ++ii) {
    int slot = ii * 256 + t;
    if (slot < 2500) {
      v[ii] = *(const float4*)(x + slot * 4);
      mx = fmaxf(mx, fmaxf(fmaxf(v[ii].x, v[ii].y), fmaxf(v[ii].z, v[ii].w)));
    }
  }
  red[t] = mx; __syncthreads();
  for (int off = 128; off; off >>= 1) {
    if (t < off) red[t] = fmaxf(red[t], red[t + off]);
    __syncthreads();
  }
  mx = red[0]; __syncthreads();
  float sm = 0.f;
#pragma unroll
  for (int ii = 0; ii < 10; ++ii) {
    int slot = ii * 256 + t;
    if (slot < 2500)
      sm += __expf(v[ii].x - mx) + __expf(v[ii].y - mx)
          + __expf(v[ii].z - mx) + __expf(v[ii].w - mx);
  }
  red[t] = sm; __syncthreads();
  for (int off = 128; off; off >>= 1) {
    if (t < off) red[t] += red[t + off];
    __syncthreads();
  }
  float lse = mx + logf(red[0]);
#pragma unroll
  for (int ii = 0; ii < 10; ++ii) {
    int slot = ii * 256 + t;
    if (slot < 2500) {
      float4 o; o.x = v[ii].x - lse; o.y = v[ii].y - lse;
      o.z = v[ii].z - lse; o.w = v[ii].w - lse;
      *(float4*)(x + slot * 4) = o;
    }
  }
}

// ---------------------------------------------------------------------------
extern "C" void kernel_launch(void* const* d_in, const int* in_sizes, int n_in,
                              void* d_out, int out_size, void* d_ws, size_t ws_size,
                              hipStream_t stream) {
  const float* X        = (const float*)d_in[0];
  const int*   gt       = (const int*)  d_in[1];
  const float* enc_Wih  = (const float*)d_in[2];
  const float* enc_Whh  = (const float*)d_in[3];
  const float* enc_bih  = (const float*)d_in[4];
  const float* enc_bhh  = (const float*)d_in[5];
  const float* att_w    = (const float*)d_in[6];
  const float* att_b    = (const float*)d_in[7];
  const float* dec_Wih  = (const float*)d_in[8];
  const float* dec_Whh  = (const float*)d_in[9];
  const float* dec_bih  = (const float*)d_in[10];
  const float* dec_bhh  = (const float*)d_in[11];
  const float* out_W    = (const float*)d_in[12];
  const float* out_b    = (const float*)d_in[13];
  float* out = (float*)d_out;

  // workspace carve-up
  float* p = (float*)d_ws;
  float* Gienc  = p; p += NS * NB * G3;          // fp32, dead after encoder
  float* Gdec   = p; p += NL * NB * G3;
  float* escoreT = p; p += NB * NS;
  __hip_bfloat16* q = (__hip_bfloat16*)p;
  __hip_bfloat16* enchBb = q; q += (size_t)NB * NS * NH;
  __hip_bfloat16* Wcat_e = q; q += (size_t)3 * 256 * 256;
  __hip_bfloat16* Wcat_d = q; q += (size_t)6 * 256 * 256;
  __hip_bfloat16* Xb     = q; q += (size_t)4096 * KP2;
  __hip_bfloat16* Wencb  = q; q += (size_t)G3 * KP2;
  __hip_bfloat16* Woutb  = q; q += (size_t)NOUTP * NH;
  __hip_bfloat16* dechb  = q; q += (size_t)NL * NB * NH;
  // ENCWT [64 b][768 c][64 s] bf16 (6.3 MB) aliases Gienc (12.6 MB)
  __hip_bfloat16* ENCWT  = (__hip_bfloat16*)Gienc;
  // split-K partials (50 MB fp32) in d_out scratch (overwritten later)
  float* Pout = (float*)d_out;

  // prep (independent)
  k_cvt_pad<<<4096, 256, 0, stream>>>(X, Xb, 4096, NVIN, KP2, 1);
  k_cvt_pad<<<G3, 256, 0, stream>>>(enc_Wih, Wencb, G3, NVIN, KP2, 1);
  k_cvt_pad<<<NOUTP, 256, 0, stream>>>(out_W, Woutb, NVOUT, NH, NH, 1);
  k_wpack<<<768, 256, 0, stream>>>(enc_Whh, NH, enc_Whh, NH, Wcat_e, 3 * 65536);
  k_wpack<<<1536, 256, 0, stream>>>(dec_Wih, NH + NVOUT, dec_Whh, NH, Wcat_d, 6 * 65536);
  k_pregather<<<NL * NB, 256, 0, stream>>>(dec_Wih, dec_bih, gt, Gdec);

  k_gemm_encS<<<dim3(6, 32, 4), 256, 0, stream>>>(Xb, Wencb, Pout);
  k_reduce4<<<3072, 256, 0, stream>>>((const float4*)Pout, enc_bih, (float4*)Gienc);
  k_encoder4<<<64, 512, 0, stream>>>(Gienc, Wcat_e, enc_bhh, att_w, enchBb, escoreT);
  k_gemm_encw<<<dim3(6, 32), 256, 0, stream>>>(enchBb, Wcat_d, ENCWT);
  k_decoder6<<<64, 512, 0, stream>>>(Gdec, Wcat_d, dec_bhh, enchBb, ENCWT,
                                     escoreT, att_w, att_b, dechb);
  k_gemm_outS<<<dim3(79, 32), 256, 0, stream>>>(dechb, Woutb, out_b, out);
  k_logsoftmax<<<NB * NL, 256, 0, stream>>>(out);
}

// Round 11
// 733.836 us; speedup vs baseline: 3.6757x; 1.0757x over previous
//
#include <hip/hip_runtime.h>
#include <hip/hip_bf16.h>
#include <math.h>

// Problem dims (fixed by the reference)
#define NB 64      // batch
#define NS 64      // encoder steps
#define NL 64      // decoder steps
#define NH 256     // hidden
#define G3 768     // 3*NH (gates r,z,n)
#define NVIN 10000
#define NVOUT 10000
#define KP2 10240   // NVIN padded (4 splits x 40 x BK=64)
#define NOUTP 10112 // NVOUT padded to 128 for out GEMM

typedef __attribute__((ext_vector_type(8))) short bf16x8;  // 8 bf16 (4 VGPRs)
typedef __attribute__((ext_vector_type(4))) float f32x4;   // MFMA accumulator
typedef __attribute__((ext_vector_type(4))) unsigned int u32x4;

// async global->LDS, 16B per lane (dest must be wave-uniform base + lane*16)
__device__ __forceinline__ void gld_lds16(const __hip_bfloat16* g, __hip_bfloat16* l) {
  __builtin_amdgcn_global_load_lds(
      (const __attribute__((address_space(1))) unsigned int*)(const void*)g,
      (__attribute__((address_space(3))) unsigned int*)(void*)l, 16, 0, 0);
}

__device__ __forceinline__ unsigned int f2bf(float f) {  // RNE fp32->bf16 bits
  unsigned int u = __float_as_uint(f);
  return (u + 0x7fff + ((u >> 16) & 1)) >> 16;
}

__device__ __forceinline__ float fast_tanh(float x) {   // tanh via v_exp_f32
  float e = __expf(-2.f * x);
  return (1.f - e) / (1.f + e);
}

// Workgroup barrier WITHOUT the vmcnt(0) drain __syncthreads() emits.
// LDS writes are made visible (lgkmcnt(0)); in-flight global stores/loads
// keep flying across steps (T4: never drain vmcnt to 0 in the main loop).
__device__ __forceinline__ void lds_barrier() {
  asm volatile("s_waitcnt lgkmcnt(0)\n\ts_barrier" ::: "memory");
}

// ---------------------------------------------------------------------------
// fp32 -> bf16 convert with padding; swz=1 pre-swizzles columns within each
// 64-group by ((row&7)<<3) so linear global_load_lds + XOR'd ds_read is
// conflict-free (T2/m173: swizzle the SOURCE, keep LDS dest linear).
// ---------------------------------------------------------------------------
__global__ __launch_bounds__(256) void k_cvt_pad(
    const float* __restrict__ in, __hip_bfloat16* __restrict__ out,
    int in_rows, int in_cols, int out_cols, int swz) {
  int r = blockIdx.x;
  const float* src = in + (size_t)r * in_cols;
  __hip_bfloat16* dst = out + (size_t)r * out_cols;
  bool live = r < in_rows;
  int sx = swz ? ((r & 7) << 3) : 0;
  for (int c = threadIdx.x * 4; c < out_cols; c += 1024) {
    int cc = (c & ~63) | ((c & 63) ^ sx);
    __hip_bfloat16 v[4];
    if (live && cc + 3 < in_cols) {
      float4 f = *(const float4*)(src + cc);
      v[0] = __float2bfloat16(f.x); v[1] = __float2bfloat16(f.y);
      v[2] = __float2bfloat16(f.z); v[3] = __float2bfloat16(f.w);
    } else {
      v[0] = v[1] = v[2] = v[3] = __float2bfloat16(0.f);
    }
    *(ushort4*)(dst + c) = *(const ushort4*)v;
  }
}

// ---------------------------------------------------------------------------
// Pack recurrent weights to bf16 Wcat[f][c][k].
// ---------------------------------------------------------------------------
__global__ __launch_bounds__(256) void k_wpack(
    const float* __restrict__ srcA, int strideA,
    const float* __restrict__ srcB, int strideB,
    __hip_bfloat16* __restrict__ out, int total) {
  int idx = blockIdx.x * 256 + threadIdx.x;
  if (idx >= total) return;
  int k = idx & 255, c = (idx >> 8) & 255, f = idx >> 16;
  float v = (f < 3) ? srcA[(size_t)(f * 256 + c) * strideA + k]
                    : srcB[(size_t)((f - 3) * 256 + c) * strideB + k];
  out[idx] = __float2bfloat16(v);
}

// ---------------------------------------------------------------------------
// Enc GEMM, split-K (see R7): P[z] partials, reduced by k_reduce4.
// ---------------------------------------------------------------------------
__global__ __launch_bounds__(256) void k_gemm_encS(
    const __hip_bfloat16* __restrict__ A, const __hip_bfloat16* __restrict__ B,
    float* __restrict__ P) {
  __shared__ __hip_bfloat16 As[128][64];
  __shared__ __hip_bfloat16 Bs[128][64];
  int t = threadIdx.x;
  int wid = t >> 6, lane = t & 63;
  int m0 = blockIdx.y * 128, n0 = blockIdx.x * 128;
  int wr = wid >> 1, wc = wid & 1;
  int r16 = lane & 15, hi16 = lane >> 4;
  int xr = (r16 & 7) << 4;
  f32x4 acc[4][4] = {};
  int kbeg = blockIdx.z * 2560;
  for (int ks = 0; ks < 40; ++ks) {
    int k0 = kbeg + ks * 64;
    __syncthreads();
#pragma unroll
    for (int is = 0; is < 4; ++is) {
      int off = is * 4096 + t * 16;
      int r = off >> 7, e = (off & 127) >> 1;
      gld_lds16(A + (size_t)(m0 + r) * KP2 + k0 + e, &As[r][e]);
      gld_lds16(B + (size_t)(n0 + r) * KP2 + k0 + e, &Bs[r][e]);
    }
    __syncthreads();
    const char* ab = (const char*)As;
    const char* bb = (const char*)Bs;
#pragma unroll
    for (int kk = 0; kk < 2; ++kk) {
      int ko = kk * 64 + hi16 * 16;
      bf16x8 af[4], bfr[4];
#pragma unroll
      for (int i = 0; i < 4; ++i) {
        af[i]  = *(const bf16x8*)(ab + (wr * 64 + i * 16 + r16) * 128 + (ko ^ xr));
        bfr[i] = *(const bf16x8*)(bb + (wc * 64 + i * 16 + r16) * 128 + (ko ^ xr));
      }
#pragma unroll
      for (int i = 0; i < 4; ++i)
#pragma unroll
        for (int j = 0; j < 4; ++j)
          acc[i][j] = __builtin_amdgcn_mfma_f32_16x16x32_bf16(af[i], bfr[j], acc[i][j], 0, 0, 0);
    }
  }
  float* Pz = P + (size_t)blockIdx.z * 4096 * G3;
#pragma unroll
  for (int i = 0; i < 4; ++i)
#pragma unroll
    for (int j = 0; j < 4; ++j) {
      int ccol = n0 + wc * 64 + j * 16 + r16;
#pragma unroll
      for (int q = 0; q < 4; ++q) {
        int crow = m0 + wr * 64 + i * 16 + hi16 * 4 + q;
        Pz[(size_t)crow * G3 + ccol] = acc[i][j][q];
      }
    }
}

// Gienc = P0+P1+P2+P3 + bias
__global__ __launch_bounds__(256) void k_reduce4(
    const float4* __restrict__ P, const float* __restrict__ bias,
    float4* __restrict__ G) {
  int idx = blockIdx.x * 256 + threadIdx.x;
  float4 a = P[idx], b = P[idx + 786432], c = P[idx + 2 * 786432],
         d = P[idx + 3 * 786432];
  float4 bs = *(const float4*)(bias + (idx % 192) * 4);
  float4 o;
  o.x = a.x + b.x + c.x + d.x + bs.x;
  o.y = a.y + b.y + c.y + d.y + bs.y;
  o.z = a.z + b.z + c.z + d.z + bs.z;
  o.w = a.w + b.w + c.w + d.w + bs.w;
  G[idx] = o;
}

// ---------------------------------------------------------------------------
// Out GEMM (BK=64 + swizzle, see R7).
// ---------------------------------------------------------------------------
__global__ __launch_bounds__(256) void k_gemm_outS(
    const __hip_bfloat16* __restrict__ A, const __hip_bfloat16* __restrict__ B,
    const float* __restrict__ bias, float* __restrict__ C) {
  __shared__ __hip_bfloat16 As[128][64];
  __shared__ __hip_bfloat16 Bs[128][64];
  int t = threadIdx.x;
  int wid = t >> 6, lane = t & 63;
  int m0 = blockIdx.y * 128, n0 = blockIdx.x * 128;
  int wr = wid >> 1, wc = wid & 1;
  int r16 = lane & 15, hi16 = lane >> 4;
  int xr = (r16 & 7) << 4;
  f32x4 acc[4][4] = {};
  for (int k0 = 0; k0 < NH; k0 += 64) {
    __syncthreads();
#pragma unroll
    for (int is = 0; is < 4; ++is) {
      int off = is * 4096 + t * 16;
      int r = off >> 7, e = (off & 127) >> 1;
      gld_lds16(A + (size_t)(m0 + r) * NH + k0 + e, &As[r][e]);
      gld_lds16(B + (size_t)(n0 + r) * NH + k0 + e, &Bs[r][e]);
    }
    __syncthreads();
    const char* ab = (const char*)As;
    const char* bb = (const char*)Bs;
#pragma unroll
    for (int kk = 0; kk < 2; ++kk) {
      int ko = kk * 64 + hi16 * 16;
      bf16x8 af[4], bfr[4];
#pragma unroll
      for (int i = 0; i < 4; ++i) {
        af[i]  = *(const bf16x8*)(ab + (wr * 64 + i * 16 + r16) * 128 + (ko ^ xr));
        bfr[i] = *(const bf16x8*)(bb + (wc * 64 + i * 16 + r16) * 128 + (ko ^ xr));
      }
#pragma unroll
      for (int i = 0; i < 4; ++i)
#pragma unroll
        for (int j = 0; j < 4; ++j)
          acc[i][j] = __builtin_amdgcn_mfma_f32_16x16x32_bf16(af[i], bfr[j], acc[i][j], 0, 0, 0);
    }
  }
#pragma unroll
  for (int i = 0; i < 4; ++i)
#pragma unroll
    for (int j = 0; j < 4; ++j) {
      int ccol = n0 + wc * 64 + j * 16 + r16;
      if (ccol < NVOUT) {
        float bs = bias[ccol];
#pragma unroll
        for (int q = 0; q < 4; ++q) {
          int crow = m0 + wr * 64 + i * 16 + hi16 * 4 + q;  // = l*64+b
          int l = crow >> 6, b = crow & 63;
          C[((size_t)b * NL + l) * NVOUT + ccol] = acc[i][j][q] + bs;
        }
      }
    }
}

// ---------------------------------------------------------------------------
// ENCW GEMM -> TRANSPOSED, swizzled output: ENCWT[b][c][s ^ ((c&7)<<3)] =
// sum_k ench[b*64+s][k] * Wih_ctx[c][k].
// ---------------------------------------------------------------------------
__global__ __launch_bounds__(256) void k_gemm_encw(
    const __hip_bfloat16* __restrict__ A, const __hip_bfloat16* __restrict__ B,
    __hip_bfloat16* __restrict__ CT) {
  __shared__ __hip_bfloat16 As[128][32];
  __shared__ __hip_bfloat16 Bs[128][32];
  int t = threadIdx.x;
  int wid = t >> 6, lane = t & 63;
  int m0 = blockIdx.y * 128, n0 = blockIdx.x * 128;
  int wr = wid >> 1, wc = wid & 1;
  f32x4 acc[4][4] = {};
  for (int k0 = 0; k0 < NH; k0 += 32) {
    __syncthreads();
#pragma unroll
    for (int is = 0; is < 2; ++is) {
      int off = is * 4096 + wid * 1024 + lane * 16;
      int r = off >> 6, cb = (off & 63) >> 1;
      gld_lds16(A + (size_t)(m0 + r) * NH + k0 + cb, &As[r][cb]);
      gld_lds16(B + (size_t)(n0 + r) * NH + k0 + cb, &Bs[r][cb]);
    }
    __syncthreads();
    int r16 = lane & 15, kb = (lane >> 4) * 8;
    bf16x8 af[4], bfr[4];
#pragma unroll
    for (int i = 0; i < 4; ++i) {
      af[i]  = *(const bf16x8*)&As[wr * 64 + i * 16 + r16][kb];
      bfr[i] = *(const bf16x8*)&Bs[wc * 64 + i * 16 + r16][kb];
    }
#pragma unroll
    for (int i = 0; i < 4; ++i)
#pragma unroll
      for (int j = 0; j < 4; ++j)
        acc[i][j] = __builtin_amdgcn_mfma_f32_16x16x32_bf16(af[i], bfr[j], acc[i][j], 0, 0, 0);
  }
  int r16 = lane & 15, rg = lane >> 4;
#pragma unroll
  for (int i = 0; i < 4; ++i)
#pragma unroll
    for (int j = 0; j < 4; ++j) {
      int ccol = n0 + wc * 64 + j * 16 + r16;
#pragma unroll
      for (int q = 0; q < 4; ++q) {
        int crow = m0 + wr * 64 + i * 16 + rg * 4 + q;   // = b*64+s
        int bb = crow >> 6, ss = crow & 63;
        CT[((size_t)bb * G3 + ccol) * 64 + (ss ^ ((ccol & 7) << 3))] =
            __float2bfloat16(acc[i][j][q]);
      }
    }
}

// ---------------------------------------------------------------------------
// Pre-gather decoder one-hot input term: Gdec = bih + onehot column.
// ---------------------------------------------------------------------------
__global__ __launch_bounds__(256) void k_pregather(
    const float* __restrict__ Wih, const float* __restrict__ bih,
    const int* __restrict__ gt, float* __restrict__ Gdec) {
  int ib = blockIdx.x;              // i*64+b
  int i = ib >> 6, b = ib & 63;
  int tok = (i > 0) ? gt[b * NL + (i - 1)] : -1;
  for (int g = threadIdx.x; g < G3; g += 256) {
    float v = bih[g];
    if (tok >= 0) v += Wih[(size_t)g * (NH + NVOUT) + NH + tok];
    Gdec[(size_t)ib * G3 + g] = v;
  }
}

// ---------------------------------------------------------------------------
// Encoder scan v5: 64 WGs x 512 thr, one batch/WG, Whh VGPR-resident.
// Minimal step: Gi prefetch -> 8 broadcast ds_read -> 48 MFMA -> gates
// (h in-register) -> hbf write -> RAW barrier (no vmcnt drain: enchB HBM
// store-acks stay in flight; __syncthreads was draining them every step).
// escore computation moved to k_escoreB (post-kernel).
// ---------------------------------------------------------------------------
__global__ __launch_bounds__(512) void k_encoder5(
    const float* __restrict__ Gi, const __hip_bfloat16* __restrict__ Wcat,
    const float* __restrict__ bhh, __hip_bfloat16* __restrict__ enchB) {
  __shared__ __hip_bfloat16 hbf[2][256];
  int t = threadIdx.x, w = t >> 6, lane = t & 63;
  int b = blockIdx.x;
  int r16 = lane & 15, hi16 = lane >> 4;
  int cw = w * 32;
  bf16x8 wv[3][2][8];
#pragma unroll
  for (int f = 0; f < 3; ++f)
#pragma unroll
    for (int fc = 0; fc < 2; ++fc)
#pragma unroll
      for (int kf = 0; kf < 8; ++kf)
        wv[f][fc][kf] = *(const bf16x8*)(Wcat +
            (((size_t)f * 256 + cw + fc * 16 + r16) * 256 + kf * 32 + hi16 * 8));
  float bh0[2], bh1[2], bh2[2];
#pragma unroll
  for (int fc = 0; fc < 2; ++fc) {
    bh0[fc] = bhh[cw + fc * 16 + r16];
    bh1[fc] = bhh[256 + cw + fc * 16 + r16];
    bh2[fc] = bhh[512 + cw + fc * 16 + r16];
  }
  if (t < 256) {
    hbf[0][t] = __float2bfloat16(0.f);
    hbf[1][t] = __float2bfloat16(0.f);
  }
  __syncthreads();
  float hp[2] = {0.f, 0.f};
  int cur = 0;
  for (int s = 0; s < NS; ++s) {
    float gd0[2], gd1[2], gd2[2];
    if (hi16 == 0) {
      const float* gp = Gi + ((size_t)b * 64 + s) * G3;
#pragma unroll
      for (int fc = 0; fc < 2; ++fc) {
        gd0[fc] = gp[cw + fc * 16 + r16];
        gd1[fc] = gp[256 + cw + fc * 16 + r16];
        gd2[fc] = gp[512 + cw + fc * 16 + r16];
      }
    }
    const char* hb = (const char*)&hbf[cur][0];
    f32x4 acc[3][2] = {};
#pragma unroll
    for (int half = 0; half < 2; ++half) {
      bf16x8 ah[4];
#pragma unroll
      for (int kf = 0; kf < 4; ++kf)
        ah[kf] = *(const bf16x8*)(hb + (half * 4 + kf) * 64 + hi16 * 16);  // broadcast
#pragma unroll
      for (int f = 0; f < 3; ++f)
#pragma unroll
        for (int fc = 0; fc < 2; ++fc)
#pragma unroll
          for (int kf = 0; kf < 4; ++kf)
            acc[f][fc] = __builtin_amdgcn_mfma_f32_16x16x32_bf16(
                ah[kf], wv[f][fc][half * 4 + kf], acc[f][fc], 0, 0, 0);
    }
    if (hi16 == 0) {
      int nxt = cur ^ 1;
#pragma unroll
      for (int fc = 0; fc < 2; ++fc) {
        int c = cw + fc * 16 + r16;
        float rr = 1.f / (1.f + __expf(-(gd0[fc] + acc[0][fc][0] + bh0[fc])));
        float zz = 1.f / (1.f + __expf(-(gd1[fc] + acc[1][fc][0] + bh1[fc])));
        float nn = fast_tanh(gd2[fc] + rr * (acc[2][fc][0] + bh2[fc]));
        float hn = (1.f - zz) * nn + zz * hp[fc];
        hp[fc] = hn;
        hbf[nxt][c] = __float2bfloat16(hn);
        enchB[((size_t)b * 64 + s) * 256 + c] = __float2bfloat16(hn);
      }
    }
    lds_barrier();
    cur ^= 1;
  }
}

// escoreT[b*64+s] = enc_h[b][s] . w_enc   (4 rows/block, 64 lanes/row)
__global__ __launch_bounds__(256) void k_escoreB(
    const __hip_bfloat16* __restrict__ enchB, const float* __restrict__ att_w,
    float* __restrict__ escoreT) {
  int row = blockIdx.x * 4 + (threadIdx.x >> 6);   // = b*64+s
  int lane = threadIdx.x & 63;
  ushort4 u = *(const ushort4*)(enchB + (size_t)row * 256 + lane * 4);
  const float* we = att_w + 256 + lane * 4;
  float p = __uint_as_float((unsigned)u.x << 16) * we[0]
          + __uint_as_float((unsigned)u.y << 16) * we[1]
          + __uint_as_float((unsigned)u.z << 16) * we[2]
          + __uint_as_float((unsigned)u.w << 16) * we[3];
#pragma unroll
  for (int off = 32; off; off >>= 1) p += __shfl_xor(p, off, 64);
  if (lane == 0) escoreT[row] = p;
}

// ---------------------------------------------------------------------------
// Decoder scan v7. 64 WGs x 512 thr, 1 batch/WG, RAW barriers.
// p = h.w_dec is PIPELINED ACROSS THE BARRIER: computed during step i's gate
// phase from the just-updated in-register h (2 FMA + 4-shfl 16-lane reduce +
// psum[nxt][w] LDS write); step i+1 reads it as 2 broadcast ds_read_b128 + 7
// adds. The old front-end (4 ds_reads of h32 + 6-shfl chain) and h32 die.
// Unnormalized e feeds gi; sum(e) via MFMA against an all-ones row appended
// to encwT (row 768); divide at the gates.
// ---------------------------------------------------------------------------
__global__ __launch_bounds__(512) void k_decoder7(
    const float* __restrict__ Gdec, const __hip_bfloat16* __restrict__ Wcat6,
    const float* __restrict__ bhh, const __hip_bfloat16* __restrict__ enchB,
    const __hip_bfloat16* __restrict__ ENCWT, const float* __restrict__ escoreT,
    const float* __restrict__ att_w, const float* __restrict__ att_b,
    __hip_bfloat16* __restrict__ dechb) {
  __shared__ __hip_bfloat16 encwT[G3 + 8][64];  // rows 0-767 staged; row 768 = ones
  __shared__ __hip_bfloat16 hbf[2][256];
  __shared__ float psumL[2][8];
  int t = threadIdx.x, w = t >> 6, lane = t & 63;
  int b = blockIdx.x;
  int r16 = lane & 15, hi16 = lane >> 4;
  int cw = w * 32;
  // stage ENCWT b-slice (96 KB contiguous, swizzle pre-baked in global)
  {
    const char* srcb = (const char*)(ENCWT + (size_t)b * G3 * 64);
    char* dstb = (char*)&encwT[0][0];
#pragma unroll
    for (int is = 0; is < 12; ++is) {
      int off = is * 8192 + t * 16;
      gld_lds16((const __hip_bfloat16*)(srcb + off), (__hip_bfloat16*)(dstb + off));
    }
  }
  {   // all-ones row 768 (for sum(e) via the gi-MFMA path; c=768 -> xb=0)
    unsigned* op = (unsigned*)&encwT[768][0];
    if (t < 32) op[t] = 0x3F803F80u;
  }
  // all 3 Whh panels resident (panels 3,4,5 of Wcat6)
  bf16x8 wv[3][2][8];
#pragma unroll
  for (int f = 0; f < 3; ++f)
#pragma unroll
    for (int fc = 0; fc < 2; ++fc)
#pragma unroll
      for (int kf = 0; kf < 8; ++kf)
        wv[f][fc][kf] = *(const bf16x8*)(Wcat6 +
            (((size_t)(3 + f) * 256 + cw + fc * 16 + r16) * 256 + kf * 32 + hi16 * 8));
  float wd0 = att_w[cw + r16], wd1 = att_w[cw + 16 + r16];   // w_dec slices
  float attb = att_b[0];
  float esc = escoreT[(size_t)b * 64 + lane];
  float bh0[2], bh1[2], bh2[2];
#pragma unroll
  for (int fc = 0; fc < 2; ++fc) {
    bh0[fc] = bhh[cw + fc * 16 + r16];
    bh1[fc] = bhh[256 + cw + fc * 16 + r16];
    bh2[fc] = bhh[512 + cw + fc * 16 + r16];
  }
  if (t < 256) {
    hbf[0][t] = enchB[((size_t)b * 64 + 63) * 256 + t];
    hbf[1][t] = __float2bfloat16(0.f);
  }
  // h in-register (lanes<16); initial p partial -> psumL[0]
  float hp[2];
  hp[0] = __bfloat162float(enchB[((size_t)b * 64 + 63) * 256 + cw + r16]);
  hp[1] = __bfloat162float(enchB[((size_t)b * 64 + 63) * 256 + cw + 16 + r16]);
  if (hi16 == 0) {
    float pp = hp[0] * wd0 + hp[1] * wd1;
    pp += __shfl_xor(pp, 1, 64); pp += __shfl_xor(pp, 2, 64);
    pp += __shfl_xor(pp, 4, 64); pp += __shfl_xor(pp, 8, 64);
    if (lane == 0) psumL[0][w] = pp;
  }
  __syncthreads();                 // init barrier: drains encwT staging too
  int bs3 = (b & 7) << 3;
  int cur = 0;
  for (int i = 0; i < NL; ++i) {
    // Gdec prefetch (lanes<16, stays in flight across the whole step)
    float gd0[2], gd1[2], gd2[2];
    if (hi16 == 0) {
      const float* gp = Gdec + ((size_t)i * 64 + b) * G3;
#pragma unroll
      for (int fc = 0; fc < 2; ++fc) {
        gd0[fc] = gp[cw + fc * 16 + r16];
        gd1[fc] = gp[256 + cw + fc * 16 + r16];
        gd2[fc] = gp[512 + cw + fc * 16 + r16];
      }
    }
    // h A-frags (broadcast) + pipelined p (2 broadcast b128 reads + 7 adds)
    const char* hb = (const char*)&hbf[cur][0];
    bf16x8 ah[8];
#pragma unroll
    for (int kf = 0; kf < 8; ++kf)
      ah[kf] = *(const bf16x8*)(hb + kf * 64 + hi16 * 16);
    float4 pa = *(const float4*)&psumL[cur][0];
    float4 pb = *(const float4*)&psumL[cur][4];
    float p = ((pa.x + pa.y) + (pa.z + pa.w)) + ((pb.x + pb.y) + (pb.z + pb.w));
    // gh MFMAs (independent of softmax)
    f32x4 acch[3][2] = {};
#pragma unroll
    for (int f = 0; f < 3; ++f)
#pragma unroll
      for (int fc = 0; fc < 2; ++fc)
#pragma unroll
        for (int kf = 0; kf < 8; ++kf)
          acch[f][fc] = __builtin_amdgcn_mfma_f32_16x16x32_bf16(
              ah[kf], wv[f][fc][kf], acch[f][fc], 0, 0, 0);
    // softmax tail: per-lane e (s = lane), no reduction needed
    float lg = fmaxf(esc + p + attb, 0.f);
    float e = __expf(lg);            // no max-subtract: lg bounded small
    // pack UNNORMALIZED e -> A-frags (16 independent shuffles)
    bf16x8 af_[2];
#pragma unroll
    for (int kf = 0; kf < 2; ++kf) {
      u32x4 tmp;
#pragma unroll
      for (int j = 0; j < 4; ++j) {
        int src = hi16 * 8 + kf * 32 + 2 * j;
        tmp[j] = f2bf(__shfl(e, src, 64)) | (f2bf(__shfl(e, src + 1, 64)) << 16);
      }
      af_[kf] = __builtin_bit_cast(bf16x8, tmp);
    }
    // gi MFMAs (B from swizzled LDS) + sum(e) via ones-row
    f32x4 acci[3][2] = {};
    f32x4 accs = {};
    const char* eb = (const char*)&encwT[0][0];
#pragma unroll
    for (int g = 0; g < 3; ++g)
#pragma unroll
      for (int fc = 0; fc < 2; ++fc) {
        int cloc = g * 256 + cw + fc * 16 + r16;
        int xb = (cloc & 7) << 4;
#pragma unroll
        for (int kf = 0; kf < 2; ++kf) {
          bf16x8 bfrag = *(const bf16x8*)(eb + cloc * 128 + ((kf * 64 + hi16 * 16) ^ xb));
          acci[g][fc] = __builtin_amdgcn_mfma_f32_16x16x32_bf16(
              af_[kf], bfrag, acci[g][fc], 0, 0, 0);
        }
      }
#pragma unroll
    for (int kf = 0; kf < 2; ++kf) {
      bf16x8 ofrag = *(const bf16x8*)(eb + 768 * 128 + kf * 64 + hi16 * 16);
      accs = __builtin_amdgcn_mfma_f32_16x16x32_bf16(af_[kf], ofrag, accs, 0, 0, 0);
    }
    // gates + h update + NEXT step's p partial (lanes<16)
    if (hi16 == 0) {
      float rn = 1.f / accs[0];
      int nxt = cur ^ 1;
      float hn2[2];
#pragma unroll
      for (int fc = 0; fc < 2; ++fc) {
        int c = cw + fc * 16 + r16;
        float rr = 1.f / (1.f + __expf(-(gd0[fc] + acci[0][fc][0] * rn + acch[0][fc][0] + bh0[fc])));
        float zz = 1.f / (1.f + __expf(-(gd1[fc] + acci[1][fc][0] * rn + acch[1][fc][0] + bh1[fc])));
        float nn = fast_tanh(gd2[fc] + acci[2][fc][0] * rn + rr * (acch[2][fc][0] + bh2[fc]));
        float hn = (1.f - zz) * nn + zz * hp[fc];
        hp[fc] = hn; hn2[fc] = hn;
        hbf[nxt][c] = __float2bfloat16(hn);
        int cs = (c & ~63) | ((c & 63) ^ bs3);   // pre-swizzle for out GEMM
        dechb[((size_t)i * 64 + b) * 256 + cs] = __float2bfloat16(hn);
      }
      float pp = hn2[0] * wd0 + hn2[1] * wd1;
      pp += __shfl_xor(pp, 1, 64); pp += __shfl_xor(pp, 2, 64);
      pp += __shfl_xor(pp, 4, 64); pp += __shfl_xor(pp, 8, 64);
      if (lane == 0) psumL[cur ^ 1][w] = pp;
    }
    lds_barrier();
    cur ^= 1;
  }
}

// ---------------------------------------------------------------------------
// Log-softmax, register-resident single read + single write (one WG/row).
// ---------------------------------------------------------------------------
__global__ __launch_bounds__(256) void k_logsoftmax(float* __restrict__ out) {
  float* x = out + (size_t)blockIdx.x * NVOUT;
  __shared__ float red[256];
  int t = threadIdx.x;
  float4 v[10];
  float mx = -1e30f;
#pragma unroll
  for (int ii = 0; ii < 10; ++ii) {
    int slot = ii * 256 + t;
    if (slot < 2500) {
      v[ii] = *(const float4*)(x + slot * 4);
      mx = fmaxf(mx, fmaxf(fmaxf(v[ii].x, v[ii].y), fmaxf(v[ii].z, v[ii].w)));
    }
  }
  red[t] = mx; __syncthreads();
  for (int off = 128; off; off >>= 1) {
    if (t < off) red[t] = fmaxf(red[t], red[t + off]);
    __syncthreads();
  }
  mx = red[0]; __syncthreads();
  float sm = 0.f;
#pragma unroll
  for (int ii = 0; ii < 10; ++ii) {
    int slot = ii * 256 + t;
    if (slot < 2500)
      sm += __expf(v[ii].x - mx) + __expf(v[ii].y - mx)
          + __expf(v[ii].z - mx) + __expf(v[ii].w - mx);
  }
  red[t] = sm; __syncthreads();
  for (int off = 128; off; off >>= 1) {
    if (t < off) red[t] += red[t + off];
    __syncthreads();
  }
  float lse = mx + logf(red[0]);
#pragma unroll
  for (int ii = 0; ii < 10; ++ii) {
    int slot = ii * 256 + t;
    if (slot < 2500) {
      float4 o; o.x = v[ii].x - lse; o.y = v[ii].y - lse;
      o.z = v[ii].z - lse; o.w = v[ii].w - lse;
      *(float4*)(x + slot * 4) = o;
    }
  }
}

// ---------------------------------------------------------------------------
extern "C" void kernel_launch(void* const* d_in, const int* in_sizes, int n_in,
                              void* d_out, int out_size, void* d_ws, size_t ws_size,
                              hipStream_t stream) {
  const float* X        = (const float*)d_in[0];
  const int*   gt       = (const int*)  d_in[1];
  const float* enc_Wih  = (const float*)d_in[2];
  const float* enc_Whh  = (const float*)d_in[3];
  const float* enc_bih  = (const float*)d_in[4];
  const float* enc_bhh  = (const float*)d_in[5];
  const float* att_w    = (const float*)d_in[6];
  const float* att_b    = (const float*)d_in[7];
  const float* dec_Wih  = (const float*)d_in[8];
  const float* dec_Whh  = (const float*)d_in[9];
  const float* dec_bih  = (const float*)d_in[10];
  const float* dec_bhh  = (const float*)d_in[11];
  const float* out_W    = (const float*)d_in[12];
  const float* out_b    = (const float*)d_in[13];
  float* out = (float*)d_out;

  // workspace carve-up
  float* p = (float*)d_ws;
  float* Gienc  = p; p += NS * NB * G3;          // fp32, dead after encoder
  float* Gdec   = p; p += NL * NB * G3;
  float* escoreT = p; p += NB * NS;
  __hip_bfloat16* q = (__hip_bfloat16*)p;
  __hip_bfloat16* enchBb = q; q += (size_t)NB * NS * NH;
  __hip_bfloat16* Wcat_e = q; q += (size_t)3 * 256 * 256;
  __hip_bfloat16* Wcat_d = q; q += (size_t)6 * 256 * 256;
  __hip_bfloat16* Xb     = q; q += (size_t)4096 * KP2;
  __hip_bfloat16* Wencb  = q; q += (size_t)G3 * KP2;
  __hip_bfloat16* Woutb  = q; q += (size_t)NOUTP * NH;
  __hip_bfloat16* dechb  = q; q += (size_t)NL * NB * NH;
  // ENCWT [64 b][768 c][64 s] bf16 (6.3 MB) aliases Gienc (12.6 MB)
  __hip_bfloat16* ENCWT  = (__hip_bfloat16*)Gienc;
  // split-K partials (50 MB fp32) in d_out scratch (overwritten later)
  float* Pout = (float*)d_out;

  // prep (independent)
  k_cvt_pad<<<4096, 256, 0, stream>>>(X, Xb, 4096, NVIN, KP2, 1);
  k_cvt_pad<<<G3, 256, 0, stream>>>(enc_Wih, Wencb, G3, NVIN, KP2, 1);
  k_cvt_pad<<<NOUTP, 256, 0, stream>>>(out_W, Woutb, NVOUT, NH, NH, 1);
  k_wpack<<<768, 256, 0, stream>>>(enc_Whh, NH, enc_Whh, NH, Wcat_e, 3 * 65536);
  k_wpack<<<1536, 256, 0, stream>>>(dec_Wih, NH + NVOUT, dec_Whh, NH, Wcat_d, 6 * 65536);
  k_pregather<<<NL * NB, 256, 0, stream>>>(dec_Wih, dec_bih, gt, Gdec);

  k_gemm_encS<<<dim3(6, 32, 4), 256, 0, stream>>>(Xb, Wencb, Pout);
  k_reduce4<<<3072, 256, 0, stream>>>((const float4*)Pout, enc_bih, (float4*)Gienc);
  k_encoder5<<<64, 512, 0, stream>>>(Gienc, Wcat_e, enc_bhh, enchBb);
  k_escoreB<<<1024, 256, 0, stream>>>(enchBb, att_w, escoreT);
  k_gemm_encw<<<dim3(6, 32), 256, 0, stream>>>(enchBb, Wcat_d, ENCWT);
  k_decoder7<<<64, 512, 0, stream>>>(Gdec, Wcat_d, dec_bhh, enchBb, ENCWT,
                                     escoreT, att_w, att_b, dechb);
  k_gemm_outS<<<dim3(79, 32), 256, 0, stream>>>(dechb, Woutb, out_b, out);
  k_logsoftmax<<<NB * NL, 256, 0, stream>>>(out);
}

// Round 12
// 713.930 us; speedup vs baseline: 3.7782x; 1.0279x over previous
//
#include <hip/hip_runtime.h>
#include <hip/hip_bf16.h>
#include <math.h>

// Problem dims (fixed by the reference)
#define NB 64      // batch
#define NS 64      // encoder steps
#define NL 64      // decoder steps
#define NH 256     // hidden
#define G3 768     // 3*NH (gates r,z,n)
#define NVIN 10000
#define NVOUT 10000
#define KP2 10240   // NVIN padded (4 splits x 40 x BK=64)
#define NOUTP 10112 // NVOUT padded to 128 for out GEMM

typedef __attribute__((ext_vector_type(8))) short bf16x8;  // 8 bf16 (4 VGPRs)
typedef __attribute__((ext_vector_type(4))) float f32x4;   // MFMA accumulator
typedef __attribute__((ext_vector_type(4))) unsigned int u32x4;

// async global->LDS, 16B per lane (dest must be wave-uniform base + lane*16)
__device__ __forceinline__ void gld_lds16(const __hip_bfloat16* g, __hip_bfloat16* l) {
  __builtin_amdgcn_global_load_lds(
      (const __attribute__((address_space(1))) unsigned int*)(const void*)g,
      (__attribute__((address_space(3))) unsigned int*)(void*)l, 16, 0, 0);
}

__device__ __forceinline__ unsigned int f2bf(float f) {  // RNE fp32->bf16 bits
  unsigned int u = __float_as_uint(f);
  return (u + 0x7fff + ((u >> 16) & 1)) >> 16;
}

__device__ __forceinline__ float fast_tanh(float x) {   // tanh via v_exp_f32
  float e = __expf(-2.f * x);
  return (1.f - e) / (1.f + e);
}

// Workgroup barrier WITHOUT the vmcnt(0) drain __syncthreads() emits.
__device__ __forceinline__ void lds_barrier() {
  asm volatile("s_waitcnt lgkmcnt(0)\n\ts_barrier" ::: "memory");
}

// ---------------------------------------------------------------------------
// fp32 -> bf16 convert with padding; swz=1 pre-swizzles columns within each
// 64-group by ((row&7)<<3) (T2/m173: swizzle SOURCE, LDS dest linear).
// ---------------------------------------------------------------------------
__global__ __launch_bounds__(256) void k_cvt_pad(
    const float* __restrict__ in, __hip_bfloat16* __restrict__ out,
    int in_rows, int in_cols, int out_cols, int swz) {
  int r = blockIdx.x;
  const float* src = in + (size_t)r * in_cols;
  __hip_bfloat16* dst = out + (size_t)r * out_cols;
  bool live = r < in_rows;
  int sx = swz ? ((r & 7) << 3) : 0;
  for (int c = threadIdx.x * 4; c < out_cols; c += 1024) {
    int cc = (c & ~63) | ((c & 63) ^ sx);
    __hip_bfloat16 v[4];
    if (live && cc + 3 < in_cols) {
      float4 f = *(const float4*)(src + cc);
      v[0] = __float2bfloat16(f.x); v[1] = __float2bfloat16(f.y);
      v[2] = __float2bfloat16(f.z); v[3] = __float2bfloat16(f.w);
    } else {
      v[0] = v[1] = v[2] = v[3] = __float2bfloat16(0.f);
    }
    *(ushort4*)(dst + c) = *(const ushort4*)v;
  }
}

// ---------------------------------------------------------------------------
// Pack recurrent weights to bf16 Wcat[f][c][k].
// ---------------------------------------------------------------------------
__global__ __launch_bounds__(256) void k_wpack(
    const float* __restrict__ srcA, int strideA,
    const float* __restrict__ srcB, int strideB,
    __hip_bfloat16* __restrict__ out, int total) {
  int idx = blockIdx.x * 256 + threadIdx.x;
  if (idx >= total) return;
  int k = idx & 255, c = (idx >> 8) & 255, f = idx >> 16;
  float v = (f < 3) ? srcA[(size_t)(f * 256 + c) * strideA + k]
                    : srcB[(size_t)((f - 3) * 256 + c) * strideB + k];
  out[idx] = __float2bfloat16(v);
}

// ---------------------------------------------------------------------------
// Enc GEMM, split-K (see R7): P[z] partials, reduced by k_reduce4.
// ---------------------------------------------------------------------------
__global__ __launch_bounds__(256) void k_gemm_encS(
    const __hip_bfloat16* __restrict__ A, const __hip_bfloat16* __restrict__ B,
    float* __restrict__ P) {
  __shared__ __hip_bfloat16 As[128][64];
  __shared__ __hip_bfloat16 Bs[128][64];
  int t = threadIdx.x;
  int wid = t >> 6, lane = t & 63;
  int m0 = blockIdx.y * 128, n0 = blockIdx.x * 128;
  int wr = wid >> 1, wc = wid & 1;
  int r16 = lane & 15, hi16 = lane >> 4;
  int xr = (r16 & 7) << 4;
  f32x4 acc[4][4] = {};
  int kbeg = blockIdx.z * 2560;
  for (int ks = 0; ks < 40; ++ks) {
    int k0 = kbeg + ks * 64;
    __syncthreads();
#pragma unroll
    for (int is = 0; is < 4; ++is) {
      int off = is * 4096 + t * 16;
      int r = off >> 7, e = (off & 127) >> 1;
      gld_lds16(A + (size_t)(m0 + r) * KP2 + k0 + e, &As[r][e]);
      gld_lds16(B + (size_t)(n0 + r) * KP2 + k0 + e, &Bs[r][e]);
    }
    __syncthreads();
    const char* ab = (const char*)As;
    const char* bb = (const char*)Bs;
#pragma unroll
    for (int kk = 0; kk < 2; ++kk) {
      int ko = kk * 64 + hi16 * 16;
      bf16x8 af[4], bfr[4];
#pragma unroll
      for (int i = 0; i < 4; ++i) {
        af[i]  = *(const bf16x8*)(ab + (wr * 64 + i * 16 + r16) * 128 + (ko ^ xr));
        bfr[i] = *(const bf16x8*)(bb + (wc * 64 + i * 16 + r16) * 128 + (ko ^ xr));
      }
#pragma unroll
      for (int i = 0; i < 4; ++i)
#pragma unroll
        for (int j = 0; j < 4; ++j)
          acc[i][j] = __builtin_amdgcn_mfma_f32_16x16x32_bf16(af[i], bfr[j], acc[i][j], 0, 0, 0);
    }
  }
  float* Pz = P + (size_t)blockIdx.z * 4096 * G3;
#pragma unroll
  for (int i = 0; i < 4; ++i)
#pragma unroll
    for (int j = 0; j < 4; ++j) {
      int ccol = n0 + wc * 64 + j * 16 + r16;
#pragma unroll
      for (int q = 0; q < 4; ++q) {
        int crow = m0 + wr * 64 + i * 16 + hi16 * 4 + q;
        Pz[(size_t)crow * G3 + ccol] = acc[i][j][q];
      }
    }
}

// Gienc = P0+P1+P2+P3 + bias
__global__ __launch_bounds__(256) void k_reduce4(
    const float4* __restrict__ P, const float* __restrict__ bias,
    float4* __restrict__ G) {
  int idx = blockIdx.x * 256 + threadIdx.x;
  float4 a = P[idx], b = P[idx + 786432], c = P[idx + 2 * 786432],
         d = P[idx + 3 * 786432];
  float4 bs = *(const float4*)(bias + (idx % 192) * 4);
  float4 o;
  o.x = a.x + b.x + c.x + d.x + bs.x;
  o.y = a.y + b.y + c.y + d.y + bs.y;
  o.z = a.z + b.z + c.z + d.z + bs.z;
  o.w = a.w + b.w + c.w + d.w + bs.w;
  G[idx] = o;
}

// ---------------------------------------------------------------------------
// Out GEMM (BK=64 + swizzle, see R7).
// ---------------------------------------------------------------------------
__global__ __launch_bounds__(256) void k_gemm_outS(
    const __hip_bfloat16* __restrict__ A, const __hip_bfloat16* __restrict__ B,
    const float* __restrict__ bias, float* __restrict__ C) {
  __shared__ __hip_bfloat16 As[128][64];
  __shared__ __hip_bfloat16 Bs[128][64];
  int t = threadIdx.x;
  int wid = t >> 6, lane = t & 63;
  int m0 = blockIdx.y * 128, n0 = blockIdx.x * 128;
  int wr = wid >> 1, wc = wid & 1;
  int r16 = lane & 15, hi16 = lane >> 4;
  int xr = (r16 & 7) << 4;
  f32x4 acc[4][4] = {};
  for (int k0 = 0; k0 < NH; k0 += 64) {
    __syncthreads();
#pragma unroll
    for (int is = 0; is < 4; ++is) {
      int off = is * 4096 + t * 16;
      int r = off >> 7, e = (off & 127) >> 1;
      gld_lds16(A + (size_t)(m0 + r) * NH + k0 + e, &As[r][e]);
      gld_lds16(B + (size_t)(n0 + r) * NH + k0 + e, &Bs[r][e]);
    }
    __syncthreads();
    const char* ab = (const char*)As;
    const char* bb = (const char*)Bs;
#pragma unroll
    for (int kk = 0; kk < 2; ++kk) {
      int ko = kk * 64 + hi16 * 16;
      bf16x8 af[4], bfr[4];
#pragma unroll
      for (int i = 0; i < 4; ++i) {
        af[i]  = *(const bf16x8*)(ab + (wr * 64 + i * 16 + r16) * 128 + (ko ^ xr));
        bfr[i] = *(const bf16x8*)(bb + (wc * 64 + i * 16 + r16) * 128 + (ko ^ xr));
      }
#pragma unroll
      for (int i = 0; i < 4; ++i)
#pragma unroll
        for (int j = 0; j < 4; ++j)
          acc[i][j] = __builtin_amdgcn_mfma_f32_16x16x32_bf16(af[i], bfr[j], acc[i][j], 0, 0, 0);
    }
  }
#pragma unroll
  for (int i = 0; i < 4; ++i)
#pragma unroll
    for (int j = 0; j < 4; ++j) {
      int ccol = n0 + wc * 64 + j * 16 + r16;
      if (ccol < NVOUT) {
        float bs = bias[ccol];
#pragma unroll
        for (int q = 0; q < 4; ++q) {
          int crow = m0 + wr * 64 + i * 16 + hi16 * 4 + q;  // = l*64+b
          int l = crow >> 6, b = crow & 63;
          C[((size_t)b * NL + l) * NVOUT + ccol] = acc[i][j][q] + bs;
        }
      }
    }
}

// ---------------------------------------------------------------------------
// ENCW GEMM (plain rows): ENCW[b*64+s][c] = sum_k ench[b*64+s][k]*Wih_ctx[c][k]
// ---------------------------------------------------------------------------
__global__ __launch_bounds__(256) void k_gemm_encw(
    const __hip_bfloat16* __restrict__ A, const __hip_bfloat16* __restrict__ B,
    __hip_bfloat16* __restrict__ C) {
  __shared__ __hip_bfloat16 As[128][32];
  __shared__ __hip_bfloat16 Bs[128][32];
  int t = threadIdx.x;
  int wid = t >> 6, lane = t & 63;
  int m0 = blockIdx.y * 128, n0 = blockIdx.x * 128;
  int wr = wid >> 1, wc = wid & 1;
  f32x4 acc[4][4] = {};
  for (int k0 = 0; k0 < NH; k0 += 32) {
    __syncthreads();
#pragma unroll
    for (int is = 0; is < 2; ++is) {
      int off = is * 4096 + wid * 1024 + lane * 16;
      int r = off >> 6, cb = (off & 63) >> 1;
      gld_lds16(A + (size_t)(m0 + r) * NH + k0 + cb, &As[r][cb]);
      gld_lds16(B + (size_t)(n0 + r) * NH + k0 + cb, &Bs[r][cb]);
    }
    __syncthreads();
    int r16 = lane & 15, kb = (lane >> 4) * 8;
    bf16x8 af[4], bfr[4];
#pragma unroll
    for (int i = 0; i < 4; ++i) {
      af[i]  = *(const bf16x8*)&As[wr * 64 + i * 16 + r16][kb];
      bfr[i] = *(const bf16x8*)&Bs[wc * 64 + i * 16 + r16][kb];
    }
#pragma unroll
    for (int i = 0; i < 4; ++i)
#pragma unroll
      for (int j = 0; j < 4; ++j)
        acc[i][j] = __builtin_amdgcn_mfma_f32_16x16x32_bf16(af[i], bfr[j], acc[i][j], 0, 0, 0);
  }
  int r16 = lane & 15, rg = lane >> 4;
#pragma unroll
  for (int i = 0; i < 4; ++i)
#pragma unroll
    for (int j = 0; j < 4; ++j) {
      int ccol = n0 + wc * 64 + j * 16 + r16;
#pragma unroll
      for (int q = 0; q < 4; ++q) {
        int crow = m0 + wr * 64 + i * 16 + rg * 4 + q;   // = b*64+s
        C[(size_t)crow * G3 + ccol] = __float2bfloat16(acc[i][j][q]);
      }
    }
}

// ---------------------------------------------------------------------------
// Attention prefix tables (the gi(δ) collapse):
//   sort esc[b] desc -> thrG[b][r]; wexp_r = exp(thr_r); sigG[b][m]=Σ_{r<m}wexp
//   TP[b][m][c] = Σ_{r<m} wexp_r * ENCW[b][idx_r][c]
//   TQ[b][m][c] = Σ_{r>=m} ENCW[b][idx_r][c]
// Then gi = (e^δ TP[m] + TQ[m]) / (e^δ sig[m] + 64-m), m = #{esc+δ>0}.
// ---------------------------------------------------------------------------
__global__ __launch_bounds__(256) void k_tabs(
    const __hip_bfloat16* __restrict__ ENCW, const float* __restrict__ escoreT,
    __hip_bfloat16* __restrict__ TP, __hip_bfloat16* __restrict__ TQ,
    float* __restrict__ thrG, float* __restrict__ sigG) {
  __shared__ float thrL[64];
  __shared__ int   idxL[64];
  __shared__ float wexpL[64];
  int b = blockIdx.x, t = threadIdx.x;
  if (t < 64) {   // wave 0: rank-sort (desc, index tiebreak)
    float mine = escoreT[b * 64 + t];
    int rank = 0;
    for (int j = 0; j < 64; ++j) {
      float v = __shfl(mine, j, 64);
      rank += (v > mine) || (v == mine && j < t);
    }
    thrL[rank] = mine;
    idxL[rank] = t;
  }
  __syncthreads();
  if (t < 64) {
    float e = __expf(thrL[t]);
    wexpL[t] = e;
    float s = e;   // inclusive scan over sorted ranks
    for (int off = 1; off < 64; off <<= 1) {
      float o = __shfl_up(s, off, 64);
      if (t >= off) s += o;
    }
    sigG[b * 65 + t + 1] = s;
    if (t == 0) sigG[b * 65] = 0.f;
    thrG[b * 64 + t] = thrL[t];
  }
  __syncthreads();
#pragma unroll
  for (int cc = 0; cc < 3; ++cc) {
    int c = t + cc * 256;
    const __hip_bfloat16* ep = ENCW + (size_t)b * 64 * G3 + c;
    float T = 0.f;
    for (int s = 0; s < 64; ++s) T += __bfloat162float(ep[(size_t)s * G3]);
    float P = 0.f, U = 0.f;
    __hip_bfloat16* tp = TP + (size_t)b * 65 * G3 + c;
    __hip_bfloat16* tq = TQ + (size_t)b * 65 * G3 + c;
    tp[0] = __float2bfloat16(0.f);
    tq[0] = __float2bfloat16(T);
    for (int m = 1; m <= 64; ++m) {
      int j = idxL[m - 1];
      float e = __bfloat162float(ep[(size_t)j * G3]);
      P += wexpL[m - 1] * e;
      U += e;
      tp[(size_t)m * G3] = __float2bfloat16(P);
      tq[(size_t)m * G3] = __float2bfloat16(T - U);
    }
  }
}

// ---------------------------------------------------------------------------
// Pre-gather decoder one-hot input term: Gdec = bih + onehot column.
// ---------------------------------------------------------------------------
__global__ __launch_bounds__(256) void k_pregather(
    const float* __restrict__ Wih, const float* __restrict__ bih,
    const int* __restrict__ gt, float* __restrict__ Gdec) {
  int ib = blockIdx.x;              // i*64+b
  int i = ib >> 6, b = ib & 63;
  int tok = (i > 0) ? gt[b * NL + (i - 1)] : -1;
  for (int g = threadIdx.x; g < G3; g += 256) {
    float v = bih[g];
    if (tok >= 0) v += Wih[(size_t)g * (NH + NVOUT) + NH + tok];
    Gdec[(size_t)ib * G3 + g] = v;
  }
}

// ---------------------------------------------------------------------------
// Encoder scan v5 (unchanged from R11).
// ---------------------------------------------------------------------------
__global__ __launch_bounds__(512) void k_encoder5(
    const float* __restrict__ Gi, const __hip_bfloat16* __restrict__ Wcat,
    const float* __restrict__ bhh, __hip_bfloat16* __restrict__ enchB) {
  __shared__ __hip_bfloat16 hbf[2][256];
  int t = threadIdx.x, w = t >> 6, lane = t & 63;
  int b = blockIdx.x;
  int r16 = lane & 15, hi16 = lane >> 4;
  int cw = w * 32;
  bf16x8 wv[3][2][8];
#pragma unroll
  for (int f = 0; f < 3; ++f)
#pragma unroll
    for (int fc = 0; fc < 2; ++fc)
#pragma unroll
      for (int kf = 0; kf < 8; ++kf)
        wv[f][fc][kf] = *(const bf16x8*)(Wcat +
            (((size_t)f * 256 + cw + fc * 16 + r16) * 256 + kf * 32 + hi16 * 8));
  float bh0[2], bh1[2], bh2[2];
#pragma unroll
  for (int fc = 0; fc < 2; ++fc) {
    bh0[fc] = bhh[cw + fc * 16 + r16];
    bh1[fc] = bhh[256 + cw + fc * 16 + r16];
    bh2[fc] = bhh[512 + cw + fc * 16 + r16];
  }
  if (t < 256) {
    hbf[0][t] = __float2bfloat16(0.f);
    hbf[1][t] = __float2bfloat16(0.f);
  }
  __syncthreads();
  float hp[2] = {0.f, 0.f};
  int cur = 0;
  for (int s = 0; s < NS; ++s) {
    float gd0[2], gd1[2], gd2[2];
    if (hi16 == 0) {
      const float* gp = Gi + ((size_t)b * 64 + s) * G3;
#pragma unroll
      for (int fc = 0; fc < 2; ++fc) {
        gd0[fc] = gp[cw + fc * 16 + r16];
        gd1[fc] = gp[256 + cw + fc * 16 + r16];
        gd2[fc] = gp[512 + cw + fc * 16 + r16];
      }
    }
    const char* hb = (const char*)&hbf[cur][0];
    f32x4 acc[3][2] = {};
#pragma unroll
    for (int half = 0; half < 2; ++half) {
      bf16x8 ah[4];
#pragma unroll
      for (int kf = 0; kf < 4; ++kf)
        ah[kf] = *(const bf16x8*)(hb + (half * 4 + kf) * 64 + hi16 * 16);  // broadcast
#pragma unroll
      for (int f = 0; f < 3; ++f)
#pragma unroll
        for (int fc = 0; fc < 2; ++fc)
#pragma unroll
          for (int kf = 0; kf < 4; ++kf)
            acc[f][fc] = __builtin_amdgcn_mfma_f32_16x16x32_bf16(
                ah[kf], wv[f][fc][half * 4 + kf], acc[f][fc], 0, 0, 0);
    }
    if (hi16 == 0) {
      int nxt = cur ^ 1;
#pragma unroll
      for (int fc = 0; fc < 2; ++fc) {
        int c = cw + fc * 16 + r16;
        float rr = 1.f / (1.f + __expf(-(gd0[fc] + acc[0][fc][0] + bh0[fc])));
        float zz = 1.f / (1.f + __expf(-(gd1[fc] + acc[1][fc][0] + bh1[fc])));
        float nn = fast_tanh(gd2[fc] + rr * (acc[2][fc][0] + bh2[fc]));
        float hn = (1.f - zz) * nn + zz * hp[fc];
        hp[fc] = hn;
        hbf[nxt][c] = __float2bfloat16(hn);
        enchB[((size_t)b * 64 + s) * 256 + c] = __float2bfloat16(hn);
      }
    }
    lds_barrier();
    cur ^= 1;
  }
}

// escoreT[b*64+s] = enc_h[b][s] . w_enc
__global__ __launch_bounds__(256) void k_escoreB(
    const __hip_bfloat16* __restrict__ enchB, const float* __restrict__ att_w,
    float* __restrict__ escoreT) {
  int row = blockIdx.x * 4 + (threadIdx.x >> 6);   // = b*64+s
  int lane = threadIdx.x & 63;
  ushort4 u = *(const ushort4*)(enchB + (size_t)row * 256 + lane * 4);
  const float* we = att_w + 256 + lane * 4;
  float p = __uint_as_float((unsigned)u.x << 16) * we[0]
          + __uint_as_float((unsigned)u.y << 16) * we[1]
          + __uint_as_float((unsigned)u.z << 16) * we[2]
          + __uint_as_float((unsigned)u.w << 16) * we[3];
#pragma unroll
  for (int off = 32; off; off >>= 1) p += __shfl_xor(p, off, 64);
  if (lane == 0) escoreT[row] = p;
}

// ---------------------------------------------------------------------------
// Decoder scan v8: gi via the (TP,TQ,sig) tables — NO gi MFMAs, NO e-pack.
// Per step: psum -> delta -> ballot -> m -> 4 table loads (L2) under the gh
// MFMAs -> gates -> h update -> pipelined p partial -> raw barrier.
// ---------------------------------------------------------------------------
__global__ __launch_bounds__(512) void k_decoder8(
    const float* __restrict__ Gdec, const __hip_bfloat16* __restrict__ Wcat6,
    const float* __restrict__ bhh, const __hip_bfloat16* __restrict__ enchB,
    const __hip_bfloat16* __restrict__ TP, const __hip_bfloat16* __restrict__ TQ,
    const float* __restrict__ thrG, const float* __restrict__ sigG,
    const float* __restrict__ att_w, const float* __restrict__ att_b,
    __hip_bfloat16* __restrict__ dechb) {
  __shared__ __hip_bfloat16 hbf[2][256];
  __shared__ float psumL[2][8];
  __shared__ float sigL[65];
  int t = threadIdx.x, w = t >> 6, lane = t & 63;
  int b = blockIdx.x;
  int r16 = lane & 15, hi16 = lane >> 4;
  int cw = w * 32;
  // all 3 Whh panels resident (panels 3,4,5 of Wcat6)
  bf16x8 wv[3][2][8];
#pragma unroll
  for (int f = 0; f < 3; ++f)
#pragma unroll
    for (int fc = 0; fc < 2; ++fc)
#pragma unroll
      for (int kf = 0; kf < 8; ++kf)
        wv[f][fc][kf] = *(const bf16x8*)(Wcat6 +
            (((size_t)(3 + f) * 256 + cw + fc * 16 + r16) * 256 + kf * 32 + hi16 * 8));
  float wd0 = att_w[cw + r16], wd1 = att_w[cw + 16 + r16];
  float attb = att_b[0];
  float thr = thrG[(size_t)b * 64 + lane];       // sorted esc (desc)
  if (t < 65) sigL[t] = sigG[(size_t)b * 65 + t];
  float bh0[2], bh1[2], bh2[2];
#pragma unroll
  for (int fc = 0; fc < 2; ++fc) {
    bh0[fc] = bhh[cw + fc * 16 + r16];
    bh1[fc] = bhh[256 + cw + fc * 16 + r16];
    bh2[fc] = bhh[512 + cw + fc * 16 + r16];
  }
  if (t < 256) {
    hbf[0][t] = enchB[((size_t)b * 64 + 63) * 256 + t];
    hbf[1][t] = __float2bfloat16(0.f);
  }
  float hp[2];
  hp[0] = __bfloat162float(enchB[((size_t)b * 64 + 63) * 256 + cw + r16]);
  hp[1] = __bfloat162float(enchB[((size_t)b * 64 + 63) * 256 + cw + 16 + r16]);
  if (hi16 == 0) {
    float pp = hp[0] * wd0 + hp[1] * wd1;
    pp += __shfl_xor(pp, 1, 64); pp += __shfl_xor(pp, 2, 64);
    pp += __shfl_xor(pp, 4, 64); pp += __shfl_xor(pp, 8, 64);
    if (lane == 0) psumL[0][w] = pp;
  }
  __syncthreads();
  const __hip_bfloat16* tpb = TP + (size_t)b * 65 * G3;
  const __hip_bfloat16* tqb = TQ + (size_t)b * 65 * G3;
  int bs3 = (b & 7) << 3;
  int cur = 0;
  for (int i = 0; i < NL; ++i) {
    // Gdec prefetch (in flight across the step)
    float gd0[2], gd1[2], gd2[2];
    if (hi16 == 0) {
      const float* gp = Gdec + ((size_t)i * 64 + b) * G3;
#pragma unroll
      for (int fc = 0; fc < 2; ++fc) {
        gd0[fc] = gp[cw + fc * 16 + r16];
        gd1[fc] = gp[256 + cw + fc * 16 + r16];
        gd2[fc] = gp[512 + cw + fc * 16 + r16];
      }
    }
    // pipelined p + delta + m (short chain)
    float4 pa = *(const float4*)&psumL[cur][0];
    float4 pb = *(const float4*)&psumL[cur][4];
    float d = ((pa.x + pa.y) + (pa.z + pa.w)) + ((pb.x + pb.y) + (pb.z + pb.w)) + attb;
    float ed = __expf(d);
    unsigned long long bal = __ballot(thr + d > 0.f);
    int m = __popcll(bal);
    // table loads (L2, hidden under the gh MFMAs below)
    float tp0 = 0.f, tp1 = 0.f, tq0 = 0.f, tq1 = 0.f, sg = 0.f;
    if (hi16 == 0) {
      const __hip_bfloat16* tpr = tpb + (size_t)m * G3 + cw + r16;
      const __hip_bfloat16* tqr = tqb + (size_t)m * G3 + cw + r16;
      tp0 = __bfloat162float(tpr[0]);  tp1 = __bfloat162float(tpr[16]);
      tq0 = __bfloat162float(tqr[0]);  tq1 = __bfloat162float(tqr[16]);
      sg = sigL[m];
    }
    // gh MFMAs (h row-broadcast A-frags)
    const char* hb = (const char*)&hbf[cur][0];
    bf16x8 ah[8];
#pragma unroll
    for (int kf = 0; kf < 8; ++kf)
      ah[kf] = *(const bf16x8*)(hb + kf * 64 + hi16 * 16);
    f32x4 acch[3][2] = {};
#pragma unroll
    for (int f = 0; f < 3; ++f)
#pragma unroll
      for (int fc = 0; fc < 2; ++fc)
#pragma unroll
        for (int kf = 0; kf < 8; ++kf)
          acch[f][fc] = __builtin_amdgcn_mfma_f32_16x16x32_bf16(
              ah[kf], wv[f][fc][kf], acch[f][fc], 0, 0, 0);
    // gates + h update + next-step p partial (lanes<16)
    if (hi16 == 0) {
      float rn = 1.f / (ed * sg + (float)(64 - m));
      float gi0 = (ed * tp0 + tq0) * rn;
      float gi1 = (ed * tp1 + tq1) * rn;
      int nxt = cur ^ 1;
      float hn2[2];
#pragma unroll
      for (int fc = 0; fc < 2; ++fc) {
        int c = cw + fc * 16 + r16;
        float gi = fc ? gi1 : gi0;
        // NOTE: gi tables are per-gate-panel: col offsets 0,256,512 handled
        // by separate loads below — see per-panel loads.
        (void)gi;
        (void)c;
      }
      // per-panel table values: r gate at c, z at 256+c, n at 512+c
      float tpr0[2], tpz0[2], tpn0[2], tqr0[2], tqz0[2], tqn0[2];
#pragma unroll
      for (int fc = 0; fc < 2; ++fc) {
        int c = cw + fc * 16 + r16;
        tpr0[fc] = __bfloat162float(tpb[(size_t)m * G3 + c]);
        tpz0[fc] = __bfloat162float(tpb[(size_t)m * G3 + 256 + c]);
        tpn0[fc] = __bfloat162float(tpb[(size_t)m * G3 + 512 + c]);
        tqr0[fc] = __bfloat162float(tqb[(size_t)m * G3 + c]);
        tqz0[fc] = __bfloat162float(tqb[(size_t)m * G3 + 256 + c]);
        tqn0[fc] = __bfloat162float(tqb[(size_t)m * G3 + 512 + c]);
      }
#pragma unroll
      for (int fc = 0; fc < 2; ++fc) {
        int c = cw + fc * 16 + r16;
        float gir = (ed * tpr0[fc] + tqr0[fc]) * rn;
        float giz = (ed * tpz0[fc] + tqz0[fc]) * rn;
        float gin = (ed * tpn0[fc] + tqn0[fc]) * rn;
        float rr = 1.f / (1.f + __expf(-(gd0[fc] + gir + acch[0][fc][0] + bh0[fc])));
        float zz = 1.f / (1.f + __expf(-(gd1[fc] + giz + acch[1][fc][0] + bh1[fc])));
        float nn = fast_tanh(gd2[fc] + gin + rr * (acch[2][fc][0] + bh2[fc]));
        float hn = (1.f - zz) * nn + zz * hp[fc];
        hp[fc] = hn; hn2[fc] = hn;
        hbf[nxt][c] = __float2bfloat16(hn);
        int cs = (c & ~63) | ((c & 63) ^ bs3);
        dechb[((size_t)i * 64 + b) * 256 + cs] = __float2bfloat16(hn);
      }
      float pp = hn2[0] * wd0 + hn2[1] * wd1;
      pp += __shfl_xor(pp, 1, 64); pp += __shfl_xor(pp, 2, 64);
      pp += __shfl_xor(pp, 4, 64); pp += __shfl_xor(pp, 8, 64);
      if (lane == 0) psumL[cur ^ 1][w] = pp;
    }
    lds_barrier();
    cur ^= 1;
  }
}

// ---------------------------------------------------------------------------
// Log-softmax, register-resident single read + single write (one WG/row).
// ---------------------------------------------------------------------------
__global__ __launch_bounds__(256) void k_logsoftmax(float* __restrict__ out) {
  float* x = out + (size_t)blockIdx.x * NVOUT;
  __shared__ float red[256];
  int t = threadIdx.x;
  float4 v[10];
  float mx = -1e30f;
#pragma unroll
  for (int ii = 0; ii < 10; ++ii) {
    int slot = ii * 256 + t;
    if (slot < 2500) {
      v[ii] = *(const float4*)(x + slot * 4);
      mx = fmaxf(mx, fmaxf(fmaxf(v[ii].x, v[ii].y), fmaxf(v[ii].z, v[ii].w)));
    }
  }
  red[t] = mx; __syncthreads();
  for (int off = 128; off; off >>= 1) {
    if (t < off) red[t] = fmaxf(red[t], red[t + off]);
    __syncthreads();
  }
  mx = red[0]; __syncthreads();
  float sm = 0.f;
#pragma unroll
  for (int ii = 0; ii < 10; ++ii) {
    int slot = ii * 256 + t;
    if (slot < 2500)
      sm += __expf(v[ii].x - mx) + __expf(v[ii].y - mx)
          + __expf(v[ii].z - mx) + __expf(v[ii].w - mx);
  }
  red[t] = sm; __syncthreads();
  for (int off = 128; off; off >>= 1) {
    if (t < off) red[t] += red[t + off];
    __syncthreads();
  }
  float lse = mx + logf(red[0]);
#pragma unroll
  for (int ii = 0; ii < 10; ++ii) {
    int slot = ii * 256 + t;
    if (slot < 2500) {
      float4 o; o.x = v[ii].x - lse; o.y = v[ii].y - lse;
      o.z = v[ii].z - lse; o.w = v[ii].w - lse;
      *(float4*)(x + slot * 4) = o;
    }
  }
}

// ---------------------------------------------------------------------------
extern "C" void kernel_launch(void* const* d_in, const int* in_sizes, int n_in,
                              void* d_out, int out_size, void* d_ws, size_t ws_size,
                              hipStream_t stream) {
  const float* X        = (const float*)d_in[0];
  const int*   gt       = (const int*)  d_in[1];
  const float* enc_Wih  = (const float*)d_in[2];
  const float* enc_Whh  = (const float*)d_in[3];
  const float* enc_bih  = (const float*)d_in[4];
  const float* enc_bhh  = (const float*)d_in[5];
  const float* att_w    = (const float*)d_in[6];
  const float* att_b    = (const float*)d_in[7];
  const float* dec_Wih  = (const float*)d_in[8];
  const float* dec_Whh  = (const float*)d_in[9];
  const float* dec_bih  = (const float*)d_in[10];
  const float* dec_bhh  = (const float*)d_in[11];
  const float* out_W    = (const float*)d_in[12];
  const float* out_b    = (const float*)d_in[13];
  float* out = (float*)d_out;

  // workspace carve-up
  float* p = (float*)d_ws;
  float* Gienc  = p; p += NS * NB * G3;          // fp32, dead after encoder
  float* Gdec   = p; p += NL * NB * G3;
  float* escoreT = p; p += NB * NS;
  __hip_bfloat16* q = (__hip_bfloat16*)p;
  __hip_bfloat16* enchBb = q; q += (size_t)NB * NS * NH;
  __hip_bfloat16* Wcat_e = q; q += (size_t)3 * 256 * 256;
  __hip_bfloat16* Wcat_d = q; q += (size_t)6 * 256 * 256;
  __hip_bfloat16* Xb     = q; q += (size_t)4096 * KP2;
  __hip_bfloat16* Wencb  = q; q += (size_t)G3 * KP2;
  __hip_bfloat16* Woutb  = q; q += (size_t)NOUTP * NH;
  __hip_bfloat16* dechb  = q; q += (size_t)NL * NB * NH;
  // ENCW [4096][768] bf16 (6.3 MB) aliases Gienc (dead after encoder)
  __hip_bfloat16* ENCW   = (__hip_bfloat16*)Gienc;
  // attention tables alias Xb (84 MB, dead after k_gemm_encS):
  __hip_bfloat16* TP  = Xb;                               // 64*65*768 bf16 = 6.4 MB
  __hip_bfloat16* TQ  = Xb + (size_t)64 * 65 * G3;        // 6.4 MB
  float* thrG = (float*)(Xb + (size_t)2 * 64 * 65 * G3);  // 16 KB
  float* sigG = thrG + 64 * 64;                           // 16.6 KB
  // split-K partials (50 MB fp32) in d_out scratch (overwritten later)
  float* Pout = (float*)d_out;

  // prep (independent)
  k_cvt_pad<<<4096, 256, 0, stream>>>(X, Xb, 4096, NVIN, KP2, 1);
  k_cvt_pad<<<G3, 256, 0, stream>>>(enc_Wih, Wencb, G3, NVIN, KP2, 1);
  k_cvt_pad<<<NOUTP, 256, 0, stream>>>(out_W, Woutb, NVOUT, NH, NH, 1);
  k_wpack<<<768, 256, 0, stream>>>(enc_Whh, NH, enc_Whh, NH, Wcat_e, 3 * 65536);
  k_wpack<<<1536, 256, 0, stream>>>(dec_Wih, NH + NVOUT, dec_Whh, NH, Wcat_d, 6 * 65536);
  k_pregather<<<NL * NB, 256, 0, stream>>>(dec_Wih, dec_bih, gt, Gdec);

  k_gemm_encS<<<dim3(6, 32, 4), 256, 0, stream>>>(Xb, Wencb, Pout);
  k_reduce4<<<3072, 256, 0, stream>>>((const float4*)Pout, enc_bih, (float4*)Gienc);
  k_encoder5<<<64, 512, 0, stream>>>(Gienc, Wcat_e, enc_bhh, enchBb);
  k_escoreB<<<1024, 256, 0, stream>>>(enchBb, att_w, escoreT);
  k_gemm_encw<<<dim3(6, 32), 256, 0, stream>>>(enchBb, Wcat_d, ENCW);
  k_tabs<<<64, 256, 0, stream>>>(ENCW, escoreT, TP, TQ, thrG, sigG);
  k_decoder8<<<64, 512, 0, stream>>>(Gdec, Wcat_d, dec_bhh, enchBb, TP, TQ,
                                     thrG, sigG, att_w, att_b, dechb);
  k_gemm_outS<<<dim3(79, 32), 256, 0, stream>>>(dechb, Woutb, out_b, out);
  k_logsoftmax<<<NB * NL, 256, 0, stream>>>(out);
}